// Round 1
// baseline (224.858 us; speedup 1.0000x reference)
//
#include <hip/hip_runtime.h>
#include <cstdint>
#include <cstddef>

// ---------- problem constants ----------
#define BB   16
#define NN   4096
#define SS   1024
#define D1   128
#define D2   256
#define CIN  384
#define C0   256
#define C1   128
#define MM   (BB*NN)          // 65536

typedef __attribute__((ext_vector_type(8))) short short8;
typedef __attribute__((ext_vector_type(4))) float f32x4;

__device__ __forceinline__ float b2f(unsigned short h) {
    union { unsigned int u; float f; } x; x.u = ((unsigned int)h) << 16; return x.f;
}
__device__ __forceinline__ unsigned short f2b(float f) {
    union { float f; unsigned int u; } x; x.f = f;
    unsigned int r = x.u + 0x7FFFu + ((x.u >> 16) & 1u);
    return (unsigned short)(r >> 16);
}

#define GLD16(g, l) __builtin_amdgcn_global_load_lds( \
    (const __attribute__((address_space(1))) void*)(g), \
    (__attribute__((address_space(3))) void*)(l), 16, 0, 0)

// ---------- K0: tiled transpose + f32->bf16 cast ----------
// src [B, C, Np] f32  ->  dst [B, Np, dstStride] bf16 (cols [0,C))
__global__ void transpose_cast_k(const float* __restrict__ src, unsigned short* __restrict__ dst,
                                 int C, int Np, int dstStride)
{
    __shared__ float tile[64][65];
    const int b = blockIdx.z, c0 = blockIdx.y * 64, n0 = blockIdx.x * 64;
    const int t = threadIdx.x, j = t & 63, i4 = t >> 6;
#pragma unroll
    for (int p = 0; p < 64; p += 4) {
        int ci = p + i4;
        tile[ci][j] = src[((size_t)b * C + c0 + ci) * Np + n0 + j];
    }
    __syncthreads();
#pragma unroll
    for (int p = 0; p < 64; p += 4) {
        int ni = p + i4;
        dst[((size_t)b * Np + n0 + ni) * dstStride + c0 + j] = f2b(tile[j][ni]);
    }
}

// ---------- K: convert w0/w1 to bf16 ----------
__global__ void cvtw_k(const float* __restrict__ w0, const float* __restrict__ w1,
                       unsigned short* __restrict__ w0b, unsigned short* __restrict__ w1b)
{
    int i = blockIdx.x * 256 + threadIdx.x;
    if (i < C0 * CIN) w0b[i] = f2b(w0[i]);
    if (i < C1 * C0)  w1b[i] = f2b(w1[i]);
}

// ---------- K1: 3-NN (exact fp32, stable ties) + weights from UNSORTED cols 0..2 ----------
#define INS(dd, ss) do { \
    bool c2 = (dd) < d2v; d2v = c2 ? (dd) : d2v; j2 = c2 ? (ss) : j2; \
    { bool c1 = d2v < d1v; float td = d1v; int tj = j1; \
      d1v = c1 ? d2v : d1v; j1 = c1 ? j2 : j1; d2v = c1 ? td : d2v; j2 = c1 ? tj : j2; } \
    { bool c0 = d1v < d0v; float td = d0v; int tj = j0; \
      d0v = c0 ? d1v : d0v; j0 = c0 ? j1 : j0; d1v = c0 ? td : d1v; j1 = c0 ? tj : j1; } \
} while (0)

__global__ void knn_k(const float* __restrict__ xyz1, const float* __restrict__ xyz2,
                      int* __restrict__ idxb, float* __restrict__ wtb)
{
    __shared__ __align__(16) float sx[SS];
    __shared__ __align__(16) float sy[SS];
    __shared__ __align__(16) float sz[SS];
    const int b = blockIdx.y;
    const int n = blockIdx.x * 256 + threadIdx.x;
    for (int i = threadIdx.x; i < SS; i += 256) {
        sx[i] = xyz2[((size_t)b * 3 + 0) * SS + i];
        sy[i] = xyz2[((size_t)b * 3 + 1) * SS + i];
        sz[i] = xyz2[((size_t)b * 3 + 2) * SS + i];
    }
    __syncthreads();
    const float px = xyz1[((size_t)b * 3 + 0) * NN + n];
    const float py = xyz1[((size_t)b * 3 + 1) * NN + n];
    const float pz = xyz1[((size_t)b * 3 + 2) * NN + n];

    float d0v = 3.4e38f, d1v = 3.4e38f, d2v = 3.4e38f;
    int j0 = 0, j1 = 0, j2 = 0;
    const float4* x4 = (const float4*)sx;
    const float4* y4 = (const float4*)sy;
    const float4* z4 = (const float4*)sz;
    for (int s4 = 0; s4 < SS / 4; ++s4) {
        float4 xs = x4[s4], ys = y4[s4], zs = z4[s4];
        { float dx=px-xs.x, dy=py-ys.x, dz=pz-zs.x; float d=dx*dx+dy*dy+dz*dz; INS(d, s4*4+0); }
        { float dx=px-xs.y, dy=py-ys.y, dz=pz-zs.y; float d=dx*dx+dy*dy+dz*dz; INS(d, s4*4+1); }
        { float dx=px-xs.z, dy=py-ys.z, dz=pz-zs.z; float d=dx*dx+dy*dy+dz*dz; INS(d, s4*4+2); }
        { float dx=px-xs.w, dy=py-ys.w, dz=pz-zs.w; float d=dx*dx+dy*dy+dz*dz; INS(d, s4*4+3); }
    }
    // weights: distances to s=0,1,2 (faithful to reference's unsorted-column bug)
    float dd[3];
#pragma unroll
    for (int k = 0; k < 3; ++k) {
        float dx = px - sx[k], dy = py - sy[k], dz = pz - sz[k];
        float d = dx*dx + dy*dy + dz*dz;
        dd[k] = fmaxf(d, 1e-10f);
    }
    float r0 = 1.f/dd[0], r1 = 1.f/dd[1], r2 = 1.f/dd[2];
    float inv = 1.f / (r0 + r1 + r2);
    size_t base = ((size_t)b * NN + n) * 3;
    idxb[base+0] = j0; idxb[base+1] = j1; idxb[base+2] = j2;
    wtb[base+0] = r0*inv; wtb[base+1] = r1*inv; wtb[base+2] = r2*inv;
}

// ---------- K2: gather 3 rows of P2T + weighted sum -> NP cols [128,384) ----------
__global__ void interp_k(const int* __restrict__ idxb, const float* __restrict__ wtb,
                         const unsigned short* __restrict__ P2T, unsigned short* __restrict__ NP)
{
    const int b = blockIdx.y;
    const int n0 = blockIdx.x * 64;
    const int t = threadIdx.x;
    const int dpart = (t & 31) * 8;
    const int nloc = t >> 5;
#pragma unroll
    for (int p = 0; p < 8; ++p) {
        int n = n0 + p * 8 + nloc;
        size_t base = ((size_t)b * NN + n) * 3;
        int i0 = idxb[base+0], i1 = idxb[base+1], i2 = idxb[base+2];
        float w0v = wtb[base+0], w1v = wtb[base+1], w2v = wtb[base+2];
        union { uint4 v; unsigned short s[8]; } a0, a1, a2, ov;
        a0.v = *(const uint4*)(P2T + (((size_t)b * SS + i0) * D2 + dpart));
        a1.v = *(const uint4*)(P2T + (((size_t)b * SS + i1) * D2 + dpart));
        a2.v = *(const uint4*)(P2T + (((size_t)b * SS + i2) * D2 + dpart));
#pragma unroll
        for (int i = 0; i < 8; ++i)
            ov.s[i] = f2b(w0v * b2f(a0.s[i]) + w1v * b2f(a1.s[i]) + w2v * b2f(a2.s[i]));
        *(uint4*)(NP + (((size_t)b * NN + n) * CIN + D1 + dpart)) = ov.v;
    }
}

// ---------- K3: GEMM1  h1[m,o] = sum_c NP[m,c]*w0[o,c]  + per-block BN partials ----------
__launch_bounds__(512, 1)
__global__ void gemm1_k(const unsigned short* __restrict__ NP, const unsigned short* __restrict__ w0b,
                        unsigned short* __restrict__ h1, float* __restrict__ part1)
{
    __shared__ unsigned short Als[128 * 64];   // [row][k] bf16, XOR-swizzled
    __shared__ unsigned short Bls[256 * 64];   // [o][k]  bf16, XOR-swizzled
    __shared__ float lsum[2][256];
    __shared__ float lsq[2][256];

    const int t = threadIdx.x;
    const int wv = t >> 6, l = t & 63, g = l >> 4, lc = l & 15;
    const int wm = wv >> 2, wn = wv & 3;
    const int m0 = blockIdx.x * 128;
    const int sub = t & 7;

    f32x4 acc[4][4];
#pragma unroll
    for (int i = 0; i < 4; ++i)
#pragma unroll
        for (int j = 0; j < 4; ++j) acc[i][j] = (f32x4){0.f, 0.f, 0.f, 0.f};

    for (int ks = 0; ks < 6; ++ks) {
        const int k0 = ks * 64;
        __syncthreads();
#pragma unroll
        for (int q = 0; q < 2; ++q) {      // A: 16KB
            int row = q * 64 + (t >> 3);
            int bco = (sub * 16) ^ ((row & 7) << 4);
            const char* src = (const char*)NP + (((size_t)(m0 + row)) * CIN + k0) * 2 + bco;
            char* dst = (char*)Als + (q * 512 + wv * 64) * 16;
            GLD16(src, dst);
        }
#pragma unroll
        for (int q = 0; q < 4; ++q) {      // B: 32KB
            int o = q * 64 + (t >> 3);
            int bco = (sub * 16) ^ ((o & 7) << 4);
            const char* src = (const char*)w0b + (((size_t)o) * CIN + k0) * 2 + bco;
            char* dst = (char*)Bls + (q * 512 + wv * 64) * 16;
            GLD16(src, dst);
        }
        __syncthreads();
#pragma unroll
        for (int kk = 0; kk < 2; ++kk) {
            short8 af[4], bfr[4];
#pragma unroll
            for (int fm = 0; fm < 4; ++fm) {
                int row = wm * 64 + fm * 16 + lc;
                int bcol = kk * 64 + g * 16;
                af[fm] = *(const short8*)((const char*)Als + row * 128 + (bcol ^ ((row & 7) << 4)));
            }
#pragma unroll
            for (int fn = 0; fn < 4; ++fn) {
                int o = wn * 64 + fn * 16 + lc;
                int bcol = kk * 64 + g * 16;
                bfr[fn] = *(const short8*)((const char*)Bls + o * 128 + (bcol ^ ((o & 7) << 4)));
            }
#pragma unroll
            for (int fm = 0; fm < 4; ++fm)
#pragma unroll
                for (int fn = 0; fn < 4; ++fn)
                    acc[fm][fn] = __builtin_amdgcn_mfma_f32_16x16x32_bf16(af[fm], bfr[fn], acc[fm][fn], 0, 0, 0);
        }
    }

    float s1[4] = {0,0,0,0}, s2v[4] = {0,0,0,0};
#pragma unroll
    for (int fm = 0; fm < 4; ++fm)
#pragma unroll
        for (int fn = 0; fn < 4; ++fn) {
            int row = m0 + wm * 64 + fm * 16 + g * 4;
            int col = wn * 64 + fn * 16 + lc;
#pragma unroll
            for (int j = 0; j < 4; ++j) {
                float v = acc[fm][fn][j];
                h1[((size_t)(row + j)) * C0 + col] = f2b(v);
                s1[fn] += v; s2v[fn] += v * v;
            }
        }
#pragma unroll
    for (int fn = 0; fn < 4; ++fn) {
        s1[fn] += __shfl_xor(s1[fn], 16); s1[fn] += __shfl_xor(s1[fn], 32);
        s2v[fn] += __shfl_xor(s2v[fn], 16); s2v[fn] += __shfl_xor(s2v[fn], 32);
    }
    if (l < 16) {
#pragma unroll
        for (int fn = 0; fn < 4; ++fn) {
            lsum[wm][wn * 64 + fn * 16 + l] = s1[fn];
            lsq[wm][wn * 64 + fn * 16 + l] = s2v[fn];
        }
    }
    __syncthreads();
    if (t < 256) {
        part1[(size_t)blockIdx.x * 512 + t] = lsum[0][t] + lsum[1][t];
        part1[(size_t)blockIdx.x * 512 + 256 + t] = lsq[0][t] + lsq[1][t];
    }
}

// ---------- stats: finalize BN scale/shift ----------
__global__ void stats_k(const float* __restrict__ part, int nblk, int C,
                        const float* __restrict__ gam, const float* __restrict__ bet,
                        float* __restrict__ sc, float* __restrict__ sh)
{
    int o = threadIdx.x;
    if (o >= C) return;
    float s = 0.f, q = 0.f;
#pragma unroll 4
    for (int i = 0; i < nblk; ++i) {
        s += part[(size_t)i * 2 * C + o];
        q += part[(size_t)i * 2 * C + C + o];
    }
    const float inv = 1.0f / (float)MM;
    float mean = s * inv;
    float var = q * inv - mean * mean;
    float scale = gam[o] * rsqrtf(var + 1e-5f);
    sc[o] = scale;
    sh[o] = bet[o] - mean * scale;
}

// ---------- K5: GEMM2 with BN1+ReLU fused into A staging ----------
__launch_bounds__(256, 1)
__global__ void gemm2_k(const unsigned short* __restrict__ h1, const unsigned short* __restrict__ w1b,
                        const float* __restrict__ sc1, const float* __restrict__ sh1,
                        unsigned short* __restrict__ h2, float* __restrict__ part2)
{
    __shared__ unsigned short Als[128 * 64];
    __shared__ unsigned short Bls[128 * 64];
    __shared__ float scl[256], shl[256];
    __shared__ float lsum[2][128];
    __shared__ float lsq[2][128];

    const int t = threadIdx.x;
    const int wv = t >> 6, l = t & 63, g = l >> 4, lc = l & 15;
    const int wm = wv >> 1, wn = wv & 1;
    const int m0 = blockIdx.x * 128;
    const int sub = t & 7;

    scl[t] = sc1[t]; shl[t] = sh1[t];

    f32x4 acc[4][4];
#pragma unroll
    for (int i = 0; i < 4; ++i)
#pragma unroll
        for (int j = 0; j < 4; ++j) acc[i][j] = (f32x4){0.f, 0.f, 0.f, 0.f};

    for (int ks = 0; ks < 4; ++ks) {
        const int k0 = ks * 64;
        __syncthreads();
        uint4 r[4];
#pragma unroll
        for (int q = 0; q < 4; ++q) {
            int row = q * 32 + (t >> 3);
            r[q] = *(const uint4*)((const char*)h1 + (((size_t)(m0 + row)) * C0 + k0) * 2 + sub * 16);
        }
#pragma unroll
        for (int q = 0; q < 4; ++q) {
            int row = q * 32 + (t >> 3);
            union { uint4 v; unsigned short s[8]; } u, ov;
            u.v = r[q];
#pragma unroll
            for (int i = 0; i < 8; ++i) {
                int k = k0 + sub * 8 + i;
                float f = b2f(u.s[i]);
                ov.s[i] = f2b(fmaxf(0.0f, fmaf(scl[k], f, shl[k])));
            }
            *(uint4*)((char*)Als + row * 128 + ((sub * 16) ^ ((row & 7) << 4))) = ov.v;
        }
#pragma unroll
        for (int q = 0; q < 4; ++q) {      // B: 16KB
            int o = q * 32 + (t >> 3);
            int bco = (sub * 16) ^ ((o & 7) << 4);
            const char* src = (const char*)w1b + (((size_t)o) * C0 + k0) * 2 + bco;
            char* dst = (char*)Bls + (q * 256 + wv * 64) * 16;
            GLD16(src, dst);
        }
        __syncthreads();
#pragma unroll
        for (int kk = 0; kk < 2; ++kk) {
            short8 af[4], bfr[4];
#pragma unroll
            for (int fm = 0; fm < 4; ++fm) {
                int row = wm * 64 + fm * 16 + lc;
                int bcol = kk * 64 + g * 16;
                af[fm] = *(const short8*)((const char*)Als + row * 128 + (bcol ^ ((row & 7) << 4)));
            }
#pragma unroll
            for (int fn = 0; fn < 4; ++fn) {
                int o = wn * 64 + fn * 16 + lc;
                int bcol = kk * 64 + g * 16;
                bfr[fn] = *(const short8*)((const char*)Bls + o * 128 + (bcol ^ ((o & 7) << 4)));
            }
#pragma unroll
            for (int fm = 0; fm < 4; ++fm)
#pragma unroll
                for (int fn = 0; fn < 4; ++fn)
                    acc[fm][fn] = __builtin_amdgcn_mfma_f32_16x16x32_bf16(af[fm], bfr[fn], acc[fm][fn], 0, 0, 0);
        }
    }

    float s1[4] = {0,0,0,0}, s2v[4] = {0,0,0,0};
#pragma unroll
    for (int fm = 0; fm < 4; ++fm)
#pragma unroll
        for (int fn = 0; fn < 4; ++fn) {
            int row = m0 + wm * 64 + fm * 16 + g * 4;
            int col = wn * 64 + fn * 16 + lc;
#pragma unroll
            for (int j = 0; j < 4; ++j) {
                float v = acc[fm][fn][j];
                h2[((size_t)(row + j)) * C1 + col] = f2b(v);
                s1[fn] += v; s2v[fn] += v * v;
            }
        }
#pragma unroll
    for (int fn = 0; fn < 4; ++fn) {
        s1[fn] += __shfl_xor(s1[fn], 16); s1[fn] += __shfl_xor(s1[fn], 32);
        s2v[fn] += __shfl_xor(s2v[fn], 16); s2v[fn] += __shfl_xor(s2v[fn], 32);
    }
    if (l < 16) {
#pragma unroll
        for (int fn = 0; fn < 4; ++fn) {
            lsum[wm][wn * 64 + fn * 16 + l] = s1[fn];
            lsq[wm][wn * 64 + fn * 16 + l] = s2v[fn];
        }
    }
    __syncthreads();
    if (t < 128) {
        part2[(size_t)blockIdx.x * 256 + t] = lsum[0][t] + lsum[1][t];
        part2[(size_t)blockIdx.x * 256 + 128 + t] = lsq[0][t] + lsq[1][t];
    }
}

// ---------- K7: final BN2+ReLU + transpose [b,n,o] -> [b,o,n] f32 ----------
__global__ void finalize_k(const unsigned short* __restrict__ h2,
                           const float* __restrict__ sc, const float* __restrict__ sh,
                           float* __restrict__ out)
{
    __shared__ float tile[64][65];
    const int b = blockIdx.z, o0 = blockIdx.y * 64, n0 = blockIdx.x * 64;
    const int t = threadIdx.x, j = t & 63, i4 = t >> 6;
    const float scv = sc[o0 + j], shv = sh[o0 + j];
#pragma unroll
    for (int p = 0; p < 64; p += 4) {
        int ni = p + i4;
        float f = b2f(h2[((size_t)b * NN + n0 + ni) * C1 + o0 + j]);
        tile[ni][j] = fmaxf(0.0f, fmaf(scv, f, shv));
    }
    __syncthreads();
#pragma unroll
    for (int p = 0; p < 64; p += 4) {
        int oi = p + i4;
        out[((size_t)(b * C1 + o0 + oi)) * NN + n0 + j] = tile[j][oi];
    }
}

// ---------- launch ----------
extern "C" void kernel_launch(void* const* d_in, const int* in_sizes, int n_in,
                              void* d_out, int out_size, void* d_ws, size_t ws_size,
                              hipStream_t stream)
{
    const float* xyz1    = (const float*)d_in[0];
    const float* xyz2    = (const float*)d_in[1];
    const float* points1 = (const float*)d_in[2];
    const float* points2 = (const float*)d_in[3];
    const float* w0      = (const float*)d_in[4];
    const float* g0      = (const float*)d_in[6];
    const float* be0     = (const float*)d_in[7];
    const float* w1      = (const float*)d_in[8];
    const float* g1      = (const float*)d_in[10];
    const float* be1     = (const float*)d_in[11];
    float* out = (float*)d_out;
    char* ws = (char*)d_ws;

    unsigned short* NP  = (unsigned short*)(ws + 0);           // 65536*384*2 = 50331648
    unsigned short* h1  = (unsigned short*)(ws + 50331648);    // 65536*256*2 = 33554432
    unsigned short* P2T = (unsigned short*)(ws + 83886080);    // 16*1024*256*2 = 8388608
    unsigned short* h2  = (unsigned short*)(ws + 92274688);    // 65536*128*2 = 16777216
    int*   idxb  = (int*)  (ws + 109051904);                   // 65536*3*4 = 786432
    float* wtb   = (float*)(ws + 109838336);                   // 786432
    unsigned short* w0b = (unsigned short*)(ws + 110624768);   // 98304*2
    unsigned short* w1b = (unsigned short*)(ws + 110821376);   // 32768*2
    float* part1 = (float*)(ws + 110886912);                   // 512*512*4 = 1048576
    float* part2 = (float*)(ws + 111935488);                   // 512*256*4 = 524288
    float* sc1   = (float*)(ws + 112459776);
    float* sh1   = (float*)(ws + 112460800);
    float* sc2   = (float*)(ws + 112461824);
    float* sh2   = (float*)(ws + 112462336);
    // total ws needed: ~112.5 MB

    transpose_cast_k<<<dim3(NN/64, D1/64, BB), 256, 0, stream>>>(points1, NP, D1, NN, CIN);
    transpose_cast_k<<<dim3(SS/64, D2/64, BB), 256, 0, stream>>>(points2, P2T, D2, SS, D2);
    cvtw_k<<<(C0*CIN)/256, 256, 0, stream>>>(w0, w1, w0b, w1b);
    knn_k<<<dim3(NN/256, BB), 256, 0, stream>>>(xyz1, xyz2, idxb, wtb);
    interp_k<<<dim3(NN/64, BB), 256, 0, stream>>>(idxb, wtb, P2T, NP);
    gemm1_k<<<MM/128, 512, 0, stream>>>(NP, w0b, h1, part1);
    stats_k<<<1, 256, 0, stream>>>(part1, MM/128, C0, g0, be0, sc1, sh1);
    gemm2_k<<<MM/128, 256, 0, stream>>>(h1, w1b, sc1, sh1, h2, part2);
    stats_k<<<1, 128, 0, stream>>>(part2, MM/128, C1, g1, be1, sc2, sh2);
    finalize_k<<<dim3(NN/64, C1/64, BB), 256, 0, stream>>>(h2, sc2, sh2, out);
}

// Round 2
// 201.076 us; speedup vs baseline: 1.1183x; 1.1183x over previous
//
#include <hip/hip_runtime.h>
#include <cstdint>
#include <cstddef>

// ---------- problem constants ----------
#define BB   16
#define NN   4096
#define SS   1024
#define D1   128
#define D2   256
#define CIN  384
#define C0   256
#define C1   128
#define MM   (BB*NN)          // 65536

typedef __attribute__((ext_vector_type(8))) short short8;
typedef __attribute__((ext_vector_type(4))) float f32x4;

__device__ __forceinline__ float b2f(unsigned short h) {
    union { unsigned int u; float f; } x; x.u = ((unsigned int)h) << 16; return x.f;
}
__device__ __forceinline__ unsigned short f2b(float f) {
    union { float f; unsigned int u; } x; x.f = f;
    unsigned int r = x.u + 0x7FFFu + ((x.u >> 16) & 1u);
    return (unsigned short)(r >> 16);
}

#define GLD16(g, l) __builtin_amdgcn_global_load_lds( \
    (const __attribute__((address_space(1))) void*)(g), \
    (__attribute__((address_space(3))) void*)(l), 16, 0, 0)

// ---------- K0: tiled transpose + f32->bf16 cast ----------
// src [B, C, Np] f32  ->  dst [B, Np, dstStride] bf16 (cols [0,C))
__global__ void transpose_cast_k(const float* __restrict__ src, unsigned short* __restrict__ dst,
                                 int C, int Np, int dstStride)
{
    __shared__ float tile[64][65];
    const int b = blockIdx.z, c0 = blockIdx.y * 64, n0 = blockIdx.x * 64;
    const int t = threadIdx.x, j = t & 63, i4 = t >> 6;
#pragma unroll
    for (int p = 0; p < 64; p += 4) {
        int ci = p + i4;
        tile[ci][j] = src[((size_t)b * C + c0 + ci) * Np + n0 + j];
    }
    __syncthreads();
#pragma unroll
    for (int p = 0; p < 64; p += 4) {
        int ni = p + i4;
        dst[((size_t)b * Np + n0 + ni) * dstStride + c0 + j] = f2b(tile[j][ni]);
    }
}

// ---------- K: convert w0/w1 to bf16 ----------
__global__ void cvtw_k(const float* __restrict__ w0, const float* __restrict__ w1,
                       unsigned short* __restrict__ w0b, unsigned short* __restrict__ w1b)
{
    int i = blockIdx.x * 256 + threadIdx.x;
    if (i < C0 * CIN) w0b[i] = f2b(w0[i]);
    if (i < C1 * C0)  w1b[i] = f2b(w1[i]);
}

// ---------- K1: 3-NN, S split 4-way across threads, shuffle-merge ----------
// update of sorted top-3 with flat (depth-3) dependency chain
#define UPD(dd, ss) do { \
    bool ca = (dd) < d0v, cb = (dd) < d1v, cc = (dd) < d2v; \
    float t2 = cc ? (dd) : d2v; int u2 = cc ? (ss) : j2; \
    d2v = cb ? d1v : t2;        j2  = cb ? j1  : u2; \
    float t1 = ca ? d0v : (dd); int u1 = ca ? j0 : (ss); \
    d1v = cb ? t1 : d1v;        j1  = cb ? u1  : j1; \
    d0v = ca ? (dd) : d0v;      j0  = ca ? (ss) : j0; \
} while (0)

__global__ __launch_bounds__(256) void knn_k(const float* __restrict__ xyz1,
                                             const float* __restrict__ xyz2,
                                             int* __restrict__ idxb, float* __restrict__ wtb)
{
    // 4 chunks of 256 points, padded to stride 260 floats so the 4 chunks'
    // broadcast b128 reads land on disjoint banks (260 % 32 == 4).
    __shared__ __align__(16) float sx[4 * 260];
    __shared__ __align__(16) float sy[4 * 260];
    __shared__ __align__(16) float sz[4 * 260];
    const int b = blockIdx.y;
    const int t = threadIdx.x;
    const int chunk = t & 3;
    const int n = blockIdx.x * 64 + (t >> 2);

    for (int i = t; i < SS; i += 256) {
        int li = (i >> 8) * 260 + (i & 255);
        sx[li] = xyz2[((size_t)b * 3 + 0) * SS + i];
        sy[li] = xyz2[((size_t)b * 3 + 1) * SS + i];
        sz[li] = xyz2[((size_t)b * 3 + 2) * SS + i];
    }
    __syncthreads();

    const float px = xyz1[((size_t)b * 3 + 0) * NN + n];
    const float py = xyz1[((size_t)b * 3 + 1) * NN + n];
    const float pz = xyz1[((size_t)b * 3 + 2) * NN + n];

    float d0v = 3.4e38f, d1v = 3.4e38f, d2v = 3.4e38f;
    int j0 = 0, j1 = 0, j2 = 0;

    const float* cx = sx + chunk * 260;
    const float* cy = sy + chunk * 260;
    const float* cz = sz + chunk * 260;
    const int sbase = chunk * 256;
#pragma unroll 4
    for (int s4 = 0; s4 < 64; ++s4) {
        float4 xs = *(const float4*)(cx + s4 * 4);
        float4 ys = *(const float4*)(cy + s4 * 4);
        float4 zs = *(const float4*)(cz + s4 * 4);
        int s = sbase + s4 * 4;
        { float dx=px-xs.x, dy=py-ys.x, dz=pz-zs.x; float d=dx*dx+dy*dy+dz*dz; UPD(d, s+0); }
        { float dx=px-xs.y, dy=py-ys.y, dz=pz-zs.y; float d=dx*dx+dy*dy+dz*dz; UPD(d, s+1); }
        { float dx=px-xs.z, dy=py-ys.z, dz=pz-zs.z; float d=dx*dx+dy*dy+dz*dz; UPD(d, s+2); }
        { float dx=px-xs.w, dy=py-ys.w, dz=pz-zs.w; float d=dx*dx+dy*dy+dz*dz; UPD(d, s+3); }
    }

    // merge sorted-3 lists across the 4 chunk lanes (stable: lower chunk wins ties)
#pragma unroll
    for (int r = 1; r <= 2; r <<= 1) {
        float e0 = __shfl_xor(d0v, r), e1 = __shfl_xor(d1v, r), e2 = __shfl_xor(d2v, r);
        int   k0 = __shfl_xor(j0, r),  k1 = __shfl_xor(j1, r),  k2 = __shfl_xor(j2, r);
        bool ownlow = ((t & r) == 0);
        float a0 = ownlow ? d0v : e0, a1 = ownlow ? d1v : e1, a2 = ownlow ? d2v : e2;
        int   x0 = ownlow ? j0 : k0,  x1 = ownlow ? j1 : k1,  x2 = ownlow ? j2 : k2;
        float b0 = ownlow ? e0 : d0v, b1 = ownlow ? e1 : d1v, b2 = ownlow ? e2 : d2v;
        int   y0 = ownlow ? k0 : j0,  y1 = ownlow ? k1 : j1,  y2 = ownlow ? k2 : j2;
        // two-pointer merge of two sorted triples, 'a' preferred on ties
        bool c0 = a0 <= b0;
        d0v = c0 ? a0 : b0;  j0 = c0 ? x0 : y0;
        float na0 = c0 ? a1 : a0, na1 = c0 ? a2 : a1;
        int   nx0 = c0 ? x1 : x0, nx1 = c0 ? x2 : x1;
        float nb0 = c0 ? b0 : b1, nb1 = c0 ? b1 : b2;
        int   ny0 = c0 ? y0 : y1, ny1 = c0 ? y1 : y2;
        bool c1 = na0 <= nb0;
        d1v = c1 ? na0 : nb0;  j1 = c1 ? nx0 : ny0;
        float ma0 = c1 ? na1 : na0;  int mx0 = c1 ? nx1 : nx0;
        float mb0 = c1 ? nb0 : nb1;  int my0 = c1 ? ny0 : ny1;
        bool c2 = ma0 <= mb0;
        d2v = c2 ? ma0 : mb0;  j2 = c2 ? mx0 : my0;
    }

    if (chunk == 0) {
        // weights: distances to s=0,1,2 (faithful to reference's unsorted-column bug)
        float dd[3];
#pragma unroll
        for (int k = 0; k < 3; ++k) {
            float dx = px - sx[k], dy = py - sy[k], dz = pz - sz[k];
            float d = dx*dx + dy*dy + dz*dz;
            dd[k] = fmaxf(d, 1e-10f);
        }
        float r0 = 1.f/dd[0], r1 = 1.f/dd[1], r2 = 1.f/dd[2];
        float inv = 1.f / (r0 + r1 + r2);
        size_t base = ((size_t)b * NN + n) * 3;
        idxb[base+0] = j0; idxb[base+1] = j1; idxb[base+2] = j2;
        wtb[base+0] = r0*inv; wtb[base+1] = r1*inv; wtb[base+2] = r2*inv;
    }
}

// ---------- K2: gather 3 rows of P2T + weighted sum -> NP cols [128,384) ----------
__global__ void interp_k(const int* __restrict__ idxb, const float* __restrict__ wtb,
                         const unsigned short* __restrict__ P2T, unsigned short* __restrict__ NP)
{
    const int b = blockIdx.y;
    const int n0 = blockIdx.x * 64;
    const int t = threadIdx.x;
    const int dpart = (t & 31) * 8;
    const int nloc = t >> 5;
#pragma unroll
    for (int p = 0; p < 8; ++p) {
        int n = n0 + p * 8 + nloc;
        size_t base = ((size_t)b * NN + n) * 3;
        int i0 = idxb[base+0], i1 = idxb[base+1], i2 = idxb[base+2];
        float w0v = wtb[base+0], w1v = wtb[base+1], w2v = wtb[base+2];
        union { uint4 v; unsigned short s[8]; } a0, a1, a2, ov;
        a0.v = *(const uint4*)(P2T + (((size_t)b * SS + i0) * D2 + dpart));
        a1.v = *(const uint4*)(P2T + (((size_t)b * SS + i1) * D2 + dpart));
        a2.v = *(const uint4*)(P2T + (((size_t)b * SS + i2) * D2 + dpart));
#pragma unroll
        for (int i = 0; i < 8; ++i)
            ov.s[i] = f2b(w0v * b2f(a0.s[i]) + w1v * b2f(a1.s[i]) + w2v * b2f(a2.s[i]));
        *(uint4*)(NP + (((size_t)b * NN + n) * CIN + D1 + dpart)) = ov.v;
    }
}

// ---------- K3: GEMM1  h1[m,o] = sum_c NP[m,c]*w0[o,c]  + per-block BN partials ----------
__launch_bounds__(512, 1)
__global__ void gemm1_k(const unsigned short* __restrict__ NP, const unsigned short* __restrict__ w0b,
                        unsigned short* __restrict__ h1, float* __restrict__ part1)
{
    __shared__ unsigned short Als[128 * 64];   // [row][k] bf16, XOR-swizzled
    __shared__ unsigned short Bls[256 * 64];   // [o][k]  bf16, XOR-swizzled
    __shared__ float lsum[2][256];
    __shared__ float lsq[2][256];

    const int t = threadIdx.x;
    const int wv = t >> 6, l = t & 63, g = l >> 4, lc = l & 15;
    const int wm = wv >> 2, wn = wv & 3;
    const int m0 = blockIdx.x * 128;
    const int sub = t & 7;

    f32x4 acc[4][4];
#pragma unroll
    for (int i = 0; i < 4; ++i)
#pragma unroll
        for (int j = 0; j < 4; ++j) acc[i][j] = (f32x4){0.f, 0.f, 0.f, 0.f};

    for (int ks = 0; ks < 6; ++ks) {
        const int k0 = ks * 64;
        __syncthreads();
#pragma unroll
        for (int q = 0; q < 2; ++q) {      // A: 16KB
            int row = q * 64 + (t >> 3);
            int bco = (sub * 16) ^ ((row & 7) << 4);
            const char* src = (const char*)NP + (((size_t)(m0 + row)) * CIN + k0) * 2 + bco;
            char* dst = (char*)Als + (q * 512 + wv * 64) * 16;
            GLD16(src, dst);
        }
#pragma unroll
        for (int q = 0; q < 4; ++q) {      // B: 32KB
            int o = q * 64 + (t >> 3);
            int bco = (sub * 16) ^ ((o & 7) << 4);
            const char* src = (const char*)w0b + (((size_t)o) * CIN + k0) * 2 + bco;
            char* dst = (char*)Bls + (q * 512 + wv * 64) * 16;
            GLD16(src, dst);
        }
        __syncthreads();
#pragma unroll
        for (int kk = 0; kk < 2; ++kk) {
            short8 af[4], bfr[4];
#pragma unroll
            for (int fm = 0; fm < 4; ++fm) {
                int row = wm * 64 + fm * 16 + lc;
                int bcol = kk * 64 + g * 16;
                af[fm] = *(const short8*)((const char*)Als + row * 128 + (bcol ^ ((row & 7) << 4)));
            }
#pragma unroll
            for (int fn = 0; fn < 4; ++fn) {
                int o = wn * 64 + fn * 16 + lc;
                int bcol = kk * 64 + g * 16;
                bfr[fn] = *(const short8*)((const char*)Bls + o * 128 + (bcol ^ ((o & 7) << 4)));
            }
#pragma unroll
            for (int fm = 0; fm < 4; ++fm)
#pragma unroll
                for (int fn = 0; fn < 4; ++fn)
                    acc[fm][fn] = __builtin_amdgcn_mfma_f32_16x16x32_bf16(af[fm], bfr[fn], acc[fm][fn], 0, 0, 0);
        }
    }

    float s1[4] = {0,0,0,0}, s2v[4] = {0,0,0,0};
#pragma unroll
    for (int fm = 0; fm < 4; ++fm)
#pragma unroll
        for (int fn = 0; fn < 4; ++fn) {
            int row = m0 + wm * 64 + fm * 16 + g * 4;
            int col = wn * 64 + fn * 16 + lc;
#pragma unroll
            for (int j = 0; j < 4; ++j) {
                float v = acc[fm][fn][j];
                h1[((size_t)(row + j)) * C0 + col] = f2b(v);
                s1[fn] += v; s2v[fn] += v * v;
            }
        }
#pragma unroll
    for (int fn = 0; fn < 4; ++fn) {
        s1[fn] += __shfl_xor(s1[fn], 16); s1[fn] += __shfl_xor(s1[fn], 32);
        s2v[fn] += __shfl_xor(s2v[fn], 16); s2v[fn] += __shfl_xor(s2v[fn], 32);
    }
    if (l < 16) {
#pragma unroll
        for (int fn = 0; fn < 4; ++fn) {
            lsum[wm][wn * 64 + fn * 16 + l] = s1[fn];
            lsq[wm][wn * 64 + fn * 16 + l] = s2v[fn];
        }
    }
    __syncthreads();
    if (t < 256) {
        part1[(size_t)blockIdx.x * 512 + t] = lsum[0][t] + lsum[1][t];
        part1[(size_t)blockIdx.x * 512 + 256 + t] = lsq[0][t] + lsq[1][t];
    }
}

// ---------- stats: finalize BN scale/shift ----------
__global__ void stats_k(const float* __restrict__ part, int nblk, int C,
                        const float* __restrict__ gam, const float* __restrict__ bet,
                        float* __restrict__ sc, float* __restrict__ sh)
{
    int o = threadIdx.x;
    if (o >= C) return;
    float s = 0.f, q = 0.f;
#pragma unroll 4
    for (int i = 0; i < nblk; ++i) {
        s += part[(size_t)i * 2 * C + o];
        q += part[(size_t)i * 2 * C + C + o];
    }
    const float inv = 1.0f / (float)MM;
    float mean = s * inv;
    float var = q * inv - mean * mean;
    float scale = gam[o] * rsqrtf(var + 1e-5f);
    sc[o] = scale;
    sh[o] = bet[o] - mean * scale;
}

// ---------- K5: GEMM2 with BN1+ReLU fused into A staging ----------
__launch_bounds__(256, 1)
__global__ void gemm2_k(const unsigned short* __restrict__ h1, const unsigned short* __restrict__ w1b,
                        const float* __restrict__ sc1, const float* __restrict__ sh1,
                        unsigned short* __restrict__ h2, float* __restrict__ part2)
{
    __shared__ unsigned short Als[128 * 64];
    __shared__ unsigned short Bls[128 * 64];
    __shared__ float scl[256], shl[256];
    __shared__ float lsum[2][128];
    __shared__ float lsq[2][128];

    const int t = threadIdx.x;
    const int wv = t >> 6, l = t & 63, g = l >> 4, lc = l & 15;
    const int wm = wv >> 1, wn = wv & 1;
    const int m0 = blockIdx.x * 128;
    const int sub = t & 7;

    scl[t] = sc1[t]; shl[t] = sh1[t];

    f32x4 acc[4][4];
#pragma unroll
    for (int i = 0; i < 4; ++i)
#pragma unroll
        for (int j = 0; j < 4; ++j) acc[i][j] = (f32x4){0.f, 0.f, 0.f, 0.f};

    for (int ks = 0; ks < 4; ++ks) {
        const int k0 = ks * 64;
        __syncthreads();
        uint4 r[4];
#pragma unroll
        for (int q = 0; q < 4; ++q) {
            int row = q * 32 + (t >> 3);
            r[q] = *(const uint4*)((const char*)h1 + (((size_t)(m0 + row)) * C0 + k0) * 2 + sub * 16);
        }
#pragma unroll
        for (int q = 0; q < 4; ++q) {
            int row = q * 32 + (t >> 3);
            union { uint4 v; unsigned short s[8]; } u, ov;
            u.v = r[q];
#pragma unroll
            for (int i = 0; i < 8; ++i) {
                int k = k0 + sub * 8 + i;
                float f = b2f(u.s[i]);
                ov.s[i] = f2b(fmaxf(0.0f, fmaf(scl[k], f, shl[k])));
            }
            *(uint4*)((char*)Als + row * 128 + ((sub * 16) ^ ((row & 7) << 4))) = ov.v;
        }
#pragma unroll
        for (int q = 0; q < 4; ++q) {      // B: 16KB
            int o = q * 32 + (t >> 3);
            int bco = (sub * 16) ^ ((o & 7) << 4);
            const char* src = (const char*)w1b + (((size_t)o) * C0 + k0) * 2 + bco;
            char* dst = (char*)Bls + (q * 256 + wv * 64) * 16;
            GLD16(src, dst);
        }
        __syncthreads();
#pragma unroll
        for (int kk = 0; kk < 2; ++kk) {
            short8 af[4], bfr[4];
#pragma unroll
            for (int fm = 0; fm < 4; ++fm) {
                int row = wm * 64 + fm * 16 + lc;
                int bcol = kk * 64 + g * 16;
                af[fm] = *(const short8*)((const char*)Als + row * 128 + (bcol ^ ((row & 7) << 4)));
            }
#pragma unroll
            for (int fn = 0; fn < 4; ++fn) {
                int o = wn * 64 + fn * 16 + lc;
                int bcol = kk * 64 + g * 16;
                bfr[fn] = *(const short8*)((const char*)Bls + o * 128 + (bcol ^ ((o & 7) << 4)));
            }
#pragma unroll
            for (int fm = 0; fm < 4; ++fm)
#pragma unroll
                for (int fn = 0; fn < 4; ++fn)
                    acc[fm][fn] = __builtin_amdgcn_mfma_f32_16x16x32_bf16(af[fm], bfr[fn], acc[fm][fn], 0, 0, 0);
        }
    }

    float s1[4] = {0,0,0,0}, s2v[4] = {0,0,0,0};
#pragma unroll
    for (int fm = 0; fm < 4; ++fm)
#pragma unroll
        for (int fn = 0; fn < 4; ++fn) {
            int row = m0 + wm * 64 + fm * 16 + g * 4;
            int col = wn * 64 + fn * 16 + lc;
#pragma unroll
            for (int j = 0; j < 4; ++j) {
                float v = acc[fm][fn][j];
                h2[((size_t)(row + j)) * C1 + col] = f2b(v);
                s1[fn] += v; s2v[fn] += v * v;
            }
        }
#pragma unroll
    for (int fn = 0; fn < 4; ++fn) {
        s1[fn] += __shfl_xor(s1[fn], 16); s1[fn] += __shfl_xor(s1[fn], 32);
        s2v[fn] += __shfl_xor(s2v[fn], 16); s2v[fn] += __shfl_xor(s2v[fn], 32);
    }
    if (l < 16) {
#pragma unroll
        for (int fn = 0; fn < 4; ++fn) {
            lsum[wm][wn * 64 + fn * 16 + l] = s1[fn];
            lsq[wm][wn * 64 + fn * 16 + l] = s2v[fn];
        }
    }
    __syncthreads();
    if (t < 128) {
        part2[(size_t)blockIdx.x * 256 + t] = lsum[0][t] + lsum[1][t];
        part2[(size_t)blockIdx.x * 256 + 128 + t] = lsq[0][t] + lsq[1][t];
    }
}

// ---------- K7: final BN2+ReLU + transpose [b,n,o] -> [b,o,n] f32 ----------
__global__ void finalize_k(const unsigned short* __restrict__ h2,
                           const float* __restrict__ sc, const float* __restrict__ sh,
                           float* __restrict__ out)
{
    __shared__ float tile[64][65];
    const int b = blockIdx.z, o0 = blockIdx.y * 64, n0 = blockIdx.x * 64;
    const int t = threadIdx.x, j = t & 63, i4 = t >> 6;
    const float scv = sc[o0 + j], shv = sh[o0 + j];
#pragma unroll
    for (int p = 0; p < 64; p += 4) {
        int ni = p + i4;
        float f = b2f(h2[((size_t)b * NN + n0 + ni) * C1 + o0 + j]);
        tile[ni][j] = fmaxf(0.0f, fmaf(scv, f, shv));
    }
    __syncthreads();
#pragma unroll
    for (int p = 0; p < 64; p += 4) {
        int oi = p + i4;
        out[((size_t)(b * C1 + o0 + oi)) * NN + n0 + j] = tile[j][oi];
    }
}

// ---------- launch ----------
extern "C" void kernel_launch(void* const* d_in, const int* in_sizes, int n_in,
                              void* d_out, int out_size, void* d_ws, size_t ws_size,
                              hipStream_t stream)
{
    const float* xyz1    = (const float*)d_in[0];
    const float* xyz2    = (const float*)d_in[1];
    const float* points1 = (const float*)d_in[2];
    const float* points2 = (const float*)d_in[3];
    const float* w0      = (const float*)d_in[4];
    const float* g0      = (const float*)d_in[6];
    const float* be0     = (const float*)d_in[7];
    const float* w1      = (const float*)d_in[8];
    const float* g1      = (const float*)d_in[10];
    const float* be1     = (const float*)d_in[11];
    float* out = (float*)d_out;
    char* ws = (char*)d_ws;

    unsigned short* NP  = (unsigned short*)(ws + 0);           // 65536*384*2 = 50331648
    unsigned short* h1  = (unsigned short*)(ws + 50331648);    // 65536*256*2 = 33554432
    unsigned short* P2T = (unsigned short*)(ws + 83886080);    // 16*1024*256*2 = 8388608
    unsigned short* h2  = (unsigned short*)(ws + 92274688);    // 65536*128*2 = 16777216
    int*   idxb  = (int*)  (ws + 109051904);                   // 65536*3*4 = 786432
    float* wtb   = (float*)(ws + 109838336);                   // 786432
    unsigned short* w0b = (unsigned short*)(ws + 110624768);   // 98304*2
    unsigned short* w1b = (unsigned short*)(ws + 110821376);   // 32768*2
    float* part1 = (float*)(ws + 110886912);                   // 512*512*4 = 1048576
    float* part2 = (float*)(ws + 111935488);                   // 512*256*4 = 524288
    float* sc1   = (float*)(ws + 112459776);
    float* sh1   = (float*)(ws + 112460800);
    float* sc2   = (float*)(ws + 112461824);
    float* sh2   = (float*)(ws + 112462336);
    // total ws needed: ~112.5 MB

    transpose_cast_k<<<dim3(NN/64, D1/64, BB), 256, 0, stream>>>(points1, NP, D1, NN, CIN);
    transpose_cast_k<<<dim3(SS/64, D2/64, BB), 256, 0, stream>>>(points2, P2T, D2, SS, D2);
    cvtw_k<<<(C0*CIN)/256, 256, 0, stream>>>(w0, w1, w0b, w1b);
    knn_k<<<dim3(NN/64, BB), 256, 0, stream>>>(xyz1, xyz2, idxb, wtb);
    interp_k<<<dim3(NN/64, BB), 256, 0, stream>>>(idxb, wtb, P2T, NP);
    gemm1_k<<<MM/128, 512, 0, stream>>>(NP, w0b, h1, part1);
    stats_k<<<1, 256, 0, stream>>>(part1, MM/128, C0, g0, be0, sc1, sh1);
    gemm2_k<<<MM/128, 256, 0, stream>>>(h1, w1b, sc1, sh1, h2, part2);
    stats_k<<<1, 128, 0, stream>>>(part2, MM/128, C1, g1, be1, sc2, sh2);
    finalize_k<<<dim3(NN/64, C1/64, BB), 256, 0, stream>>>(h2, sc2, sh2, out);
}

// Round 3
// 137.475 us; speedup vs baseline: 1.6356x; 1.4626x over previous
//
#include <hip/hip_runtime.h>
#include <cstdint>
#include <cstddef>

// ---------- problem constants ----------
#define BB   16
#define NN   4096
#define SS   1024
#define D1   128
#define D2   256
#define CIN  384
#define C0   256
#define C1   128
#define MM   (BB*NN)          // 65536
#define NBLK (MM/128)         // 512 gemm blocks

typedef __attribute__((ext_vector_type(8))) short short8;
typedef __attribute__((ext_vector_type(4))) float f32x4;

__device__ __forceinline__ float b2f(unsigned short h) {
    union { unsigned int u; float f; } x; x.u = ((unsigned int)h) << 16; return x.f;
}
__device__ __forceinline__ unsigned short f2b(float f) {
    union { float f; unsigned int u; } x; x.f = f;
    unsigned int r = x.u + 0x7FFFu + ((x.u >> 16) & 1u);
    return (unsigned short)(r >> 16);
}

#define GLD16(g, l) __builtin_amdgcn_global_load_lds( \
    (const __attribute__((address_space(1))) void*)(g), \
    (__attribute__((address_space(3))) void*)(l), 16, 0, 0)

// ---------- K0: tiled transpose + f32->bf16 cast ----------
__global__ void transpose_cast_k(const float* __restrict__ src, unsigned short* __restrict__ dst,
                                 int C, int Np, int dstStride)
{
    __shared__ float tile[64][65];
    const int b = blockIdx.z, c0 = blockIdx.y * 64, n0 = blockIdx.x * 64;
    const int t = threadIdx.x, j = t & 63, i4 = t >> 6;
#pragma unroll
    for (int p = 0; p < 64; p += 4) {
        int ci = p + i4;
        tile[ci][j] = src[((size_t)b * C + c0 + ci) * Np + n0 + j];
    }
    __syncthreads();
#pragma unroll
    for (int p = 0; p < 64; p += 4) {
        int ni = p + i4;
        dst[((size_t)b * Np + n0 + ni) * dstStride + c0 + j] = f2b(tile[j][ni]);
    }
}

// ---------- K: convert w0/w1 to bf16 ----------
__global__ void cvtw_k(const float* __restrict__ w0, const float* __restrict__ w1,
                       unsigned short* __restrict__ w0b, unsigned short* __restrict__ w1b)
{
    int i = blockIdx.x * 256 + threadIdx.x;
    if (i < C0 * CIN) w0b[i] = f2b(w0[i]);
    if (i < C1 * C0)  w1b[i] = f2b(w1[i]);
}

// ---------- K1: 3-NN, S split 8-way across threads, shuffle-merge ----------
// sorted top-3 update with flat (depth-3) dependency chain
#define UPD(dd, ss) do { \
    bool ca = (dd) < d0v, cb = (dd) < d1v, cc = (dd) < d2v; \
    float t2 = cc ? (dd) : d2v; int u2 = cc ? (ss) : j2; \
    d2v = cb ? d1v : t2;        j2  = cb ? j1  : u2; \
    float t1 = ca ? d0v : (dd); int u1 = ca ? j0 : (ss); \
    d1v = cb ? t1 : d1v;        j1  = cb ? u1  : j1; \
    d0v = ca ? (dd) : d0v;      j0  = ca ? (ss) : j0; \
} while (0)

__global__ __launch_bounds__(256) void knn_k(const float* __restrict__ xyz1,
                                             const float* __restrict__ xyz2,
                                             int* __restrict__ idxb, float* __restrict__ wtb)
{
    // 8 chunks of 128 points, padded to stride 132 floats: broadcast b128
    // reads from the 8 chunk-groups cover all 32 banks conflict-free.
    __shared__ __align__(16) float sx[8 * 132];
    __shared__ __align__(16) float sy[8 * 132];
    __shared__ __align__(16) float sz[8 * 132];
    const int b = blockIdx.y;
    const int t = threadIdx.x;
    const int chunk = t & 7;
    const int n = blockIdx.x * 32 + (t >> 3);

    for (int i = t; i < SS; i += 256) {
        int li = (i >> 7) * 132 + (i & 127);
        sx[li] = xyz2[((size_t)b * 3 + 0) * SS + i];
        sy[li] = xyz2[((size_t)b * 3 + 1) * SS + i];
        sz[li] = xyz2[((size_t)b * 3 + 2) * SS + i];
    }
    __syncthreads();

    const float px = xyz1[((size_t)b * 3 + 0) * NN + n];
    const float py = xyz1[((size_t)b * 3 + 1) * NN + n];
    const float pz = xyz1[((size_t)b * 3 + 2) * NN + n];

    float d0v = 3.4e38f, d1v = 3.4e38f, d2v = 3.4e38f;
    int j0 = 0, j1 = 0, j2 = 0;

    const float* cx = sx + chunk * 132;
    const float* cy = sy + chunk * 132;
    const float* cz = sz + chunk * 132;
    const int sbase = chunk * 128;
#pragma unroll 4
    for (int s4 = 0; s4 < 32; ++s4) {
        float4 xs = *(const float4*)(cx + s4 * 4);
        float4 ys = *(const float4*)(cy + s4 * 4);
        float4 zs = *(const float4*)(cz + s4 * 4);
        int s = sbase + s4 * 4;
        { float dx=px-xs.x, dy=py-ys.x, dz=pz-zs.x; float d=dx*dx+dy*dy+dz*dz; UPD(d, s+0); }
        { float dx=px-xs.y, dy=py-ys.y, dz=pz-zs.y; float d=dx*dx+dy*dy+dz*dz; UPD(d, s+1); }
        { float dx=px-xs.z, dy=py-ys.z, dz=pz-zs.z; float d=dx*dx+dy*dy+dz*dz; UPD(d, s+2); }
        { float dx=px-xs.w, dy=py-ys.w, dz=pz-zs.w; float d=dx*dx+dy*dy+dz*dz; UPD(d, s+3); }
    }

    // merge sorted-3 lists across the 8 chunk lanes (stable: lower chunk wins ties)
#pragma unroll
    for (int r = 1; r <= 4; r <<= 1) {
        float e0 = __shfl_xor(d0v, r), e1 = __shfl_xor(d1v, r), e2 = __shfl_xor(d2v, r);
        int   k0 = __shfl_xor(j0, r),  k1 = __shfl_xor(j1, r),  k2 = __shfl_xor(j2, r);
        bool ownlow = ((t & r) == 0);
        float a0 = ownlow ? d0v : e0, a1 = ownlow ? d1v : e1, a2 = ownlow ? d2v : e2;
        int   x0 = ownlow ? j0 : k0,  x1 = ownlow ? j1 : k1,  x2 = ownlow ? j2 : k2;
        float b0 = ownlow ? e0 : d0v, b1 = ownlow ? e1 : d1v, b2 = ownlow ? e2 : d2v;
        int   y0 = ownlow ? k0 : j0,  y1 = ownlow ? k1 : j1,  y2 = ownlow ? k2 : j2;
        bool c0 = a0 <= b0;
        d0v = c0 ? a0 : b0;  j0 = c0 ? x0 : y0;
        float na0 = c0 ? a1 : a0, na1 = c0 ? a2 : a1;
        int   nx0 = c0 ? x1 : x0, nx1 = c0 ? x2 : x1;
        float nb0 = c0 ? b0 : b1, nb1 = c0 ? b1 : b2;
        int   ny0 = c0 ? y0 : y1, ny1 = c0 ? y1 : y2;
        bool c1 = na0 <= nb0;
        d1v = c1 ? na0 : nb0;  j1 = c1 ? nx0 : ny0;
        float ma0 = c1 ? na1 : na0;  int mx0 = c1 ? nx1 : nx0;
        float mb0 = c1 ? nb0 : nb1;  int my0 = c1 ? ny0 : ny1;
        bool c2 = ma0 <= mb0;
        d2v = c2 ? ma0 : mb0;  j2 = c2 ? mx0 : my0;
    }

    if (chunk == 0) {
        // weights: distances to s=0,1,2 (faithful to reference's unsorted-column bug)
        float dd[3];
#pragma unroll
        for (int k = 0; k < 3; ++k) {
            float dx = px - sx[k], dy = py - sy[k], dz = pz - sz[k];
            float d = dx*dx + dy*dy + dz*dz;
            dd[k] = fmaxf(d, 1e-10f);
        }
        float r0 = 1.f/dd[0], r1 = 1.f/dd[1], r2 = 1.f/dd[2];
        float inv = 1.f / (r0 + r1 + r2);
        size_t base = ((size_t)b * NN + n) * 3;
        idxb[base+0] = j0; idxb[base+1] = j1; idxb[base+2] = j2;
        wtb[base+0] = r0*inv; wtb[base+1] = r1*inv; wtb[base+2] = r2*inv;
    }
}

// ---------- K2: gather 3 rows of P2T + weighted sum -> NP cols [128,384) ----------
__global__ void interp_k(const int* __restrict__ idxb, const float* __restrict__ wtb,
                         const unsigned short* __restrict__ P2T, unsigned short* __restrict__ NP)
{
    const int b = blockIdx.y;
    const int n0 = blockIdx.x * 64;
    const int t = threadIdx.x;
    const int dpart = (t & 31) * 8;
    const int nloc = t >> 5;
#pragma unroll
    for (int p = 0; p < 8; ++p) {
        int n = n0 + p * 8 + nloc;
        size_t base = ((size_t)b * NN + n) * 3;
        int i0 = idxb[base+0], i1 = idxb[base+1], i2 = idxb[base+2];
        float w0v = wtb[base+0], w1v = wtb[base+1], w2v = wtb[base+2];
        union { uint4 v; unsigned short s[8]; } a0, a1, a2, ov;
        a0.v = *(const uint4*)(P2T + (((size_t)b * SS + i0) * D2 + dpart));
        a1.v = *(const uint4*)(P2T + (((size_t)b * SS + i1) * D2 + dpart));
        a2.v = *(const uint4*)(P2T + (((size_t)b * SS + i2) * D2 + dpart));
#pragma unroll
        for (int i = 0; i < 8; ++i)
            ov.s[i] = f2b(w0v * b2f(a0.s[i]) + w1v * b2f(a1.s[i]) + w2v * b2f(a2.s[i]));
        *(uint4*)(NP + (((size_t)b * NN + n) * CIN + D1 + dpart)) = ov.v;
    }
}

// ---------- K3: GEMM1  h1[m,o] = sum_c NP[m,c]*w0[o,c]  + per-block BN partials ----------
__launch_bounds__(512, 1)
__global__ void gemm1_k(const unsigned short* __restrict__ NP, const unsigned short* __restrict__ w0b,
                        unsigned short* __restrict__ h1, float* __restrict__ part1)
{
    __shared__ unsigned short Als[128 * 64];   // [row][k] bf16, XOR-swizzled
    __shared__ unsigned short Bls[256 * 64];   // [o][k]  bf16, XOR-swizzled
    __shared__ float lsum[2][256];
    __shared__ float lsq[2][256];

    const int t = threadIdx.x;
    const int wv = t >> 6, l = t & 63, g = l >> 4, lc = l & 15;
    const int wm = wv >> 2, wn = wv & 3;
    const int m0 = blockIdx.x * 128;
    const int sub = t & 7;

    f32x4 acc[4][4];
#pragma unroll
    for (int i = 0; i < 4; ++i)
#pragma unroll
        for (int j = 0; j < 4; ++j) acc[i][j] = (f32x4){0.f, 0.f, 0.f, 0.f};

    for (int ks = 0; ks < 6; ++ks) {
        const int k0 = ks * 64;
        __syncthreads();
#pragma unroll
        for (int q = 0; q < 2; ++q) {      // A: 16KB
            int row = q * 64 + (t >> 3);
            int bco = (sub * 16) ^ ((row & 7) << 4);
            const char* src = (const char*)NP + (((size_t)(m0 + row)) * CIN + k0) * 2 + bco;
            char* dst = (char*)Als + (q * 512 + wv * 64) * 16;
            GLD16(src, dst);
        }
#pragma unroll
        for (int q = 0; q < 4; ++q) {      // B: 32KB
            int o = q * 64 + (t >> 3);
            int bco = (sub * 16) ^ ((o & 7) << 4);
            const char* src = (const char*)w0b + (((size_t)o) * CIN + k0) * 2 + bco;
            char* dst = (char*)Bls + (q * 512 + wv * 64) * 16;
            GLD16(src, dst);
        }
        __syncthreads();
#pragma unroll
        for (int kk = 0; kk < 2; ++kk) {
            short8 af[4], bfr[4];
#pragma unroll
            for (int fm = 0; fm < 4; ++fm) {
                int row = wm * 64 + fm * 16 + lc;
                int bcol = kk * 64 + g * 16;
                af[fm] = *(const short8*)((const char*)Als + row * 128 + (bcol ^ ((row & 7) << 4)));
            }
#pragma unroll
            for (int fn = 0; fn < 4; ++fn) {
                int o = wn * 64 + fn * 16 + lc;
                int bcol = kk * 64 + g * 16;
                bfr[fn] = *(const short8*)((const char*)Bls + o * 128 + (bcol ^ ((o & 7) << 4)));
            }
#pragma unroll
            for (int fm = 0; fm < 4; ++fm)
#pragma unroll
                for (int fn = 0; fn < 4; ++fn)
                    acc[fm][fn] = __builtin_amdgcn_mfma_f32_16x16x32_bf16(af[fm], bfr[fn], acc[fm][fn], 0, 0, 0);
        }
    }

    float s1[4] = {0,0,0,0}, s2v[4] = {0,0,0,0};
#pragma unroll
    for (int fm = 0; fm < 4; ++fm)
#pragma unroll
        for (int fn = 0; fn < 4; ++fn) {
            int row = m0 + wm * 64 + fm * 16 + g * 4;
            int col = wn * 64 + fn * 16 + lc;
#pragma unroll
            for (int j = 0; j < 4; ++j) {
                float v = acc[fm][fn][j];
                h1[((size_t)(row + j)) * C0 + col] = f2b(v);
                s1[fn] += v; s2v[fn] += v * v;
            }
        }
#pragma unroll
    for (int fn = 0; fn < 4; ++fn) {
        s1[fn] += __shfl_xor(s1[fn], 16); s1[fn] += __shfl_xor(s1[fn], 32);
        s2v[fn] += __shfl_xor(s2v[fn], 16); s2v[fn] += __shfl_xor(s2v[fn], 32);
    }
    if (l < 16) {
#pragma unroll
        for (int fn = 0; fn < 4; ++fn) {
            lsum[wm][wn * 64 + fn * 16 + l] = s1[fn];
            lsq[wm][wn * 64 + fn * 16 + l] = s2v[fn];
        }
    }
    __syncthreads();
    // partials transposed: [channel][block] so stats reads coalesce
    if (t < 256) {
        part1[(size_t)t * NBLK + blockIdx.x]          = lsum[0][t] + lsum[1][t];
        part1[(size_t)(C0 + t) * NBLK + blockIdx.x]   = lsq[0][t] + lsq[1][t];
    }
}

// ---------- stats: one wave per channel, coalesced [channel][block] reads ----------
__global__ void stats_k(const float* __restrict__ part, int nblk, int C,
                        const float* __restrict__ gam, const float* __restrict__ bet,
                        float* __restrict__ sc, float* __restrict__ sh)
{
    const int w = threadIdx.x >> 6, l = threadIdx.x & 63;
    const int o = blockIdx.x * 4 + w;
    if (o >= C) return;
    float s = 0.f, q = 0.f;
    for (int i = l; i < nblk; i += 64) {
        s += part[(size_t)o * nblk + i];
        q += part[(size_t)(C + o) * nblk + i];
    }
#pragma unroll
    for (int r = 32; r; r >>= 1) { s += __shfl_xor(s, r); q += __shfl_xor(q, r); }
    if (l == 0) {
        const float inv = 1.0f / (float)MM;
        float mean = s * inv;
        float var = q * inv - mean * mean;
        float scale = gam[o] * rsqrtf(var + 1e-5f);
        sc[o] = scale;
        sh[o] = bet[o] - mean * scale;
    }
}

// ---------- K5: GEMM2 with BN1+ReLU fused into A staging ----------
__launch_bounds__(256, 1)
__global__ void gemm2_k(const unsigned short* __restrict__ h1, const unsigned short* __restrict__ w1b,
                        const float* __restrict__ sc1, const float* __restrict__ sh1,
                        unsigned short* __restrict__ h2, float* __restrict__ part2)
{
    __shared__ unsigned short Als[128 * 64];
    __shared__ unsigned short Bls[128 * 64];
    __shared__ float scl[256], shl[256];
    __shared__ float lsum[2][128];
    __shared__ float lsq[2][128];

    const int t = threadIdx.x;
    const int wv = t >> 6, l = t & 63, g = l >> 4, lc = l & 15;
    const int wm = wv >> 1, wn = wv & 1;
    const int m0 = blockIdx.x * 128;
    const int sub = t & 7;

    scl[t] = sc1[t]; shl[t] = sh1[t];

    f32x4 acc[4][4];
#pragma unroll
    for (int i = 0; i < 4; ++i)
#pragma unroll
        for (int j = 0; j < 4; ++j) acc[i][j] = (f32x4){0.f, 0.f, 0.f, 0.f};

    for (int ks = 0; ks < 4; ++ks) {
        const int k0 = ks * 64;
        __syncthreads();
        uint4 r[4];
#pragma unroll
        for (int q = 0; q < 4; ++q) {
            int row = q * 32 + (t >> 3);
            r[q] = *(const uint4*)((const char*)h1 + (((size_t)(m0 + row)) * C0 + k0) * 2 + sub * 16);
        }
#pragma unroll
        for (int q = 0; q < 4; ++q) {
            int row = q * 32 + (t >> 3);
            union { uint4 v; unsigned short s[8]; } u, ov;
            u.v = r[q];
#pragma unroll
            for (int i = 0; i < 8; ++i) {
                int k = k0 + sub * 8 + i;
                float f = b2f(u.s[i]);
                ov.s[i] = f2b(fmaxf(0.0f, fmaf(scl[k], f, shl[k])));
            }
            *(uint4*)((char*)Als + row * 128 + ((sub * 16) ^ ((row & 7) << 4))) = ov.v;
        }
#pragma unroll
        for (int q = 0; q < 4; ++q) {      // B: 16KB
            int o = q * 32 + (t >> 3);
            int bco = (sub * 16) ^ ((o & 7) << 4);
            const char* src = (const char*)w1b + (((size_t)o) * C0 + k0) * 2 + bco;
            char* dst = (char*)Bls + (q * 256 + wv * 64) * 16;
            GLD16(src, dst);
        }
        __syncthreads();
#pragma unroll
        for (int kk = 0; kk < 2; ++kk) {
            short8 af[4], bfr[4];
#pragma unroll
            for (int fm = 0; fm < 4; ++fm) {
                int row = wm * 64 + fm * 16 + lc;
                int bcol = kk * 64 + g * 16;
                af[fm] = *(const short8*)((const char*)Als + row * 128 + (bcol ^ ((row & 7) << 4)));
            }
#pragma unroll
            for (int fn = 0; fn < 4; ++fn) {
                int o = wn * 64 + fn * 16 + lc;
                int bcol = kk * 64 + g * 16;
                bfr[fn] = *(const short8*)((const char*)Bls + o * 128 + (bcol ^ ((o & 7) << 4)));
            }
#pragma unroll
            for (int fm = 0; fm < 4; ++fm)
#pragma unroll
                for (int fn = 0; fn < 4; ++fn)
                    acc[fm][fn] = __builtin_amdgcn_mfma_f32_16x16x32_bf16(af[fm], bfr[fn], acc[fm][fn], 0, 0, 0);
        }
    }

    float s1[4] = {0,0,0,0}, s2v[4] = {0,0,0,0};
#pragma unroll
    for (int fm = 0; fm < 4; ++fm)
#pragma unroll
        for (int fn = 0; fn < 4; ++fn) {
            int row = m0 + wm * 64 + fm * 16 + g * 4;
            int col = wn * 64 + fn * 16 + lc;
#pragma unroll
            for (int j = 0; j < 4; ++j) {
                float v = acc[fm][fn][j];
                h2[((size_t)(row + j)) * C1 + col] = f2b(v);
                s1[fn] += v; s2v[fn] += v * v;
            }
        }
#pragma unroll
    for (int fn = 0; fn < 4; ++fn) {
        s1[fn] += __shfl_xor(s1[fn], 16); s1[fn] += __shfl_xor(s1[fn], 32);
        s2v[fn] += __shfl_xor(s2v[fn], 16); s2v[fn] += __shfl_xor(s2v[fn], 32);
    }
    if (l < 16) {
#pragma unroll
        for (int fn = 0; fn < 4; ++fn) {
            lsum[wm][wn * 64 + fn * 16 + l] = s1[fn];
            lsq[wm][wn * 64 + fn * 16 + l] = s2v[fn];
        }
    }
    __syncthreads();
    if (t < 128) {
        part2[(size_t)t * NBLK + blockIdx.x]        = lsum[0][t] + lsum[1][t];
        part2[(size_t)(C1 + t) * NBLK + blockIdx.x] = lsq[0][t] + lsq[1][t];
    }
}

// ---------- K7: final BN2+ReLU + transpose [b,n,o] -> [b,o,n] f32 ----------
__global__ void finalize_k(const unsigned short* __restrict__ h2,
                           const float* __restrict__ sc, const float* __restrict__ sh,
                           float* __restrict__ out)
{
    __shared__ float tile[64][65];
    const int b = blockIdx.z, o0 = blockIdx.y * 64, n0 = blockIdx.x * 64;
    const int t = threadIdx.x, j = t & 63, i4 = t >> 6;
    const float scv = sc[o0 + j], shv = sh[o0 + j];
#pragma unroll
    for (int p = 0; p < 64; p += 4) {
        int ni = p + i4;
        float f = b2f(h2[((size_t)b * NN + n0 + ni) * C1 + o0 + j]);
        tile[ni][j] = fmaxf(0.0f, fmaf(scv, f, shv));
    }
    __syncthreads();
#pragma unroll
    for (int p = 0; p < 64; p += 4) {
        int oi = p + i4;
        out[((size_t)(b * C1 + o0 + oi)) * NN + n0 + j] = tile[j][oi];
    }
}

// ---------- launch ----------
extern "C" void kernel_launch(void* const* d_in, const int* in_sizes, int n_in,
                              void* d_out, int out_size, void* d_ws, size_t ws_size,
                              hipStream_t stream)
{
    const float* xyz1    = (const float*)d_in[0];
    const float* xyz2    = (const float*)d_in[1];
    const float* points1 = (const float*)d_in[2];
    const float* points2 = (const float*)d_in[3];
    const float* w0      = (const float*)d_in[4];
    const float* g0      = (const float*)d_in[6];
    const float* be0     = (const float*)d_in[7];
    const float* w1      = (const float*)d_in[8];
    const float* g1      = (const float*)d_in[10];
    const float* be1     = (const float*)d_in[11];
    float* out = (float*)d_out;
    char* ws = (char*)d_ws;

    unsigned short* NP  = (unsigned short*)(ws + 0);           // 65536*384*2 = 50331648
    unsigned short* h1  = (unsigned short*)(ws + 50331648);    // 65536*256*2 = 33554432
    unsigned short* P2T = (unsigned short*)(ws + 83886080);    // 16*1024*256*2 = 8388608
    unsigned short* h2  = (unsigned short*)(ws + 92274688);    // 65536*128*2 = 16777216
    int*   idxb  = (int*)  (ws + 109051904);                   // 65536*3*4 = 786432
    float* wtb   = (float*)(ws + 109838336);                   // 786432
    unsigned short* w0b = (unsigned short*)(ws + 110624768);   // 98304*2
    unsigned short* w1b = (unsigned short*)(ws + 110821376);   // 32768*2
    float* part1 = (float*)(ws + 110886912);                   // 2*256*512*4 = 1048576
    float* part2 = (float*)(ws + 111935488);                   // 2*128*512*4 = 524288
    float* sc1   = (float*)(ws + 112459776);
    float* sh1   = (float*)(ws + 112460800);
    float* sc2   = (float*)(ws + 112461824);
    float* sh2   = (float*)(ws + 112462336);
    // total ws needed: ~112.5 MB

    transpose_cast_k<<<dim3(NN/64, D1/64, BB), 256, 0, stream>>>(points1, NP, D1, NN, CIN);
    transpose_cast_k<<<dim3(SS/64, D2/64, BB), 256, 0, stream>>>(points2, P2T, D2, SS, D2);
    cvtw_k<<<(C0*CIN)/256, 256, 0, stream>>>(w0, w1, w0b, w1b);
    knn_k<<<dim3(NN/32, BB), 256, 0, stream>>>(xyz1, xyz2, idxb, wtb);
    interp_k<<<dim3(NN/64, BB), 256, 0, stream>>>(idxb, wtb, P2T, NP);
    gemm1_k<<<MM/128, 512, 0, stream>>>(NP, w0b, h1, part1);
    stats_k<<<C0/4, 256, 0, stream>>>(part1, NBLK, C0, g0, be0, sc1, sh1);
    gemm2_k<<<MM/128, 256, 0, stream>>>(h1, w1b, sc1, sh1, h2, part2);
    stats_k<<<C1/4, 256, 0, stream>>>(part2, NBLK, C1, g1, be1, sc2, sh2);
    finalize_k<<<dim3(NN/64, C1/64, BB), 256, 0, stream>>>(h2, sc2, sh2, out);
}

// Round 4
// 126.072 us; speedup vs baseline: 1.7836x; 1.0905x over previous
//
#include <hip/hip_runtime.h>
#include <cstdint>
#include <cstddef>

// ---------- problem constants ----------
#define BB   16
#define NN   4096
#define SS   1024
#define D1   128
#define D2   256
#define CIN  384
#define C0   256
#define C1   128
#define MM   (BB*NN)          // 65536
#define NBLK (MM/128)         // 512 gemm blocks

typedef __attribute__((ext_vector_type(8))) short short8;
typedef __attribute__((ext_vector_type(4))) float f32x4;

__device__ __forceinline__ float b2f(unsigned short h) {
    union { unsigned int u; float f; } x; x.u = ((unsigned int)h) << 16; return x.f;
}
__device__ __forceinline__ unsigned short f2b(float f) {
    union { float f; unsigned int u; } x; x.f = f;
    unsigned int r = x.u + 0x7FFFu + ((x.u >> 16) & 1u);
    return (unsigned short)(r >> 16);
}

#define GLD16(g, l) __builtin_amdgcn_global_load_lds( \
    (const __attribute__((address_space(1))) void*)(g), \
    (__attribute__((address_space(3))) void*)(l), 16, 0, 0)

// ---------- K0: tiled transpose + f32->bf16 cast ----------
__global__ void transpose_cast_k(const float* __restrict__ src, unsigned short* __restrict__ dst,
                                 int C, int Np, int dstStride)
{
    __shared__ float tile[64][65];
    const int b = blockIdx.z, c0 = blockIdx.y * 64, n0 = blockIdx.x * 64;
    const int t = threadIdx.x, j = t & 63, i4 = t >> 6;
#pragma unroll
    for (int p = 0; p < 64; p += 4) {
        int ci = p + i4;
        tile[ci][j] = src[((size_t)b * C + c0 + ci) * Np + n0 + j];
    }
    __syncthreads();
#pragma unroll
    for (int p = 0; p < 64; p += 4) {
        int ni = p + i4;
        dst[((size_t)b * Np + n0 + ni) * dstStride + c0 + j] = f2b(tile[j][ni]);
    }
}

// ---------- K: convert w0/w1 to bf16 ----------
__global__ void cvtw_k(const float* __restrict__ w0, const float* __restrict__ w1,
                       unsigned short* __restrict__ w0b, unsigned short* __restrict__ w1b)
{
    int i = blockIdx.x * 256 + threadIdx.x;
    if (i < C0 * CIN) w0b[i] = f2b(w0[i]);
    if (i < C1 * C0)  w1b[i] = f2b(w1[i]);
}

// ---------- K1: 3-NN ----------
// sorted top-3 insert: values via min/med3 (3 ops), indices via 3 cmp + 5 sel.
// Stability: strict < means on tie the incumbent (earlier s) stays ahead.
#define UPD6(dd, ss, D0, D1v, D2v, J0, J1, J2) do { \
    bool ca = (dd) < D0, cb = (dd) < D1v, cc = (dd) < D2v; \
    float m1 = __builtin_amdgcn_fmed3f((dd), D0, D1v); \
    float m2 = __builtin_amdgcn_fmed3f((dd), D1v, D2v); \
    int u1 = ca ? J0 : (ss); \
    int u2 = cb ? J1 : (ss); \
    D0 = fminf((dd), D0); \
    J2 = cc ? u2 : J2; \
    J1 = cb ? u1 : J1; \
    J0 = ca ? (ss) : J0; \
    D1v = m1; D2v = m2; \
} while (0)

// (x,xj) strictly before (y,yj) in stable order
#define LTE(x, xj, y, yj) ((x) < (y) || ((x) == (y) && (xj) < (yj)))

__global__ __launch_bounds__(256) void knn_k(const float* __restrict__ xyz1,
                                             const float* __restrict__ xyz2,
                                             int* __restrict__ idxb, float* __restrict__ wtb)
{
    // 8 chunks of 128 points, stride 132 floats: the 8 chunk-groups' broadcast
    // b128 reads cover disjoint banks.
    __shared__ __align__(16) float sx[8 * 132];
    __shared__ __align__(16) float sy[8 * 132];
    __shared__ __align__(16) float sz[8 * 132];
    const int b = blockIdx.y;
    const int t = threadIdx.x;
    const int chunk = t & 7;
    const int n = blockIdx.x * 32 + (t >> 3);

    for (int i = t; i < SS; i += 256) {
        int li = (i >> 7) * 132 + (i & 127);
        sx[li] = xyz2[((size_t)b * 3 + 0) * SS + i];
        sy[li] = xyz2[((size_t)b * 3 + 1) * SS + i];
        sz[li] = xyz2[((size_t)b * 3 + 2) * SS + i];
    }
    __syncthreads();

    const float px = xyz1[((size_t)b * 3 + 0) * NN + n];
    const float py = xyz1[((size_t)b * 3 + 1) * NN + n];
    const float pz = xyz1[((size_t)b * 3 + 2) * NN + n];

    // two independent chains: A = even candidates, B = odd candidates
    float aD0 = 3.4e38f, aD1 = 3.4e38f, aD2 = 3.4e38f;
    int   aJ0 = 0, aJ1 = 0, aJ2 = 0;
    float bD0 = 3.4e38f, bD1 = 3.4e38f, bD2 = 3.4e38f;
    int   bJ0 = 0, bJ1 = 0, bJ2 = 0;

    const float* cx = sx + chunk * 132;
    const float* cy = sy + chunk * 132;
    const float* cz = sz + chunk * 132;
    const int sbase = chunk * 128;
#pragma unroll 4
    for (int s4 = 0; s4 < 32; ++s4) {
        float4 xs = *(const float4*)(cx + s4 * 4);
        float4 ys = *(const float4*)(cy + s4 * 4);
        float4 zs = *(const float4*)(cz + s4 * 4);
        int s = sbase + s4 * 4;
        { float dx=px-xs.x, dy=py-ys.x, dz=pz-zs.x; float d=dx*dx+dy*dy+dz*dz; UPD6(d, s+0, aD0,aD1,aD2,aJ0,aJ1,aJ2); }
        { float dx=px-xs.y, dy=py-ys.y, dz=pz-zs.y; float d=dx*dx+dy*dy+dz*dz; UPD6(d, s+1, bD0,bD1,bD2,bJ0,bJ1,bJ2); }
        { float dx=px-xs.z, dy=py-ys.z, dz=pz-zs.z; float d=dx*dx+dy*dy+dz*dz; UPD6(d, s+2, aD0,aD1,aD2,aJ0,aJ1,aJ2); }
        { float dx=px-xs.w, dy=py-ys.w, dz=pz-zs.w; float d=dx*dx+dy*dy+dz*dz; UPD6(d, s+3, bD0,bD1,bD2,bJ0,bJ1,bJ2); }
    }

    // in-thread merge of the two sorted triples (exact (d,s) stable order)
    float d0v, d1v, d2v; int j0, j1, j2;
    {
        bool c0 = LTE(aD0, aJ0, bD0, bJ0);
        d0v = c0 ? aD0 : bD0;  j0 = c0 ? aJ0 : bJ0;
        float na0 = c0 ? aD1 : aD0, na1 = c0 ? aD2 : aD1;
        int   nx0 = c0 ? aJ1 : aJ0, nx1 = c0 ? aJ2 : aJ1;
        float nb0 = c0 ? bD0 : bD1, nb1 = c0 ? bD1 : bD2;
        int   ny0 = c0 ? bJ0 : bJ1, ny1 = c0 ? bJ1 : bJ2;
        bool c1 = LTE(na0, nx0, nb0, ny0);
        d1v = c1 ? na0 : nb0;  j1 = c1 ? nx0 : ny0;
        float ma0 = c1 ? na1 : na0;  int mx0 = c1 ? nx1 : nx0;
        float mb0 = c1 ? nb0 : nb1;  int my0 = c1 ? ny0 : ny1;
        bool c2 = LTE(ma0, mx0, mb0, my0);
        d2v = c2 ? ma0 : mb0;  j2 = c2 ? mx0 : my0;
    }

    // merge across the 8 chunk lanes (lower chunk = lower s wins ties via <=)
#pragma unroll
    for (int r = 1; r <= 4; r <<= 1) {
        float e0 = __shfl_xor(d0v, r), e1 = __shfl_xor(d1v, r), e2 = __shfl_xor(d2v, r);
        int   k0 = __shfl_xor(j0, r),  k1 = __shfl_xor(j1, r),  k2 = __shfl_xor(j2, r);
        bool ownlow = ((t & r) == 0);
        float a0 = ownlow ? d0v : e0, a1 = ownlow ? d1v : e1, a2 = ownlow ? d2v : e2;
        int   x0 = ownlow ? j0 : k0,  x1 = ownlow ? j1 : k1,  x2 = ownlow ? j2 : k2;
        float b0 = ownlow ? e0 : d0v, b1 = ownlow ? e1 : d1v, b2 = ownlow ? e2 : d2v;
        int   y0 = ownlow ? k0 : j0,  y1 = ownlow ? k1 : j1,  y2 = ownlow ? k2 : j2;
        bool c0 = a0 <= b0;
        d0v = c0 ? a0 : b0;  j0 = c0 ? x0 : y0;
        float na0 = c0 ? a1 : a0, na1 = c0 ? a2 : a1;
        int   nx0 = c0 ? x1 : x0, nx1 = c0 ? x2 : x1;
        float nb0 = c0 ? b0 : b1, nb1 = c0 ? b1 : b2;
        int   ny0 = c0 ? y0 : y1, ny1 = c0 ? y1 : y2;
        bool c1 = na0 <= nb0;
        d1v = c1 ? na0 : nb0;  j1 = c1 ? nx0 : ny0;
        float ma0 = c1 ? na1 : na0;  int mx0 = c1 ? nx1 : nx0;
        float mb0 = c1 ? nb0 : nb1;  int my0 = c1 ? ny0 : ny1;
        bool c2 = ma0 <= mb0;
        d2v = c2 ? ma0 : mb0;  j2 = c2 ? mx0 : my0;
    }

    if (chunk == 0) {
        // weights: distances to s=0,1,2 (faithful to reference's unsorted-column bug)
        float dd[3];
#pragma unroll
        for (int k = 0; k < 3; ++k) {
            float dx = px - sx[k], dy = py - sy[k], dz = pz - sz[k];
            float d = dx*dx + dy*dy + dz*dz;
            dd[k] = fmaxf(d, 1e-10f);
        }
        float r0 = 1.f/dd[0], r1 = 1.f/dd[1], r2 = 1.f/dd[2];
        float inv = 1.f / (r0 + r1 + r2);
        size_t base = ((size_t)b * NN + n) * 3;
        idxb[base+0] = j0; idxb[base+1] = j1; idxb[base+2] = j2;
        wtb[base+0] = r0*inv; wtb[base+1] = r1*inv; wtb[base+2] = r2*inv;
    }
}

// ---------- K3: GEMM1 with interpolation fused into A staging ----------
// A[m][c]: c in [0,128) from P1T; c in [128,384) = sum_k w_k * P2T[idx_k][c-128]
__launch_bounds__(512, 1)
__global__ void gemm1_k(const unsigned short* __restrict__ P1T,
                        const unsigned short* __restrict__ P2T,
                        const int* __restrict__ idxb, const float* __restrict__ wtb,
                        const unsigned short* __restrict__ w0b,
                        unsigned short* __restrict__ h1, float* __restrict__ part1)
{
    __shared__ unsigned short Als[128 * 64];   // [row][k] bf16, XOR-swizzled
    __shared__ unsigned short Bls[256 * 64];
    __shared__ float lsum[2][256];
    __shared__ float lsq[2][256];

    const int t = threadIdx.x;
    const int wv = t >> 6, l = t & 63, g = l >> 4, lc = l & 15;
    const int wm = wv >> 2, wn = wv & 3;
    const int m0 = blockIdx.x * 128;
    const int b  = blockIdx.x >> 5;            // 32 blocks per batch
    const int sub = t & 7;

    // gather setup: thread owns row grow, 16-col window (t&3)
    const int grow = t >> 2;
    const size_t gb = ((size_t)(m0 + grow)) * 3;
    const int gi0 = idxb[gb], gi1 = idxb[gb+1], gi2 = idxb[gb+2];
    const float gw0 = wtb[gb], gw1 = wtb[gb+1], gw2 = wtb[gb+2];
    const char* gp0 = (const char*)(P2T + ((size_t)b * SS + gi0) * D2) + (t & 3) * 32;
    const char* gp1 = (const char*)(P2T + ((size_t)b * SS + gi1) * D2) + (t & 3) * 32;
    const char* gp2 = (const char*)(P2T + ((size_t)b * SS + gi2) * D2) + (t & 3) * 32;
    char* gdst = (char*)Als + grow * 128;
    const int gsw = (grow & 7) << 4;

    f32x4 acc[4][4];
#pragma unroll
    for (int i = 0; i < 4; ++i)
#pragma unroll
        for (int j = 0; j < 4; ++j) acc[i][j] = (f32x4){0.f, 0.f, 0.f, 0.f};

    for (int ks = 0; ks < 6; ++ks) {
        const int k0 = ks * 64;
        __syncthreads();
        if (ks < 2) {
#pragma unroll
            for (int q = 0; q < 2; ++q) {      // A from P1T via global_load_lds
                int row = q * 64 + (t >> 3);
                int bco = (sub * 16) ^ ((row & 7) << 4);
                const char* src = (const char*)P1T + (((size_t)(m0 + row)) * D1 + k0) * 2 + bco;
                char* dst = (char*)Als + (q * 512 + wv * 64) * 16;
                GLD16(src, dst);
            }
        } else {
            const int cgB = (ks - 2) * 128;    // byte offset of 64-col window in P2T row
#pragma unroll
            for (int h = 0; h < 2; ++h) {
                union { uint4 v; unsigned short s[8]; } a0, a1, a2, ov;
                a0.v = *(const uint4*)(gp0 + cgB + h * 16);
                a1.v = *(const uint4*)(gp1 + cgB + h * 16);
                a2.v = *(const uint4*)(gp2 + cgB + h * 16);
#pragma unroll
                for (int i = 0; i < 8; ++i)
                    ov.s[i] = f2b(gw0 * b2f(a0.s[i]) + gw1 * b2f(a1.s[i]) + gw2 * b2f(a2.s[i]));
                *(uint4*)(gdst + (((t & 3) * 32 + h * 16) ^ gsw)) = ov.v;
            }
        }
#pragma unroll
        for (int q = 0; q < 4; ++q) {      // B: 32KB
            int o = q * 64 + (t >> 3);
            int bco = (sub * 16) ^ ((o & 7) << 4);
            const char* src = (const char*)w0b + (((size_t)o) * CIN + k0) * 2 + bco;
            char* dst = (char*)Bls + (q * 512 + wv * 64) * 16;
            GLD16(src, dst);
        }
        __syncthreads();
#pragma unroll
        for (int kk = 0; kk < 2; ++kk) {
            short8 af[4], bfr[4];
#pragma unroll
            for (int fm = 0; fm < 4; ++fm) {
                int row = wm * 64 + fm * 16 + lc;
                int bcol = kk * 64 + g * 16;
                af[fm] = *(const short8*)((const char*)Als + row * 128 + (bcol ^ ((row & 7) << 4)));
            }
#pragma unroll
            for (int fn = 0; fn < 4; ++fn) {
                int o = wn * 64 + fn * 16 + lc;
                int bcol = kk * 64 + g * 16;
                bfr[fn] = *(const short8*)((const char*)Bls + o * 128 + (bcol ^ ((o & 7) << 4)));
            }
#pragma unroll
            for (int fm = 0; fm < 4; ++fm)
#pragma unroll
                for (int fn = 0; fn < 4; ++fn)
                    acc[fm][fn] = __builtin_amdgcn_mfma_f32_16x16x32_bf16(af[fm], bfr[fn], acc[fm][fn], 0, 0, 0);
        }
    }

    float s1[4] = {0,0,0,0}, s2v[4] = {0,0,0,0};
#pragma unroll
    for (int fm = 0; fm < 4; ++fm)
#pragma unroll
        for (int fn = 0; fn < 4; ++fn) {
            int row = m0 + wm * 64 + fm * 16 + g * 4;
            int col = wn * 64 + fn * 16 + lc;
#pragma unroll
            for (int j = 0; j < 4; ++j) {
                float v = acc[fm][fn][j];
                h1[((size_t)(row + j)) * C0 + col] = f2b(v);
                s1[fn] += v; s2v[fn] += v * v;
            }
        }
#pragma unroll
    for (int fn = 0; fn < 4; ++fn) {
        s1[fn] += __shfl_xor(s1[fn], 16); s1[fn] += __shfl_xor(s1[fn], 32);
        s2v[fn] += __shfl_xor(s2v[fn], 16); s2v[fn] += __shfl_xor(s2v[fn], 32);
    }
    if (l < 16) {
#pragma unroll
        for (int fn = 0; fn < 4; ++fn) {
            lsum[wm][wn * 64 + fn * 16 + l] = s1[fn];
            lsq[wm][wn * 64 + fn * 16 + l] = s2v[fn];
        }
    }
    __syncthreads();
    if (t < 256) {
        part1[(size_t)t * NBLK + blockIdx.x]        = lsum[0][t] + lsum[1][t];
        part1[(size_t)(C0 + t) * NBLK + blockIdx.x] = lsq[0][t] + lsq[1][t];
    }
}

// ---------- stats: one wave per channel, coalesced [channel][block] reads ----------
__global__ void stats_k(const float* __restrict__ part, int nblk, int C,
                        const float* __restrict__ gam, const float* __restrict__ bet,
                        float* __restrict__ sc, float* __restrict__ sh)
{
    const int w = threadIdx.x >> 6, l = threadIdx.x & 63;
    const int o = blockIdx.x * 4 + w;
    if (o >= C) return;
    float s = 0.f, q = 0.f;
    for (int i = l; i < nblk; i += 64) {
        s += part[(size_t)o * nblk + i];
        q += part[(size_t)(C + o) * nblk + i];
    }
#pragma unroll
    for (int r = 32; r; r >>= 1) { s += __shfl_xor(s, r); q += __shfl_xor(q, r); }
    if (l == 0) {
        const float inv = 1.0f / (float)MM;
        float mean = s * inv;
        float var = q * inv - mean * mean;
        float scale = gam[o] * rsqrtf(var + 1e-5f);
        sc[o] = scale;
        sh[o] = bet[o] - mean * scale;
    }
}

// ---------- K5: GEMM2 with BN1+ReLU fused into A staging ----------
__launch_bounds__(256, 1)
__global__ void gemm2_k(const unsigned short* __restrict__ h1, const unsigned short* __restrict__ w1b,
                        const float* __restrict__ sc1, const float* __restrict__ sh1,
                        unsigned short* __restrict__ h2, float* __restrict__ part2)
{
    __shared__ unsigned short Als[128 * 64];
    __shared__ unsigned short Bls[128 * 64];
    __shared__ float scl[256], shl[256];
    __shared__ float lsum[2][128];
    __shared__ float lsq[2][128];

    const int t = threadIdx.x;
    const int wv = t >> 6, l = t & 63, g = l >> 4, lc = l & 15;
    const int wm = wv >> 1, wn = wv & 1;
    const int m0 = blockIdx.x * 128;
    const int sub = t & 7;

    scl[t] = sc1[t]; shl[t] = sh1[t];

    f32x4 acc[4][4];
#pragma unroll
    for (int i = 0; i < 4; ++i)
#pragma unroll
        for (int j = 0; j < 4; ++j) acc[i][j] = (f32x4){0.f, 0.f, 0.f, 0.f};

    for (int ks = 0; ks < 4; ++ks) {
        const int k0 = ks * 64;
        __syncthreads();
        uint4 r[4];
#pragma unroll
        for (int q = 0; q < 4; ++q) {
            int row = q * 32 + (t >> 3);
            r[q] = *(const uint4*)((const char*)h1 + (((size_t)(m0 + row)) * C0 + k0) * 2 + sub * 16);
        }
#pragma unroll
        for (int q = 0; q < 4; ++q) {
            int row = q * 32 + (t >> 3);
            union { uint4 v; unsigned short s[8]; } u, ov;
            u.v = r[q];
#pragma unroll
            for (int i = 0; i < 8; ++i) {
                int k = k0 + sub * 8 + i;
                float f = b2f(u.s[i]);
                ov.s[i] = f2b(fmaxf(0.0f, fmaf(scl[k], f, shl[k])));
            }
            *(uint4*)((char*)Als + row * 128 + ((sub * 16) ^ ((row & 7) << 4))) = ov.v;
        }
#pragma unroll
        for (int q = 0; q < 4; ++q) {
            int o = q * 32 + (t >> 3);
            int bco = (sub * 16) ^ ((o & 7) << 4);
            const char* src = (const char*)w1b + (((size_t)o) * C0 + k0) * 2 + bco;
            char* dst = (char*)Bls + (q * 256 + wv * 64) * 16;
            GLD16(src, dst);
        }
        __syncthreads();
#pragma unroll
        for (int kk = 0; kk < 2; ++kk) {
            short8 af[4], bfr[4];
#pragma unroll
            for (int fm = 0; fm < 4; ++fm) {
                int row = wm * 64 + fm * 16 + lc;
                int bcol = kk * 64 + g * 16;
                af[fm] = *(const short8*)((const char*)Als + row * 128 + (bcol ^ ((row & 7) << 4)));
            }
#pragma unroll
            for (int fn = 0; fn < 4; ++fn) {
                int o = wn * 64 + fn * 16 + lc;
                int bcol = kk * 64 + g * 16;
                bfr[fn] = *(const short8*)((const char*)Bls + o * 128 + (bcol ^ ((o & 7) << 4)));
            }
#pragma unroll
            for (int fm = 0; fm < 4; ++fm)
#pragma unroll
                for (int fn = 0; fn < 4; ++fn)
                    acc[fm][fn] = __builtin_amdgcn_mfma_f32_16x16x32_bf16(af[fm], bfr[fn], acc[fm][fn], 0, 0, 0);
        }
    }

    float s1[4] = {0,0,0,0}, s2v[4] = {0,0,0,0};
#pragma unroll
    for (int fm = 0; fm < 4; ++fm)
#pragma unroll
        for (int fn = 0; fn < 4; ++fn) {
            int row = m0 + wm * 64 + fm * 16 + g * 4;
            int col = wn * 64 + fn * 16 + lc;
#pragma unroll
            for (int j = 0; j < 4; ++j) {
                float v = acc[fm][fn][j];
                h2[((size_t)(row + j)) * C1 + col] = f2b(v);
                s1[fn] += v; s2v[fn] += v * v;
            }
        }
#pragma unroll
    for (int fn = 0; fn < 4; ++fn) {
        s1[fn] += __shfl_xor(s1[fn], 16); s1[fn] += __shfl_xor(s1[fn], 32);
        s2v[fn] += __shfl_xor(s2v[fn], 16); s2v[fn] += __shfl_xor(s2v[fn], 32);
    }
    if (l < 16) {
#pragma unroll
        for (int fn = 0; fn < 4; ++fn) {
            lsum[wm][wn * 64 + fn * 16 + l] = s1[fn];
            lsq[wm][wn * 64 + fn * 16 + l] = s2v[fn];
        }
    }
    __syncthreads();
    if (t < 128) {
        part2[(size_t)t * NBLK + blockIdx.x]        = lsum[0][t] + lsum[1][t];
        part2[(size_t)(C1 + t) * NBLK + blockIdx.x] = lsq[0][t] + lsq[1][t];
    }
}

// ---------- K7: final BN2+ReLU + transpose [b,n,o] -> [b,o,n] f32 ----------
__global__ void finalize_k(const unsigned short* __restrict__ h2,
                           const float* __restrict__ sc, const float* __restrict__ sh,
                           float* __restrict__ out)
{
    __shared__ float tile[64][65];
    const int b = blockIdx.z, o0 = blockIdx.y * 64, n0 = blockIdx.x * 64;
    const int t = threadIdx.x, j = t & 63, i4 = t >> 6;
    const float scv = sc[o0 + j], shv = sh[o0 + j];
#pragma unroll
    for (int p = 0; p < 64; p += 4) {
        int ni = p + i4;
        float f = b2f(h2[((size_t)b * NN + n0 + ni) * C1 + o0 + j]);
        tile[ni][j] = fmaxf(0.0f, fmaf(scv, f, shv));
    }
    __syncthreads();
#pragma unroll
    for (int p = 0; p < 64; p += 4) {
        int oi = p + i4;
        out[((size_t)(b * C1 + o0 + oi)) * NN + n0 + j] = tile[j][oi];
    }
}

// ---------- launch ----------
extern "C" void kernel_launch(void* const* d_in, const int* in_sizes, int n_in,
                              void* d_out, int out_size, void* d_ws, size_t ws_size,
                              hipStream_t stream)
{
    const float* xyz1    = (const float*)d_in[0];
    const float* xyz2    = (const float*)d_in[1];
    const float* points1 = (const float*)d_in[2];
    const float* points2 = (const float*)d_in[3];
    const float* w0      = (const float*)d_in[4];
    const float* g0      = (const float*)d_in[6];
    const float* be0     = (const float*)d_in[7];
    const float* w1      = (const float*)d_in[8];
    const float* g1      = (const float*)d_in[10];
    const float* be1     = (const float*)d_in[11];
    float* out = (float*)d_out;
    char* ws = (char*)d_ws;

    unsigned short* P1T = (unsigned short*)(ws + 0);           // 65536*128*2 = 16777216
    unsigned short* h1  = (unsigned short*)(ws + 16777216);    // 65536*256*2 = 33554432
    unsigned short* P2T = (unsigned short*)(ws + 50331648);    // 16*1024*256*2 = 8388608
    unsigned short* h2  = (unsigned short*)(ws + 58720256);    // 65536*128*2 = 16777216
    int*   idxb  = (int*)  (ws + 75497472);                    // 786432
    float* wtb   = (float*)(ws + 76283904);                    // 786432
    unsigned short* w0b = (unsigned short*)(ws + 77070336);    // 196608
    unsigned short* w1b = (unsigned short*)(ws + 77266944);    // 65536
    float* part1 = (float*)(ws + 77332480);                    // 1048576
    float* part2 = (float*)(ws + 78381056);                    // 524288
    float* sc1   = (float*)(ws + 78905344);
    float* sh1   = (float*)(ws + 78906368);
    float* sc2   = (float*)(ws + 78907392);
    float* sh2   = (float*)(ws + 78908416);
    // total ws needed: ~79 MB

    transpose_cast_k<<<dim3(NN/64, D1/64, BB), 256, 0, stream>>>(points1, P1T, D1, NN, D1);
    transpose_cast_k<<<dim3(SS/64, D2/64, BB), 256, 0, stream>>>(points2, P2T, D2, SS, D2);
    cvtw_k<<<(C0*CIN)/256, 256, 0, stream>>>(w0, w1, w0b, w1b);
    knn_k<<<dim3(NN/32, BB), 256, 0, stream>>>(xyz1, xyz2, idxb, wtb);
    gemm1_k<<<MM/128, 512, 0, stream>>>(P1T, P2T, idxb, wtb, w0b, h1, part1);
    stats_k<<<C0/4, 256, 0, stream>>>(part1, NBLK, C0, g0, be0, sc1, sh1);
    gemm2_k<<<MM/128, 256, 0, stream>>>(h1, w1b, sc1, sh1, h2, part2);
    stats_k<<<C1/4, 256, 0, stream>>>(part2, NBLK, C1, g1, be1, sc2, sh2);
    finalize_k<<<dim3(NN/64, C1/64, BB), 256, 0, stream>>>(h2, sc2, sh2, out);
}

// Round 5
// 117.397 us; speedup vs baseline: 1.9154x; 1.0739x over previous
//
#include <hip/hip_runtime.h>
#include <cstdint>
#include <cstddef>

// ---------- problem constants ----------
#define BB   16
#define NN   4096
#define SS   1024
#define D1   128
#define D2   256
#define CIN  384
#define C0   256
#define C1   128
#define MM   (BB*NN)          // 65536
#define NBLK (MM/128)         // 512 gemm blocks

typedef __attribute__((ext_vector_type(8))) short short8;
typedef __attribute__((ext_vector_type(4))) float f32x4;

__device__ __forceinline__ float b2f(unsigned short h) {
    union { unsigned int u; float f; } x; x.u = ((unsigned int)h) << 16; return x.f;
}
__device__ __forceinline__ unsigned short f2b(float f) {
    union { float f; unsigned int u; } x; x.f = f;
    unsigned int r = x.u + 0x7FFFu + ((x.u >> 16) & 1u);
    return (unsigned short)(r >> 16);
}

#define GLD16(g, l) __builtin_amdgcn_global_load_lds( \
    (const __attribute__((address_space(1))) void*)(g), \
    (__attribute__((address_space(3))) void*)(l), 16, 0, 0)

// ---------- mega front kernel: knn + 2 transposes + weight cvt, role-interleaved ----------
// groups of 86 blocks: 32 knn + 32 P1T-transpose + 16 P2T-transpose + 6 cvtw; 64 groups.
// Rationale: knn is VALU-bound (HBM ~0.5%), transposes are HBM-bound; interleaving
// block roles puts both on each CU so the VALU and memory pipes overlap (m114).

// sorted top-3 insert: values via min/med3, indices via 3 cmp + 5 sel.
#define UPD6(dd, ss, D0, D1v, D2v, J0, J1, J2) do { \
    bool ca = (dd) < D0, cb = (dd) < D1v, cc = (dd) < D2v; \
    float m1 = __builtin_amdgcn_fmed3f((dd), D0, D1v); \
    float m2 = __builtin_amdgcn_fmed3f((dd), D1v, D2v); \
    int u1 = ca ? J0 : (ss); \
    int u2 = cb ? J1 : (ss); \
    D0 = fminf((dd), D0); \
    J2 = cc ? u2 : J2; \
    J1 = cb ? u1 : J1; \
    J0 = ca ? (ss) : J0; \
    D1v = m1; D2v = m2; \
} while (0)

#define LTE(x, xj, y, yj) ((x) < (y) || ((x) == (y) && (xj) < (yj)))

__device__ __forceinline__ void knn_body(const float* __restrict__ xyz1,
                                         const float* __restrict__ xyz2,
                                         int* __restrict__ idxb, float* __restrict__ wtb,
                                         int rb, int t, char* smem)
{
    float* sx = (float*)smem;
    float* sy = sx + 8 * 132;
    float* sz = sy + 8 * 132;
    const int b = rb >> 7;            // 128 blocks per batch
    const int bx = rb & 127;
    const int chunk = t & 7;
    const int n = bx * 32 + (t >> 3);

    for (int i = t; i < SS; i += 256) {
        int li = (i >> 7) * 132 + (i & 127);
        sx[li] = xyz2[((size_t)b * 3 + 0) * SS + i];
        sy[li] = xyz2[((size_t)b * 3 + 1) * SS + i];
        sz[li] = xyz2[((size_t)b * 3 + 2) * SS + i];
    }
    __syncthreads();

    const float px = xyz1[((size_t)b * 3 + 0) * NN + n];
    const float py = xyz1[((size_t)b * 3 + 1) * NN + n];
    const float pz = xyz1[((size_t)b * 3 + 2) * NN + n];

    float aD0 = 3.4e38f, aD1 = 3.4e38f, aD2 = 3.4e38f;
    int   aJ0 = 0, aJ1 = 0, aJ2 = 0;
    float bD0 = 3.4e38f, bD1 = 3.4e38f, bD2 = 3.4e38f;
    int   bJ0 = 0, bJ1 = 0, bJ2 = 0;

    const float* cx = sx + chunk * 132;
    const float* cy = sy + chunk * 132;
    const float* cz = sz + chunk * 132;
    const int sbase = chunk * 128;
#pragma unroll 4
    for (int s4 = 0; s4 < 32; ++s4) {
        float4 xs = *(const float4*)(cx + s4 * 4);
        float4 ys = *(const float4*)(cy + s4 * 4);
        float4 zs = *(const float4*)(cz + s4 * 4);
        int s = sbase + s4 * 4;
        { float dx=px-xs.x, dy=py-ys.x, dz=pz-zs.x; float d=dx*dx+dy*dy+dz*dz; UPD6(d, s+0, aD0,aD1,aD2,aJ0,aJ1,aJ2); }
        { float dx=px-xs.y, dy=py-ys.y, dz=pz-zs.y; float d=dx*dx+dy*dy+dz*dz; UPD6(d, s+1, bD0,bD1,bD2,bJ0,bJ1,bJ2); }
        { float dx=px-xs.z, dy=py-ys.z, dz=pz-zs.z; float d=dx*dx+dy*dy+dz*dz; UPD6(d, s+2, aD0,aD1,aD2,aJ0,aJ1,aJ2); }
        { float dx=px-xs.w, dy=py-ys.w, dz=pz-zs.w; float d=dx*dx+dy*dy+dz*dz; UPD6(d, s+3, bD0,bD1,bD2,bJ0,bJ1,bJ2); }
    }

    // in-thread merge of the two sorted triples (exact (d,s) stable order)
    float d0v, d1v, d2v; int j0, j1, j2;
    {
        bool c0 = LTE(aD0, aJ0, bD0, bJ0);
        d0v = c0 ? aD0 : bD0;  j0 = c0 ? aJ0 : bJ0;
        float na0 = c0 ? aD1 : aD0, na1 = c0 ? aD2 : aD1;
        int   nx0 = c0 ? aJ1 : aJ0, nx1 = c0 ? aJ2 : aJ1;
        float nb0 = c0 ? bD0 : bD1, nb1 = c0 ? bD1 : bD2;
        int   ny0 = c0 ? bJ0 : bJ1, ny1 = c0 ? bJ1 : bJ2;
        bool c1 = LTE(na0, nx0, nb0, ny0);
        d1v = c1 ? na0 : nb0;  j1 = c1 ? nx0 : ny0;
        float ma0 = c1 ? na1 : na0;  int mx0 = c1 ? nx1 : nx0;
        float mb0 = c1 ? nb0 : nb1;  int my0 = c1 ? ny0 : ny1;
        bool c2 = LTE(ma0, mx0, mb0, my0);
        d2v = c2 ? ma0 : mb0;  j2 = c2 ? mx0 : my0;
    }

    // merge across the 8 chunk lanes (lower chunk = lower s wins ties via <=)
#pragma unroll
    for (int r = 1; r <= 4; r <<= 1) {
        float e0 = __shfl_xor(d0v, r), e1 = __shfl_xor(d1v, r), e2 = __shfl_xor(d2v, r);
        int   k0 = __shfl_xor(j0, r),  k1 = __shfl_xor(j1, r),  k2 = __shfl_xor(j2, r);
        bool ownlow = ((t & r) == 0);
        float a0 = ownlow ? d0v : e0, a1 = ownlow ? d1v : e1, a2 = ownlow ? d2v : e2;
        int   x0 = ownlow ? j0 : k0,  x1 = ownlow ? j1 : k1,  x2 = ownlow ? j2 : k2;
        float b0 = ownlow ? e0 : d0v, b1 = ownlow ? e1 : d1v, b2 = ownlow ? e2 : d2v;
        int   y0 = ownlow ? k0 : j0,  y1 = ownlow ? k1 : j1,  y2 = ownlow ? k2 : j2;
        bool c0 = a0 <= b0;
        d0v = c0 ? a0 : b0;  j0 = c0 ? x0 : y0;
        float na0 = c0 ? a1 : a0, na1 = c0 ? a2 : a1;
        int   nx0 = c0 ? x1 : x0, nx1 = c0 ? x2 : x1;
        float nb0 = c0 ? b0 : b1, nb1 = c0 ? b1 : b2;
        int   ny0 = c0 ? y0 : y1, ny1 = c0 ? y1 : y2;
        bool c1 = na0 <= nb0;
        d1v = c1 ? na0 : nb0;  j1 = c1 ? nx0 : ny0;
        float ma0 = c1 ? na1 : na0;  int mx0 = c1 ? nx1 : nx0;
        float mb0 = c1 ? nb0 : nb1;  int my0 = c1 ? ny0 : ny1;
        bool c2 = ma0 <= mb0;
        d2v = c2 ? ma0 : mb0;  j2 = c2 ? mx0 : my0;
    }

    if (chunk == 0) {
        // weights: distances to s=0,1,2 (faithful to reference's unsorted-column bug)
        float dd[3];
#pragma unroll
        for (int k = 0; k < 3; ++k) {
            float dx = px - sx[k], dy = py - sy[k], dz = pz - sz[k];
            float d = dx*dx + dy*dy + dz*dz;
            dd[k] = fmaxf(d, 1e-10f);
        }
        float r0 = 1.f/dd[0], r1 = 1.f/dd[1], r2 = 1.f/dd[2];
        float inv = 1.f / (r0 + r1 + r2);
        size_t base = ((size_t)b * NN + n) * 3;
        idxb[base+0] = j0; idxb[base+1] = j1; idxb[base+2] = j2;
        wtb[base+0] = r0*inv; wtb[base+1] = r1*inv; wtb[base+2] = r2*inv;
    }
}

__device__ __forceinline__ void transpose_body(const float* __restrict__ src,
                                               unsigned short* __restrict__ dst,
                                               int C, int Np, int dstStride,
                                               int b, int cblk, int nblk, int t, char* smem)
{
    float (*tile)[65] = (float(*)[65])smem;
    const int c0 = cblk * 64, n0 = nblk * 64;
    const int j = t & 63, i4 = t >> 6;
#pragma unroll
    for (int p = 0; p < 64; p += 4) {
        int ci = p + i4;
        tile[ci][j] = src[((size_t)b * C + c0 + ci) * Np + n0 + j];
    }
    __syncthreads();
#pragma unroll
    for (int p = 0; p < 64; p += 4) {
        int ni = p + i4;
        dst[((size_t)b * Np + n0 + ni) * dstStride + c0 + j] = f2b(tile[j][ni]);
    }
}

__global__ __launch_bounds__(256) void mega_front_k(
    const float* __restrict__ xyz1, const float* __restrict__ xyz2,
    const float* __restrict__ points1, const float* __restrict__ points2,
    const float* __restrict__ w0, const float* __restrict__ w1,
    unsigned short* __restrict__ P1T, unsigned short* __restrict__ P2T,
    unsigned short* __restrict__ w0b, unsigned short* __restrict__ w1b,
    int* __restrict__ idxb, float* __restrict__ wtb)
{
    __shared__ __align__(16) char smem[16640];
    const unsigned bid = blockIdx.x;
    const int g = bid / 86, r = bid % 86;
    const int t = threadIdx.x;

    if (r < 32) {
        knn_body(xyz1, xyz2, idxb, wtb, g * 32 + r, t, smem);
    } else if (r < 64) {
        int rb = g * 32 + (r - 32);              // 2048 blocks: (64 nblk, 2 cblk, 16 b)
        transpose_body(points1, P1T, D1, NN, D1,
                       rb >> 7, (rb >> 6) & 1, rb & 63, t, smem);
    } else if (r < 80) {
        int rb = g * 16 + (r - 64);              // 1024 blocks: (16 nblk, 4 cblk, 16 b)
        transpose_body(points2, P2T, D2, SS, D2,
                       rb >> 6, (rb >> 4) & 3, rb & 15, t, smem);
    } else {
        int rb = g * 6 + (r - 80);               // 384 blocks
        int i = rb * 256 + t;
        if (i < C0 * CIN) w0b[i] = f2b(w0[i]);
        if (i < C1 * C0)  w1b[i] = f2b(w1[i]);
    }
}

// ---------- K3: GEMM1 with interpolation fused into A staging ----------
__launch_bounds__(512, 1)
__global__ void gemm1_k(const unsigned short* __restrict__ P1T,
                        const unsigned short* __restrict__ P2T,
                        const int* __restrict__ idxb, const float* __restrict__ wtb,
                        const unsigned short* __restrict__ w0b,
                        unsigned short* __restrict__ h1, float* __restrict__ part1)
{
    __shared__ unsigned short Als[128 * 64];   // [row][k] bf16, XOR-swizzled
    __shared__ unsigned short Bls[256 * 64];
    __shared__ float lsum[2][256];
    __shared__ float lsq[2][256];

    const int t = threadIdx.x;
    const int wv = t >> 6, l = t & 63, g = l >> 4, lc = l & 15;
    const int wm = wv >> 2, wn = wv & 3;
    const int m0 = blockIdx.x * 128;
    const int b  = blockIdx.x >> 5;            // 32 blocks per batch
    const int sub = t & 7;

    const int grow = t >> 2;
    const size_t gb = ((size_t)(m0 + grow)) * 3;
    const int gi0 = idxb[gb], gi1 = idxb[gb+1], gi2 = idxb[gb+2];
    const float gw0 = wtb[gb], gw1 = wtb[gb+1], gw2 = wtb[gb+2];
    const char* gp0 = (const char*)(P2T + ((size_t)b * SS + gi0) * D2) + (t & 3) * 32;
    const char* gp1 = (const char*)(P2T + ((size_t)b * SS + gi1) * D2) + (t & 3) * 32;
    const char* gp2 = (const char*)(P2T + ((size_t)b * SS + gi2) * D2) + (t & 3) * 32;
    char* gdst = (char*)Als + grow * 128;
    const int gsw = (grow & 7) << 4;

    f32x4 acc[4][4];
#pragma unroll
    for (int i = 0; i < 4; ++i)
#pragma unroll
        for (int j = 0; j < 4; ++j) acc[i][j] = (f32x4){0.f, 0.f, 0.f, 0.f};

    for (int ks = 0; ks < 6; ++ks) {
        const int k0 = ks * 64;
        __syncthreads();
        if (ks < 2) {
#pragma unroll
            for (int q = 0; q < 2; ++q) {      // A from P1T via global_load_lds
                int row = q * 64 + (t >> 3);
                int bco = (sub * 16) ^ ((row & 7) << 4);
                const char* src = (const char*)P1T + (((size_t)(m0 + row)) * D1 + k0) * 2 + bco;
                char* dst = (char*)Als + (q * 512 + wv * 64) * 16;
                GLD16(src, dst);
            }
        } else {
            const int cgB = (ks - 2) * 128;
#pragma unroll
            for (int h = 0; h < 2; ++h) {
                union { uint4 v; unsigned short s[8]; } a0, a1, a2, ov;
                a0.v = *(const uint4*)(gp0 + cgB + h * 16);
                a1.v = *(const uint4*)(gp1 + cgB + h * 16);
                a2.v = *(const uint4*)(gp2 + cgB + h * 16);
#pragma unroll
                for (int i = 0; i < 8; ++i)
                    ov.s[i] = f2b(gw0 * b2f(a0.s[i]) + gw1 * b2f(a1.s[i]) + gw2 * b2f(a2.s[i]));
                *(uint4*)(gdst + (((t & 3) * 32 + h * 16) ^ gsw)) = ov.v;
            }
        }
#pragma unroll
        for (int q = 0; q < 4; ++q) {      // B: 32KB
            int o = q * 64 + (t >> 3);
            int bco = (sub * 16) ^ ((o & 7) << 4);
            const char* src = (const char*)w0b + (((size_t)o) * CIN + k0) * 2 + bco;
            char* dst = (char*)Bls + (q * 512 + wv * 64) * 16;
            GLD16(src, dst);
        }
        __syncthreads();
#pragma unroll
        for (int kk = 0; kk < 2; ++kk) {
            short8 af[4], bfr[4];
#pragma unroll
            for (int fm = 0; fm < 4; ++fm) {
                int row = wm * 64 + fm * 16 + lc;
                int bcol = kk * 64 + g * 16;
                af[fm] = *(const short8*)((const char*)Als + row * 128 + (bcol ^ ((row & 7) << 4)));
            }
#pragma unroll
            for (int fn = 0; fn < 4; ++fn) {
                int o = wn * 64 + fn * 16 + lc;
                int bcol = kk * 64 + g * 16;
                bfr[fn] = *(const short8*)((const char*)Bls + o * 128 + (bcol ^ ((o & 7) << 4)));
            }
#pragma unroll
            for (int fm = 0; fm < 4; ++fm)
#pragma unroll
                for (int fn = 0; fn < 4; ++fn)
                    acc[fm][fn] = __builtin_amdgcn_mfma_f32_16x16x32_bf16(af[fm], bfr[fn], acc[fm][fn], 0, 0, 0);
        }
    }

    float s1[4] = {0,0,0,0}, s2v[4] = {0,0,0,0};
#pragma unroll
    for (int fm = 0; fm < 4; ++fm)
#pragma unroll
        for (int fn = 0; fn < 4; ++fn) {
            int row = m0 + wm * 64 + fm * 16 + g * 4;
            int col = wn * 64 + fn * 16 + lc;
#pragma unroll
            for (int j = 0; j < 4; ++j) {
                float v = acc[fm][fn][j];
                h1[((size_t)(row + j)) * C0 + col] = f2b(v);
                s1[fn] += v; s2v[fn] += v * v;
            }
        }
#pragma unroll
    for (int fn = 0; fn < 4; ++fn) {
        s1[fn] += __shfl_xor(s1[fn], 16); s1[fn] += __shfl_xor(s1[fn], 32);
        s2v[fn] += __shfl_xor(s2v[fn], 16); s2v[fn] += __shfl_xor(s2v[fn], 32);
    }
    if (l < 16) {
#pragma unroll
        for (int fn = 0; fn < 4; ++fn) {
            lsum[wm][wn * 64 + fn * 16 + l] = s1[fn];
            lsq[wm][wn * 64 + fn * 16 + l] = s2v[fn];
        }
    }
    __syncthreads();
    if (t < 256) {
        part1[(size_t)t * NBLK + blockIdx.x]        = lsum[0][t] + lsum[1][t];
        part1[(size_t)(C0 + t) * NBLK + blockIdx.x] = lsq[0][t] + lsq[1][t];
    }
}

// ---------- stats: one wave per channel, coalesced [channel][block] reads ----------
__global__ void stats_k(const float* __restrict__ part, int nblk, int C,
                        const float* __restrict__ gam, const float* __restrict__ bet,
                        float* __restrict__ sc, float* __restrict__ sh)
{
    const int w = threadIdx.x >> 6, l = threadIdx.x & 63;
    const int o = blockIdx.x * 4 + w;
    if (o >= C) return;
    float s = 0.f, q = 0.f;
    for (int i = l; i < nblk; i += 64) {
        s += part[(size_t)o * nblk + i];
        q += part[(size_t)(C + o) * nblk + i];
    }
#pragma unroll
    for (int r = 32; r; r >>= 1) { s += __shfl_xor(s, r); q += __shfl_xor(q, r); }
    if (l == 0) {
        const float inv = 1.0f / (float)MM;
        float mean = s * inv;
        float var = q * inv - mean * mean;
        float scale = gam[o] * rsqrtf(var + 1e-5f);
        sc[o] = scale;
        sh[o] = bet[o] - mean * scale;
    }
}

// ---------- K5: GEMM2 with BN1+ReLU fused into A staging ----------
__launch_bounds__(256, 1)
__global__ void gemm2_k(const unsigned short* __restrict__ h1, const unsigned short* __restrict__ w1b,
                        const float* __restrict__ sc1, const float* __restrict__ sh1,
                        unsigned short* __restrict__ h2, float* __restrict__ part2)
{
    __shared__ unsigned short Als[128 * 64];
    __shared__ unsigned short Bls[128 * 64];
    __shared__ float scl[256], shl[256];
    __shared__ float lsum[2][128];
    __shared__ float lsq[2][128];

    const int t = threadIdx.x;
    const int wv = t >> 6, l = t & 63, g = l >> 4, lc = l & 15;
    const int wm = wv >> 1, wn = wv & 1;
    const int m0 = blockIdx.x * 128;
    const int sub = t & 7;

    scl[t] = sc1[t]; shl[t] = sh1[t];

    f32x4 acc[4][4];
#pragma unroll
    for (int i = 0; i < 4; ++i)
#pragma unroll
        for (int j = 0; j < 4; ++j) acc[i][j] = (f32x4){0.f, 0.f, 0.f, 0.f};

    for (int ks = 0; ks < 4; ++ks) {
        const int k0 = ks * 64;
        __syncthreads();
        uint4 r[4];
#pragma unroll
        for (int q = 0; q < 4; ++q) {
            int row = q * 32 + (t >> 3);
            r[q] = *(const uint4*)((const char*)h1 + (((size_t)(m0 + row)) * C0 + k0) * 2 + sub * 16);
        }
#pragma unroll
        for (int q = 0; q < 4; ++q) {
            int row = q * 32 + (t >> 3);
            union { uint4 v; unsigned short s[8]; } u, ov;
            u.v = r[q];
#pragma unroll
            for (int i = 0; i < 8; ++i) {
                int k = k0 + sub * 8 + i;
                float f = b2f(u.s[i]);
                ov.s[i] = f2b(fmaxf(0.0f, fmaf(scl[k], f, shl[k])));
            }
            *(uint4*)((char*)Als + row * 128 + ((sub * 16) ^ ((row & 7) << 4))) = ov.v;
        }
#pragma unroll
        for (int q = 0; q < 4; ++q) {
            int o = q * 32 + (t >> 3);
            int bco = (sub * 16) ^ ((o & 7) << 4);
            const char* src = (const char*)w1b + (((size_t)o) * C0 + k0) * 2 + bco;
            char* dst = (char*)Bls + (q * 256 + wv * 64) * 16;
            GLD16(src, dst);
        }
        __syncthreads();
#pragma unroll
        for (int kk = 0; kk < 2; ++kk) {
            short8 af[4], bfr[4];
#pragma unroll
            for (int fm = 0; fm < 4; ++fm) {
                int row = wm * 64 + fm * 16 + lc;
                int bcol = kk * 64 + g * 16;
                af[fm] = *(const short8*)((const char*)Als + row * 128 + (bcol ^ ((row & 7) << 4)));
            }
#pragma unroll
            for (int fn = 0; fn < 4; ++fn) {
                int o = wn * 64 + fn * 16 + lc;
                int bcol = kk * 64 + g * 16;
                bfr[fn] = *(const short8*)((const char*)Bls + o * 128 + (bcol ^ ((o & 7) << 4)));
            }
#pragma unroll
            for (int fm = 0; fm < 4; ++fm)
#pragma unroll
                for (int fn = 0; fn < 4; ++fn)
                    acc[fm][fn] = __builtin_amdgcn_mfma_f32_16x16x32_bf16(af[fm], bfr[fn], acc[fm][fn], 0, 0, 0);
        }
    }

    float s1[4] = {0,0,0,0}, s2v[4] = {0,0,0,0};
#pragma unroll
    for (int fm = 0; fm < 4; ++fm)
#pragma unroll
        for (int fn = 0; fn < 4; ++fn) {
            int row = m0 + wm * 64 + fm * 16 + g * 4;
            int col = wn * 64 + fn * 16 + lc;
#pragma unroll
            for (int j = 0; j < 4; ++j) {
                float v = acc[fm][fn][j];
                h2[((size_t)(row + j)) * C1 + col] = f2b(v);
                s1[fn] += v; s2v[fn] += v * v;
            }
        }
#pragma unroll
    for (int fn = 0; fn < 4; ++fn) {
        s1[fn] += __shfl_xor(s1[fn], 16); s1[fn] += __shfl_xor(s1[fn], 32);
        s2v[fn] += __shfl_xor(s2v[fn], 16); s2v[fn] += __shfl_xor(s2v[fn], 32);
    }
    if (l < 16) {
#pragma unroll
        for (int fn = 0; fn < 4; ++fn) {
            lsum[wm][wn * 64 + fn * 16 + l] = s1[fn];
            lsq[wm][wn * 64 + fn * 16 + l] = s2v[fn];
        }
    }
    __syncthreads();
    if (t < 128) {
        part2[(size_t)t * NBLK + blockIdx.x]        = lsum[0][t] + lsum[1][t];
        part2[(size_t)(C1 + t) * NBLK + blockIdx.x] = lsq[0][t] + lsq[1][t];
    }
}

// ---------- K7: final BN2+ReLU + transpose [b,n,o] -> [b,o,n] f32 ----------
__global__ void finalize_k(const unsigned short* __restrict__ h2,
                           const float* __restrict__ sc, const float* __restrict__ sh,
                           float* __restrict__ out)
{
    __shared__ float tile[64][65];
    const int b = blockIdx.z, o0 = blockIdx.y * 64, n0 = blockIdx.x * 64;
    const int t = threadIdx.x, j = t & 63, i4 = t >> 6;
    const float scv = sc[o0 + j], shv = sh[o0 + j];
#pragma unroll
    for (int p = 0; p < 64; p += 4) {
        int ni = p + i4;
        float f = b2f(h2[((size_t)b * NN + n0 + ni) * C1 + o0 + j]);
        tile[ni][j] = fmaxf(0.0f, fmaf(scv, f, shv));
    }
    __syncthreads();
#pragma unroll
    for (int p = 0; p < 64; p += 4) {
        int oi = p + i4;
        out[((size_t)(b * C1 + o0 + oi)) * NN + n0 + j] = tile[j][oi];
    }
}

// ---------- launch ----------
extern "C" void kernel_launch(void* const* d_in, const int* in_sizes, int n_in,
                              void* d_out, int out_size, void* d_ws, size_t ws_size,
                              hipStream_t stream)
{
    const float* xyz1    = (const float*)d_in[0];
    const float* xyz2    = (const float*)d_in[1];
    const float* points1 = (const float*)d_in[2];
    const float* points2 = (const float*)d_in[3];
    const float* w0      = (const float*)d_in[4];
    const float* g0      = (const float*)d_in[6];
    const float* be0     = (const float*)d_in[7];
    const float* w1      = (const float*)d_in[8];
    const float* g1      = (const float*)d_in[10];
    const float* be1     = (const float*)d_in[11];
    float* out = (float*)d_out;
    char* ws = (char*)d_ws;

    unsigned short* P1T = (unsigned short*)(ws + 0);           // 16777216
    unsigned short* h1  = (unsigned short*)(ws + 16777216);    // 33554432
    unsigned short* P2T = (unsigned short*)(ws + 50331648);    // 8388608
    unsigned short* h2  = (unsigned short*)(ws + 58720256);    // 16777216
    int*   idxb  = (int*)  (ws + 75497472);                    // 786432
    float* wtb   = (float*)(ws + 76283904);                    // 786432
    unsigned short* w0b = (unsigned short*)(ws + 77070336);    // 196608
    unsigned short* w1b = (unsigned short*)(ws + 77266944);    // 65536
    float* part1 = (float*)(ws + 77332480);                    // 1048576
    float* part2 = (float*)(ws + 78381056);                    // 524288
    float* sc1   = (float*)(ws + 78905344);
    float* sh1   = (float*)(ws + 78906368);
    float* sc2   = (float*)(ws + 78907392);
    float* sh2   = (float*)(ws + 78908416);
    // total ws needed: ~79 MB

    mega_front_k<<<86 * 64, 256, 0, stream>>>(xyz1, xyz2, points1, points2, w0, w1,
                                              P1T, P2T, w0b, w1b, idxb, wtb);
    gemm1_k<<<MM/128, 512, 0, stream>>>(P1T, P2T, idxb, wtb, w0b, h1, part1);
    stats_k<<<C0/4, 256, 0, stream>>>(part1, NBLK, C0, g0, be0, sc1, sh1);
    gemm2_k<<<MM/128, 256, 0, stream>>>(h1, w1b, sc1, sh1, h2, part2);
    stats_k<<<C1/4, 256, 0, stream>>>(part2, NBLK, C1, g1, be1, sc2, sh2);
    finalize_k<<<dim3(NN/64, C1/64, BB), 256, 0, stream>>>(h2, sc2, sh2, out);
}

// Round 6
// 117.267 us; speedup vs baseline: 1.9175x; 1.0011x over previous
//
#include <hip/hip_runtime.h>
#include <cstdint>
#include <cstddef>

// ---------- problem constants ----------
#define BB   16
#define NN   4096
#define SS   1024
#define D1   128
#define D2   256
#define CIN  384
#define C0   256
#define C1   128
#define MM   (BB*NN)          // 65536
#define NBLK (MM/128)         // 512 gemm blocks

typedef __attribute__((ext_vector_type(8))) short short8;
typedef __attribute__((ext_vector_type(4))) float f32x4;

__device__ __forceinline__ float b2f(unsigned short h) {
    union { unsigned int u; float f; } x; x.u = ((unsigned int)h) << 16; return x.f;
}
__device__ __forceinline__ unsigned short f2b(float f) {
    union { float f; unsigned int u; } x; x.f = f;
    unsigned int r = x.u + 0x7FFFu + ((x.u >> 16) & 1u);
    return (unsigned short)(r >> 16);
}

#define GLD16(g, l) __builtin_amdgcn_global_load_lds( \
    (const __attribute__((address_space(1))) void*)(g), \
    (__attribute__((address_space(3))) void*)(l), 16, 0, 0)

// ---------- knn v3: scalar candidate stream + packed (d,idx) f64 keys ----------
// One wave = 64 query points scanning a wave-uniform candidate quarter (256 pts).
// Candidate coords come via the scalar pipe (uniform addresses); top-3 kept as
// doubles with hi32 = f32 distance bits, lo32 = index: for nonneg finite d this
// orders exactly by (d, s) lexicographic = the stable argsort order. Sorted
// insert = 5 v_min/max_f64, indices carried for free.
__device__ __forceinline__ void knn_body3(const float* __restrict__ xyz1,
                                          const float* __restrict__ xyz2,
                                          int* __restrict__ idxb, float* __restrict__ wtb,
                                          int rb, int t, char* smem)
{
    double* mrg = (double*)smem;           // [4][64][3]
    const int b    = rb >> 6;              // 64 blocks per batch
    const int lane = t & 63;
    const int n    = (rb & 63) * 64 + lane;
    const int wu   = __builtin_amdgcn_readfirstlane(t >> 6);   // wave id 0..3 (uniform)

    const float* qx = xyz2 + ((size_t)b * 3 + 0) * SS + wu * 256;
    const float* qy = xyz2 + ((size_t)b * 3 + 1) * SS + wu * 256;
    const float* qz = xyz2 + ((size_t)b * 3 + 2) * SS + wu * 256;

    const float px = xyz1[((size_t)b * 3 + 0) * NN + n];
    const float py = xyz1[((size_t)b * 3 + 1) * NN + n];
    const float pz = xyz1[((size_t)b * 3 + 2) * NN + n];

    const double INITK = __hiloint2double(0x7F7FFFFF, 0);
    double A0 = INITK, A1 = INITK, A2 = INITK;
    double B0 = INITK, B1 = INITK, B2 = INITK;
    const int sb = wu * 256;

#pragma unroll 4
    for (int s = 0; s < 256; s += 2) {
        {   // even candidates -> chain A
            float qxv = qx[s], qyv = qy[s], qzv = qz[s];
            float dx = px - qxv, dy = py - qyv, dz = pz - qzv;
            float d = dx*dx + dy*dy + dz*dz;
            double k = __hiloint2double(__float_as_int(d), sb + s);
            double t0 = fmin(k, A0), h0 = fmax(k, A0);
            double t1 = fmin(h0, A1), h1 = fmax(h0, A1);
            A2 = fmin(h1, A2); A0 = t0; A1 = t1;
        }
        {   // odd candidates -> chain B
            float qxv = qx[s+1], qyv = qy[s+1], qzv = qz[s+1];
            float dx = px - qxv, dy = py - qyv, dz = pz - qzv;
            float d = dx*dx + dy*dy + dz*dz;
            double k = __hiloint2double(__float_as_int(d), sb + s + 1);
            double t0 = fmin(k, B0), h0 = fmax(k, B0);
            double t1 = fmin(h0, B1), h1 = fmax(h0, B1);
            B2 = fmin(h1, B2); B0 = t0; B1 = t1;
        }
    }
    // in-lane merge of sorted triples A,B (keys unique -> order exact)
    double K0, K1, K2;
    {
        double y0 = fmax(A0, B0);
        K0 = fmin(A0, B0);
        double x1 = fmin(A1, B1);
        K1 = fmin(y0, x1);
        double z  = fmax(y0, x1);
        double x2 = fmin(A2, B2);
        K2 = fmin(z, x2);
    }
    if (wu > 0) {
        mrg[(wu * 64 + lane) * 3 + 0] = K0;
        mrg[(wu * 64 + lane) * 3 + 1] = K1;
        mrg[(wu * 64 + lane) * 3 + 2] = K2;
    }
    __syncthreads();
    if (wu == 0) {
#pragma unroll
        for (int q = 1; q < 4; ++q) {
            double C0d = mrg[(q * 64 + lane) * 3 + 0];
            double C1d = mrg[(q * 64 + lane) * 3 + 1];
            double C2d = mrg[(q * 64 + lane) * 3 + 2];
            double y0 = fmax(K0, C0d);
            K0 = fmin(K0, C0d);
            double x1 = fmin(K1, C1d);
            double nK1 = fmin(y0, x1);
            double z  = fmax(y0, x1);
            double x2 = fmin(K2, C2d);
            K2 = fmin(z, x2);
            K1 = nK1;
        }
        int j0 = __double2loint(K0), j1 = __double2loint(K1), j2 = __double2loint(K2);
        // weights: distances to s=0,1,2 (faithful to reference's unsorted-column bug)
        float dd0, dd1, dd2;
        { float dx=px-qx[0], dy=py-qy[0], dz=pz-qz[0]; dd0 = fmaxf(dx*dx+dy*dy+dz*dz, 1e-10f); }
        { float dx=px-qx[1], dy=py-qy[1], dz=pz-qz[1]; dd1 = fmaxf(dx*dx+dy*dy+dz*dz, 1e-10f); }
        { float dx=px-qx[2], dy=py-qy[2], dz=pz-qz[2]; dd2 = fmaxf(dx*dx+dy*dy+dz*dz, 1e-10f); }
        float r0 = 1.f/dd0, r1 = 1.f/dd1, r2 = 1.f/dd2;
        float inv = 1.f / (r0 + r1 + r2);
        size_t base = ((size_t)b * NN + n) * 3;
        idxb[base+0] = j0; idxb[base+1] = j1; idxb[base+2] = j2;
        wtb[base+0] = r0*inv; wtb[base+1] = r1*inv; wtb[base+2] = r2*inv;
    }
}

__device__ __forceinline__ void transpose_body(const float* __restrict__ src,
                                               unsigned short* __restrict__ dst,
                                               int C, int Np, int dstStride,
                                               int b, int cblk, int nblk, int t, char* smem)
{
    float (*tile)[65] = (float(*)[65])smem;
    const int c0 = cblk * 64, n0 = nblk * 64;
    const int j = t & 63, i4 = t >> 6;
#pragma unroll
    for (int p = 0; p < 64; p += 4) {
        int ci = p + i4;
        tile[ci][j] = src[((size_t)b * C + c0 + ci) * Np + n0 + j];
    }
    __syncthreads();
#pragma unroll
    for (int p = 0; p < 64; p += 4) {
        int ni = p + i4;
        dst[((size_t)b * Np + n0 + ni) * dstStride + c0 + j] = f2b(tile[j][ni]);
    }
}

// ---------- mega front kernel: knn + 2 transposes + weight cvt, role-interleaved ----------
// groups of 70 blocks: 16 knn + 32 P1T + 16 P2T + 6 cvtw; 64 groups (exact cover).
__global__ __launch_bounds__(256) void mega_front_k(
    const float* __restrict__ xyz1, const float* __restrict__ xyz2,
    const float* __restrict__ points1, const float* __restrict__ points2,
    const float* __restrict__ w0, const float* __restrict__ w1,
    unsigned short* __restrict__ P1T, unsigned short* __restrict__ P2T,
    unsigned short* __restrict__ w0b, unsigned short* __restrict__ w1b,
    int* __restrict__ idxb, float* __restrict__ wtb)
{
    __shared__ __align__(16) char smem[16640];
    const unsigned bid = blockIdx.x;
    const int g = bid / 70, r = bid % 70;
    const int t = threadIdx.x;

    if (r < 16) {
        knn_body3(xyz1, xyz2, idxb, wtb, g * 16 + r, t, smem);
    } else if (r < 48) {
        int rb = g * 32 + (r - 16);              // 2048 blocks: (64 nblk, 2 cblk, 16 b)
        transpose_body(points1, P1T, D1, NN, D1,
                       rb >> 7, (rb >> 6) & 1, rb & 63, t, smem);
    } else if (r < 64) {
        int rb = g * 16 + (r - 48);              // 1024 blocks: (16 nblk, 4 cblk, 16 b)
        transpose_body(points2, P2T, D2, SS, D2,
                       rb >> 6, (rb >> 4) & 3, rb & 15, t, smem);
    } else {
        int rb = g * 6 + (r - 64);               // 384 blocks
        int i = rb * 256 + t;
        if (i < C0 * CIN) w0b[i] = f2b(w0[i]);
        if (i < C1 * C0)  w1b[i] = f2b(w1[i]);
    }
}

// ---------- K3: GEMM1 with interpolation fused into A staging ----------
__launch_bounds__(512, 1)
__global__ void gemm1_k(const unsigned short* __restrict__ P1T,
                        const unsigned short* __restrict__ P2T,
                        const int* __restrict__ idxb, const float* __restrict__ wtb,
                        const unsigned short* __restrict__ w0b,
                        unsigned short* __restrict__ h1, float* __restrict__ part1)
{
    __shared__ unsigned short Als[128 * 64];   // [row][k] bf16, XOR-swizzled
    __shared__ unsigned short Bls[256 * 64];
    __shared__ float lsum[2][256];
    __shared__ float lsq[2][256];

    const int t = threadIdx.x;
    const int wv = t >> 6, l = t & 63, g = l >> 4, lc = l & 15;
    const int wm = wv >> 2, wn = wv & 3;
    const int m0 = blockIdx.x * 128;
    const int b  = blockIdx.x >> 5;            // 32 blocks per batch
    const int sub = t & 7;

    const int grow = t >> 2;
    const size_t gb = ((size_t)(m0 + grow)) * 3;
    const int gi0 = idxb[gb], gi1 = idxb[gb+1], gi2 = idxb[gb+2];
    const float gw0 = wtb[gb], gw1 = wtb[gb+1], gw2 = wtb[gb+2];
    const char* gp0 = (const char*)(P2T + ((size_t)b * SS + gi0) * D2) + (t & 3) * 32;
    const char* gp1 = (const char*)(P2T + ((size_t)b * SS + gi1) * D2) + (t & 3) * 32;
    const char* gp2 = (const char*)(P2T + ((size_t)b * SS + gi2) * D2) + (t & 3) * 32;
    char* gdst = (char*)Als + grow * 128;
    const int gsw = (grow & 7) << 4;

    f32x4 acc[4][4];
#pragma unroll
    for (int i = 0; i < 4; ++i)
#pragma unroll
        for (int j = 0; j < 4; ++j) acc[i][j] = (f32x4){0.f, 0.f, 0.f, 0.f};

    for (int ks = 0; ks < 6; ++ks) {
        const int k0 = ks * 64;
        __syncthreads();
        if (ks < 2) {
#pragma unroll
            for (int q = 0; q < 2; ++q) {      // A from P1T via global_load_lds
                int row = q * 64 + (t >> 3);
                int bco = (sub * 16) ^ ((row & 7) << 4);
                const char* src = (const char*)P1T + (((size_t)(m0 + row)) * D1 + k0) * 2 + bco;
                char* dst = (char*)Als + (q * 512 + wv * 64) * 16;
                GLD16(src, dst);
            }
        } else {
            const int cgB = (ks - 2) * 128;
#pragma unroll
            for (int h = 0; h < 2; ++h) {
                union { uint4 v; unsigned short s[8]; } a0, a1, a2, ov;
                a0.v = *(const uint4*)(gp0 + cgB + h * 16);
                a1.v = *(const uint4*)(gp1 + cgB + h * 16);
                a2.v = *(const uint4*)(gp2 + cgB + h * 16);
#pragma unroll
                for (int i = 0; i < 8; ++i)
                    ov.s[i] = f2b(gw0 * b2f(a0.s[i]) + gw1 * b2f(a1.s[i]) + gw2 * b2f(a2.s[i]));
                *(uint4*)(gdst + (((t & 3) * 32 + h * 16) ^ gsw)) = ov.v;
            }
        }
#pragma unroll
        for (int q = 0; q < 4; ++q) {      // B: 32KB
            int o = q * 64 + (t >> 3);
            int bco = (sub * 16) ^ ((o & 7) << 4);
            const char* src = (const char*)w0b + (((size_t)o) * CIN + k0) * 2 + bco;
            char* dst = (char*)Bls + (q * 512 + wv * 64) * 16;
            GLD16(src, dst);
        }
        __syncthreads();
#pragma unroll
        for (int kk = 0; kk < 2; ++kk) {
            short8 af[4], bfr[4];
#pragma unroll
            for (int fm = 0; fm < 4; ++fm) {
                int row = wm * 64 + fm * 16 + lc;
                int bcol = kk * 64 + g * 16;
                af[fm] = *(const short8*)((const char*)Als + row * 128 + (bcol ^ ((row & 7) << 4)));
            }
#pragma unroll
            for (int fn = 0; fn < 4; ++fn) {
                int o = wn * 64 + fn * 16 + lc;
                int bcol = kk * 64 + g * 16;
                bfr[fn] = *(const short8*)((const char*)Bls + o * 128 + (bcol ^ ((o & 7) << 4)));
            }
#pragma unroll
            for (int fm = 0; fm < 4; ++fm)
#pragma unroll
                for (int fn = 0; fn < 4; ++fn)
                    acc[fm][fn] = __builtin_amdgcn_mfma_f32_16x16x32_bf16(af[fm], bfr[fn], acc[fm][fn], 0, 0, 0);
        }
    }

    float s1[4] = {0,0,0,0}, s2v[4] = {0,0,0,0};
#pragma unroll
    for (int fm = 0; fm < 4; ++fm)
#pragma unroll
        for (int fn = 0; fn < 4; ++fn) {
            int row = m0 + wm * 64 + fm * 16 + g * 4;
            int col = wn * 64 + fn * 16 + lc;
#pragma unroll
            for (int j = 0; j < 4; ++j) {
                float v = acc[fm][fn][j];
                h1[((size_t)(row + j)) * C0 + col] = f2b(v);
                s1[fn] += v; s2v[fn] += v * v;
            }
        }
#pragma unroll
    for (int fn = 0; fn < 4; ++fn) {
        s1[fn] += __shfl_xor(s1[fn], 16); s1[fn] += __shfl_xor(s1[fn], 32);
        s2v[fn] += __shfl_xor(s2v[fn], 16); s2v[fn] += __shfl_xor(s2v[fn], 32);
    }
    if (l < 16) {
#pragma unroll
        for (int fn = 0; fn < 4; ++fn) {
            lsum[wm][wn * 64 + fn * 16 + l] = s1[fn];
            lsq[wm][wn * 64 + fn * 16 + l] = s2v[fn];
        }
    }
    __syncthreads();
    if (t < 256) {
        part1[(size_t)t * NBLK + blockIdx.x]        = lsum[0][t] + lsum[1][t];
        part1[(size_t)(C0 + t) * NBLK + blockIdx.x] = lsq[0][t] + lsq[1][t];
    }
}

// ---------- stats: one wave per channel, coalesced [channel][block] reads ----------
__global__ void stats_k(const float* __restrict__ part, int nblk, int C,
                        const float* __restrict__ gam, const float* __restrict__ bet,
                        float* __restrict__ sc, float* __restrict__ sh)
{
    const int w = threadIdx.x >> 6, l = threadIdx.x & 63;
    const int o = blockIdx.x * 4 + w;
    if (o >= C) return;
    float s = 0.f, q = 0.f;
    for (int i = l; i < nblk; i += 64) {
        s += part[(size_t)o * nblk + i];
        q += part[(size_t)(C + o) * nblk + i];
    }
#pragma unroll
    for (int r = 32; r; r >>= 1) { s += __shfl_xor(s, r); q += __shfl_xor(q, r); }
    if (l == 0) {
        const float inv = 1.0f / (float)MM;
        float mean = s * inv;
        float var = q * inv - mean * mean;
        float scale = gam[o] * rsqrtf(var + 1e-5f);
        sc[o] = scale;
        sh[o] = bet[o] - mean * scale;
    }
}

// ---------- K5: GEMM2 with BN1+ReLU fused into A staging ----------
__launch_bounds__(256, 1)
__global__ void gemm2_k(const unsigned short* __restrict__ h1, const unsigned short* __restrict__ w1b,
                        const float* __restrict__ sc1, const float* __restrict__ sh1,
                        unsigned short* __restrict__ h2, float* __restrict__ part2)
{
    __shared__ unsigned short Als[128 * 64];
    __shared__ unsigned short Bls[128 * 64];
    __shared__ float scl[256], shl[256];
    __shared__ float lsum[2][128];
    __shared__ float lsq[2][128];

    const int t = threadIdx.x;
    const int wv = t >> 6, l = t & 63, g = l >> 4, lc = l & 15;
    const int wm = wv >> 1, wn = wv & 1;
    const int m0 = blockIdx.x * 128;
    const int sub = t & 7;

    scl[t] = sc1[t]; shl[t] = sh1[t];

    f32x4 acc[4][4];
#pragma unroll
    for (int i = 0; i < 4; ++i)
#pragma unroll
        for (int j = 0; j < 4; ++j) acc[i][j] = (f32x4){0.f, 0.f, 0.f, 0.f};

    for (int ks = 0; ks < 4; ++ks) {
        const int k0 = ks * 64;
        __syncthreads();
        uint4 r[4];
#pragma unroll
        for (int q = 0; q < 4; ++q) {
            int row = q * 32 + (t >> 3);
            r[q] = *(const uint4*)((const char*)h1 + (((size_t)(m0 + row)) * C0 + k0) * 2 + sub * 16);
        }
#pragma unroll
        for (int q = 0; q < 4; ++q) {
            int row = q * 32 + (t >> 3);
            union { uint4 v; unsigned short s[8]; } u, ov;
            u.v = r[q];
#pragma unroll
            for (int i = 0; i < 8; ++i) {
                int k = k0 + sub * 8 + i;
                float f = b2f(u.s[i]);
                ov.s[i] = f2b(fmaxf(0.0f, fmaf(scl[k], f, shl[k])));
            }
            *(uint4*)((char*)Als + row * 128 + ((sub * 16) ^ ((row & 7) << 4))) = ov.v;
        }
#pragma unroll
        for (int q = 0; q < 4; ++q) {
            int o = q * 32 + (t >> 3);
            int bco = (sub * 16) ^ ((o & 7) << 4);
            const char* src = (const char*)w1b + (((size_t)o) * C0 + k0) * 2 + bco;
            char* dst = (char*)Bls + (q * 256 + wv * 64) * 16;
            GLD16(src, dst);
        }
        __syncthreads();
#pragma unroll
        for (int kk = 0; kk < 2; ++kk) {
            short8 af[4], bfr[4];
#pragma unroll
            for (int fm = 0; fm < 4; ++fm) {
                int row = wm * 64 + fm * 16 + lc;
                int bcol = kk * 64 + g * 16;
                af[fm] = *(const short8*)((const char*)Als + row * 128 + (bcol ^ ((row & 7) << 4)));
            }
#pragma unroll
            for (int fn = 0; fn < 4; ++fn) {
                int o = wn * 64 + fn * 16 + lc;
                int bcol = kk * 64 + g * 16;
                bfr[fn] = *(const short8*)((const char*)Bls + o * 128 + (bcol ^ ((o & 7) << 4)));
            }
#pragma unroll
            for (int fm = 0; fm < 4; ++fm)
#pragma unroll
                for (int fn = 0; fn < 4; ++fn)
                    acc[fm][fn] = __builtin_amdgcn_mfma_f32_16x16x32_bf16(af[fm], bfr[fn], acc[fm][fn], 0, 0, 0);
        }
    }

    float s1[4] = {0,0,0,0}, s2v[4] = {0,0,0,0};
#pragma unroll
    for (int fm = 0; fm < 4; ++fm)
#pragma unroll
        for (int fn = 0; fn < 4; ++fn) {
            int row = m0 + wm * 64 + fm * 16 + g * 4;
            int col = wn * 64 + fn * 16 + lc;
#pragma unroll
            for (int j = 0; j < 4; ++j) {
                float v = acc[fm][fn][j];
                h2[((size_t)(row + j)) * C1 + col] = f2b(v);
                s1[fn] += v; s2v[fn] += v * v;
            }
        }
#pragma unroll
    for (int fn = 0; fn < 4; ++fn) {
        s1[fn] += __shfl_xor(s1[fn], 16); s1[fn] += __shfl_xor(s1[fn], 32);
        s2v[fn] += __shfl_xor(s2v[fn], 16); s2v[fn] += __shfl_xor(s2v[fn], 32);
    }
    if (l < 16) {
#pragma unroll
        for (int fn = 0; fn < 4; ++fn) {
            lsum[wm][wn * 64 + fn * 16 + l] = s1[fn];
            lsq[wm][wn * 64 + fn * 16 + l] = s2v[fn];
        }
    }
    __syncthreads();
    if (t < 128) {
        part2[(size_t)t * NBLK + blockIdx.x]        = lsum[0][t] + lsum[1][t];
        part2[(size_t)(C1 + t) * NBLK + blockIdx.x] = lsq[0][t] + lsq[1][t];
    }
}

// ---------- K7: final BN2+ReLU + transpose [b,n,o] -> [b,o,n] f32 ----------
__global__ void finalize_k(const unsigned short* __restrict__ h2,
                           const float* __restrict__ sc, const float* __restrict__ sh,
                           float* __restrict__ out)
{
    __shared__ float tile[64][65];
    const int b = blockIdx.z, o0 = blockIdx.y * 64, n0 = blockIdx.x * 64;
    const int t = threadIdx.x, j = t & 63, i4 = t >> 6;
    const float scv = sc[o0 + j], shv = sh[o0 + j];
#pragma unroll
    for (int p = 0; p < 64; p += 4) {
        int ni = p + i4;
        float f = b2f(h2[((size_t)b * NN + n0 + ni) * C1 + o0 + j]);
        tile[ni][j] = fmaxf(0.0f, fmaf(scv, f, shv));
    }
    __syncthreads();
#pragma unroll
    for (int p = 0; p < 64; p += 4) {
        int oi = p + i4;
        out[((size_t)(b * C1 + o0 + oi)) * NN + n0 + j] = tile[j][oi];
    }
}

// ---------- launch ----------
extern "C" void kernel_launch(void* const* d_in, const int* in_sizes, int n_in,
                              void* d_out, int out_size, void* d_ws, size_t ws_size,
                              hipStream_t stream)
{
    const float* xyz1    = (const float*)d_in[0];
    const float* xyz2    = (const float*)d_in[1];
    const float* points1 = (const float*)d_in[2];
    const float* points2 = (const float*)d_in[3];
    const float* w0      = (const float*)d_in[4];
    const float* g0      = (const float*)d_in[6];
    const float* be0     = (const float*)d_in[7];
    const float* w1      = (const float*)d_in[8];
    const float* g1      = (const float*)d_in[10];
    const float* be1     = (const float*)d_in[11];
    float* out = (float*)d_out;
    char* ws = (char*)d_ws;

    unsigned short* P1T = (unsigned short*)(ws + 0);           // 16777216
    unsigned short* h1  = (unsigned short*)(ws + 16777216);    // 33554432
    unsigned short* P2T = (unsigned short*)(ws + 50331648);    // 8388608
    unsigned short* h2  = (unsigned short*)(ws + 58720256);    // 16777216
    int*   idxb  = (int*)  (ws + 75497472);                    // 786432
    float* wtb   = (float*)(ws + 76283904);                    // 786432
    unsigned short* w0b = (unsigned short*)(ws + 77070336);    // 196608
    unsigned short* w1b = (unsigned short*)(ws + 77266944);    // 65536
    float* part1 = (float*)(ws + 77332480);                    // 1048576
    float* part2 = (float*)(ws + 78381056);                    // 524288
    float* sc1   = (float*)(ws + 78905344);
    float* sh1   = (float*)(ws + 78906368);
    float* sc2   = (float*)(ws + 78907392);
    float* sh2   = (float*)(ws + 78908416);
    // total ws needed: ~79 MB

    mega_front_k<<<70 * 64, 256, 0, stream>>>(xyz1, xyz2, points1, points2, w0, w1,
                                              P1T, P2T, w0b, w1b, idxb, wtb);
    gemm1_k<<<MM/128, 512, 0, stream>>>(P1T, P2T, idxb, wtb, w0b, h1, part1);
    stats_k<<<C0/4, 256, 0, stream>>>(part1, NBLK, C0, g0, be0, sc1, sh1);
    gemm2_k<<<MM/128, 256, 0, stream>>>(h1, w1b, sc1, sh1, h2, part2);
    stats_k<<<C1/4, 256, 0, stream>>>(part2, NBLK, C1, g1, be1, sc2, sh2);
    finalize_k<<<dim3(NN/64, C1/64, BB), 256, 0, stream>>>(h2, sc2, sh2, out);
}

// Round 8
// 113.909 us; speedup vs baseline: 1.9740x; 1.0295x over previous
//
#include <hip/hip_runtime.h>
#include <cstdint>
#include <cstddef>

// ---------- problem constants ----------
#define BB   16
#define NN   4096
#define SS   1024
#define D1   128
#define D2   256
#define CIN  384
#define C0   256
#define C1   128
#define MM   (BB*NN)          // 65536
#define NBLK (MM/128)         // 512 gemm blocks

typedef __attribute__((ext_vector_type(8))) short short8;
typedef __attribute__((ext_vector_type(4))) float f32x4;

__device__ __forceinline__ float b2f(unsigned short h) {
    union { unsigned int u; float f; } x; x.u = ((unsigned int)h) << 16; return x.f;
}
__device__ __forceinline__ unsigned short f2b(float f) {
    union { float f; unsigned int u; } x; x.f = f;
    unsigned int r = x.u + 0x7FFFu + ((x.u >> 16) & 1u);
    return (unsigned short)(r >> 16);
}

#define GLD16(g, l) __builtin_amdgcn_global_load_lds( \
    (const __attribute__((address_space(1))) void*)(g), \
    (__attribute__((address_space(3))) void*)(l), 16, 0, 0)

// ---------- knn v5: LDS float4 (qx,qy,qz,-) + NAIVE (p-q)^2 + f64 packed keys ----------
// Distance kept textually identical to rounds 1-3 (naive form; accurate for small d,
// matches the reference argsort — the round-6 expanded form cancellation regressed).
// key = double(hi = f32 d bits, lo = idx): nonneg d => f64 compare == (d, idx)
// lexicographic == stable argsort order. Sorted top-3 insert = 5 v_min/max_f64.
__device__ __forceinline__ void knn_body5(const float* __restrict__ xyz1,
                                          const float* __restrict__ xyz2,
                                          int* __restrict__ idxb, float* __restrict__ wtb,
                                          int rb, int t, char* smem)
{
    float4* cnd = (float4*)smem;           // [8][129] float4, chunk-padded
    const int b    = rb >> 7;              // 128 blocks per batch
    const int bx   = rb & 127;
    const int chunk = t & 7;
    const int n    = bx * 32 + (t >> 3);

    for (int i = t; i < SS; i += 256) {
        float qx = xyz2[((size_t)b * 3 + 0) * SS + i];
        float qy = xyz2[((size_t)b * 3 + 1) * SS + i];
        float qz = xyz2[((size_t)b * 3 + 2) * SS + i];
        cnd[(i >> 7) * 129 + (i & 127)] = make_float4(qx, qy, qz, 0.f);
    }
    __syncthreads();

    const float px = xyz1[((size_t)b * 3 + 0) * NN + n];
    const float py = xyz1[((size_t)b * 3 + 1) * NN + n];
    const float pz = xyz1[((size_t)b * 3 + 2) * NN + n];

    const double INITK = __hiloint2double(0x7F7FFFFF, 0);
    double A0 = INITK, A1 = INITK, A2 = INITK;
    double B0 = INITK, B1 = INITK, B2 = INITK;
    const float4* cc = cnd + chunk * 129;
    const int sbase = chunk * 128;

#pragma unroll 4
    for (int c = 0; c < 128; c += 2) {
        {
            float4 q = cc[c];
            float dx = px - q.x, dy = py - q.y, dz = pz - q.z;
            float d = dx*dx + dy*dy + dz*dz;
            double k = __hiloint2double(__float_as_int(d), sbase + c);
            double t0 = fmin(k, A0), h0 = fmax(k, A0);
            double t1 = fmin(h0, A1), h1 = fmax(h0, A1);
            A2 = fmin(h1, A2); A0 = t0; A1 = t1;
        }
        {
            float4 q = cc[c + 1];
            float dx = px - q.x, dy = py - q.y, dz = pz - q.z;
            float d = dx*dx + dy*dy + dz*dz;
            double k = __hiloint2double(__float_as_int(d), sbase + c + 1);
            double t0 = fmin(k, B0), h0 = fmax(k, B0);
            double t1 = fmin(h0, B1), h1 = fmax(h0, B1);
            B2 = fmin(h1, B2); B0 = t0; B1 = t1;
        }
    }

    // in-lane merge of sorted triples A,B (keys unique -> exact order)
    double K0, K1, K2;
    {
        double y0 = fmax(A0, B0);
        K0 = fmin(A0, B0);
        double x1 = fmin(A1, B1);
        K1 = fmin(y0, x1);
        double z  = fmax(y0, x1);
        K2 = fmin(z, fmin(A2, B2));
    }
    // merge across the 8 chunk lanes (keys unique -> plain min/max network exact)
#pragma unroll
    for (int r = 1; r <= 4; r <<= 1) {
        double C0d = __shfl_xor(K0, r);
        double C1d = __shfl_xor(K1, r);
        double C2d = __shfl_xor(K2, r);
        double y0 = fmax(K0, C0d);
        K0 = fmin(K0, C0d);
        double x1 = fmin(K1, C1d);
        double nK1 = fmin(y0, x1);
        double z  = fmax(y0, x1);
        K2 = fmin(z, fmin(K2, C2d));
        K1 = nK1;
    }

    if (chunk == 0) {
        int j0 = __double2loint(K0), j1 = __double2loint(K1), j2 = __double2loint(K2);
        // weights: distances to s=0,1,2, naive form (faithful to rounds 1-3)
        float4 q0 = cnd[0], q1 = cnd[1], q2 = cnd[2];
        float dd0, dd1, dd2;
        { float dx=px-q0.x, dy=py-q0.y, dz=pz-q0.z; dd0 = fmaxf(dx*dx+dy*dy+dz*dz, 1e-10f); }
        { float dx=px-q1.x, dy=py-q1.y, dz=pz-q1.z; dd1 = fmaxf(dx*dx+dy*dy+dz*dz, 1e-10f); }
        { float dx=px-q2.x, dy=py-q2.y, dz=pz-q2.z; dd2 = fmaxf(dx*dx+dy*dy+dz*dz, 1e-10f); }
        float r0 = 1.f/dd0, r1 = 1.f/dd1, r2 = 1.f/dd2;
        float inv = 1.f / (r0 + r1 + r2);
        size_t base = ((size_t)b * NN + n) * 3;
        idxb[base+0] = j0; idxb[base+1] = j1; idxb[base+2] = j2;
        wtb[base+0] = r0*inv; wtb[base+1] = r1*inv; wtb[base+2] = r2*inv;
    }
}

__device__ __forceinline__ void transpose_body(const float* __restrict__ src,
                                               unsigned short* __restrict__ dst,
                                               int C, int Np, int dstStride,
                                               int b, int cblk, int nblk, int t, char* smem)
{
    float (*tile)[65] = (float(*)[65])smem;
    const int c0 = cblk * 64, n0 = nblk * 64;
    const int j = t & 63, i4 = t >> 6;
#pragma unroll
    for (int p = 0; p < 64; p += 4) {
        int ci = p + i4;
        tile[ci][j] = src[((size_t)b * C + c0 + ci) * Np + n0 + j];
    }
    __syncthreads();
#pragma unroll
    for (int p = 0; p < 64; p += 4) {
        int ni = p + i4;
        dst[((size_t)b * Np + n0 + ni) * dstStride + c0 + j] = f2b(tile[j][ni]);
    }
}

// ---------- mega front kernel: knn + 2 transposes + weight cvt, role-interleaved ----------
// groups of 86 blocks: 32 knn + 32 P1T + 16 P2T + 6 cvtw; 64 groups (exact cover).
__global__ __launch_bounds__(256) void mega_front_k(
    const float* __restrict__ xyz1, const float* __restrict__ xyz2,
    const float* __restrict__ points1, const float* __restrict__ points2,
    const float* __restrict__ w0, const float* __restrict__ w1,
    unsigned short* __restrict__ P1T, unsigned short* __restrict__ P2T,
    unsigned short* __restrict__ w0b, unsigned short* __restrict__ w1b,
    int* __restrict__ idxb, float* __restrict__ wtb)
{
    __shared__ __align__(16) char smem[16640];
    const unsigned bid = blockIdx.x;
    const int g = bid / 86, r = bid % 86;
    const int t = threadIdx.x;

    if (r < 32) {
        knn_body5(xyz1, xyz2, idxb, wtb, g * 32 + r, t, smem);
    } else if (r < 64) {
        int rb = g * 32 + (r - 32);              // 2048 blocks: (64 nblk, 2 cblk, 16 b)
        transpose_body(points1, P1T, D1, NN, D1,
                       rb >> 7, (rb >> 6) & 1, rb & 63, t, smem);
    } else if (r < 80) {
        int rb = g * 16 + (r - 64);              // 1024 blocks: (16 nblk, 4 cblk, 16 b)
        transpose_body(points2, P2T, D2, SS, D2,
                       rb >> 6, (rb >> 4) & 3, rb & 15, t, smem);
    } else {
        int rb = g * 6 + (r - 80);               // 384 blocks
        int i = rb * 256 + t;
        if (i < C0 * CIN) w0b[i] = f2b(w0[i]);
        if (i < C1 * C0)  w1b[i] = f2b(w1[i]);
    }
}

// ---------- K3: GEMM1 with interpolation fused into A staging ----------
__launch_bounds__(512, 1)
__global__ void gemm1_k(const unsigned short* __restrict__ P1T,
                        const unsigned short* __restrict__ P2T,
                        const int* __restrict__ idxb, const float* __restrict__ wtb,
                        const unsigned short* __restrict__ w0b,
                        unsigned short* __restrict__ h1, float* __restrict__ part1)
{
    __shared__ unsigned short Als[128 * 64];   // [row][k] bf16, XOR-swizzled
    __shared__ unsigned short Bls[256 * 64];
    __shared__ float lsum[2][256];
    __shared__ float lsq[2][256];

    const int t = threadIdx.x;
    const int wv = t >> 6, l = t & 63, g = l >> 4, lc = l & 15;
    const int wm = wv >> 2, wn = wv & 3;
    const int m0 = blockIdx.x * 128;
    const int b  = blockIdx.x >> 5;            // 32 blocks per batch
    const int sub = t & 7;

    const int grow = t >> 2;
    const size_t gb = ((size_t)(m0 + grow)) * 3;
    const int gi0 = idxb[gb], gi1 = idxb[gb+1], gi2 = idxb[gb+2];
    const float gw0 = wtb[gb], gw1 = wtb[gb+1], gw2 = wtb[gb+2];
    const char* gp0 = (const char*)(P2T + ((size_t)b * SS + gi0) * D2) + (t & 3) * 32;
    const char* gp1 = (const char*)(P2T + ((size_t)b * SS + gi1) * D2) + (t & 3) * 32;
    const char* gp2 = (const char*)(P2T + ((size_t)b * SS + gi2) * D2) + (t & 3) * 32;
    char* gdst = (char*)Als + grow * 128;
    const int gsw = (grow & 7) << 4;

    f32x4 acc[4][4];
#pragma unroll
    for (int i = 0; i < 4; ++i)
#pragma unroll
        for (int j = 0; j < 4; ++j) acc[i][j] = (f32x4){0.f, 0.f, 0.f, 0.f};

    for (int ks = 0; ks < 6; ++ks) {
        const int k0 = ks * 64;
        __syncthreads();
        if (ks < 2) {
#pragma unroll
            for (int q = 0; q < 2; ++q) {      // A from P1T via global_load_lds
                int row = q * 64 + (t >> 3);
                int bco = (sub * 16) ^ ((row & 7) << 4);
                const char* src = (const char*)P1T + (((size_t)(m0 + row)) * D1 + k0) * 2 + bco;
                char* dst = (char*)Als + (q * 512 + wv * 64) * 16;
                GLD16(src, dst);
            }
        } else {
            const int cgB = (ks - 2) * 128;
#pragma unroll
            for (int h = 0; h < 2; ++h) {
                union { uint4 v; unsigned short s[8]; } a0, a1, a2, ov;
                a0.v = *(const uint4*)(gp0 + cgB + h * 16);
                a1.v = *(const uint4*)(gp1 + cgB + h * 16);
                a2.v = *(const uint4*)(gp2 + cgB + h * 16);
#pragma unroll
                for (int i = 0; i < 8; ++i)
                    ov.s[i] = f2b(gw0 * b2f(a0.s[i]) + gw1 * b2f(a1.s[i]) + gw2 * b2f(a2.s[i]));
                *(uint4*)(gdst + (((t & 3) * 32 + h * 16) ^ gsw)) = ov.v;
            }
        }
#pragma unroll
        for (int q = 0; q < 4; ++q) {      // B: 32KB
            int o = q * 64 + (t >> 3);
            int bco = (sub * 16) ^ ((o & 7) << 4);
            const char* src = (const char*)w0b + (((size_t)o) * CIN + k0) * 2 + bco;
            char* dst = (char*)Bls + (q * 512 + wv * 64) * 16;
            GLD16(src, dst);
        }
        __syncthreads();
#pragma unroll
        for (int kk = 0; kk < 2; ++kk) {
            short8 af[4], bfr[4];
#pragma unroll
            for (int fm = 0; fm < 4; ++fm) {
                int row = wm * 64 + fm * 16 + lc;
                int bcol = kk * 64 + g * 16;
                af[fm] = *(const short8*)((const char*)Als + row * 128 + (bcol ^ ((row & 7) << 4)));
            }
#pragma unroll
            for (int fn = 0; fn < 4; ++fn) {
                int o = wn * 64 + fn * 16 + lc;
                int bcol = kk * 64 + g * 16;
                bfr[fn] = *(const short8*)((const char*)Bls + o * 128 + (bcol ^ ((o & 7) << 4)));
            }
#pragma unroll
            for (int fm = 0; fm < 4; ++fm)
#pragma unroll
                for (int fn = 0; fn < 4; ++fn)
                    acc[fm][fn] = __builtin_amdgcn_mfma_f32_16x16x32_bf16(af[fm], bfr[fn], acc[fm][fn], 0, 0, 0);
        }
    }

    float s1[4] = {0,0,0,0}, s2v[4] = {0,0,0,0};
#pragma unroll
    for (int fm = 0; fm < 4; ++fm)
#pragma unroll
        for (int fn = 0; fn < 4; ++fn) {
            int row = m0 + wm * 64 + fm * 16 + g * 4;
            int col = wn * 64 + fn * 16 + lc;
#pragma unroll
            for (int j = 0; j < 4; ++j) {
                float v = acc[fm][fn][j];
                h1[((size_t)(row + j)) * C0 + col] = f2b(v);
                s1[fn] += v; s2v[fn] += v * v;
            }
        }
#pragma unroll
    for (int fn = 0; fn < 4; ++fn) {
        s1[fn] += __shfl_xor(s1[fn], 16); s1[fn] += __shfl_xor(s1[fn], 32);
        s2v[fn] += __shfl_xor(s2v[fn], 16); s2v[fn] += __shfl_xor(s2v[fn], 32);
    }
    if (l < 16) {
#pragma unroll
        for (int fn = 0; fn < 4; ++fn) {
            lsum[wm][wn * 64 + fn * 16 + l] = s1[fn];
            lsq[wm][wn * 64 + fn * 16 + l] = s2v[fn];
        }
    }
    __syncthreads();
    if (t < 256) {
        part1[(size_t)t * NBLK + blockIdx.x]        = lsum[0][t] + lsum[1][t];
        part1[(size_t)(C0 + t) * NBLK + blockIdx.x] = lsq[0][t] + lsq[1][t];
    }
}

// ---------- stats: one wave per channel, coalesced [channel][block] reads ----------
__global__ void stats_k(const float* __restrict__ part, int nblk, int C,
                        const float* __restrict__ gam, const float* __restrict__ bet,
                        float* __restrict__ sc, float* __restrict__ sh)
{
    const int w = threadIdx.x >> 6, l = threadIdx.x & 63;
    const int o = blockIdx.x * 4 + w;
    if (o >= C) return;
    float s = 0.f, q = 0.f;
    for (int i = l; i < nblk; i += 64) {
        s += part[(size_t)o * nblk + i];
        q += part[(size_t)(C + o) * nblk + i];
    }
#pragma unroll
    for (int r = 32; r; r >>= 1) { s += __shfl_xor(s, r); q += __shfl_xor(q, r); }
    if (l == 0) {
        const float inv = 1.0f / (float)MM;
        float mean = s * inv;
        float var = q * inv - mean * mean;
        float scale = gam[o] * rsqrtf(var + 1e-5f);
        sc[o] = scale;
        sh[o] = bet[o] - mean * scale;
    }
}

// ---------- K5: GEMM2 with BN1+ReLU fused into A staging ----------
__launch_bounds__(256, 1)
__global__ void gemm2_k(const unsigned short* __restrict__ h1, const unsigned short* __restrict__ w1b,
                        const float* __restrict__ sc1, const float* __restrict__ sh1,
                        unsigned short* __restrict__ h2, float* __restrict__ part2)
{
    __shared__ unsigned short Als[128 * 64];
    __shared__ unsigned short Bls[128 * 64];
    __shared__ float scl[256], shl[256];
    __shared__ float lsum[2][128];
    __shared__ float lsq[2][128];

    const int t = threadIdx.x;
    const int wv = t >> 6, l = t & 63, g = l >> 4, lc = l & 15;
    const int wm = wv >> 1, wn = wv & 1;
    const int m0 = blockIdx.x * 128;
    const int sub = t & 7;

    scl[t] = sc1[t]; shl[t] = sh1[t];

    f32x4 acc[4][4];
#pragma unroll
    for (int i = 0; i < 4; ++i)
#pragma unroll
        for (int j = 0; j < 4; ++j) acc[i][j] = (f32x4){0.f, 0.f, 0.f, 0.f};

    for (int ks = 0; ks < 4; ++ks) {
        const int k0 = ks * 64;
        __syncthreads();
        uint4 r[4];
#pragma unroll
        for (int q = 0; q < 4; ++q) {
            int row = q * 32 + (t >> 3);
            r[q] = *(const uint4*)((const char*)h1 + (((size_t)(m0 + row)) * C0 + k0) * 2 + sub * 16);
        }
#pragma unroll
        for (int q = 0; q < 4; ++q) {
            int row = q * 32 + (t >> 3);
            union { uint4 v; unsigned short s[8]; } u, ov;
            u.v = r[q];
#pragma unroll
            for (int i = 0; i < 8; ++i) {
                int k = k0 + sub * 8 + i;
                float f = b2f(u.s[i]);
                ov.s[i] = f2b(fmaxf(0.0f, fmaf(scl[k], f, shl[k])));
            }
            *(uint4*)((char*)Als + row * 128 + ((sub * 16) ^ ((row & 7) << 4))) = ov.v;
        }
#pragma unroll
        for (int q = 0; q < 4; ++q) {
            int o = q * 32 + (t >> 3);
            int bco = (sub * 16) ^ ((o & 7) << 4);
            const char* src = (const char*)w1b + (((size_t)o) * C0 + k0) * 2 + bco;
            char* dst = (char*)Bls + (q * 256 + wv * 64) * 16;
            GLD16(src, dst);
        }
        __syncthreads();
#pragma unroll
        for (int kk = 0; kk < 2; ++kk) {
            short8 af[4], bfr[4];
#pragma unroll
            for (int fm = 0; fm < 4; ++fm) {
                int row = wm * 64 + fm * 16 + lc;
                int bcol = kk * 64 + g * 16;
                af[fm] = *(const short8*)((const char*)Als + row * 128 + (bcol ^ ((row & 7) << 4)));
            }
#pragma unroll
            for (int fn = 0; fn < 4; ++fn) {
                int o = wn * 64 + fn * 16 + lc;
                int bcol = kk * 64 + g * 16;
                bfr[fn] = *(const short8*)((const char*)Bls + o * 128 + (bcol ^ ((o & 7) << 4)));
            }
#pragma unroll
            for (int fm = 0; fm < 4; ++fm)
#pragma unroll
                for (int fn = 0; fn < 4; ++fn)
                    acc[fm][fn] = __builtin_amdgcn_mfma_f32_16x16x32_bf16(af[fm], bfr[fn], acc[fm][fn], 0, 0, 0);
        }
    }

    float s1[4] = {0,0,0,0}, s2v[4] = {0,0,0,0};
#pragma unroll
    for (int fm = 0; fm < 4; ++fm)
#pragma unroll
        for (int fn = 0; fn < 4; ++fn) {
            int row = m0 + wm * 64 + fm * 16 + g * 4;
            int col = wn * 64 + fn * 16 + lc;
#pragma unroll
            for (int j = 0; j < 4; ++j) {
                float v = acc[fm][fn][j];
                h2[((size_t)(row + j)) * C1 + col] = f2b(v);
                s1[fn] += v; s2v[fn] += v * v;
            }
        }
#pragma unroll
    for (int fn = 0; fn < 4; ++fn) {
        s1[fn] += __shfl_xor(s1[fn], 16); s1[fn] += __shfl_xor(s1[fn], 32);
        s2v[fn] += __shfl_xor(s2v[fn], 16); s2v[fn] += __shfl_xor(s2v[fn], 32);
    }
    if (l < 16) {
#pragma unroll
        for (int fn = 0; fn < 4; ++fn) {
            lsum[wm][wn * 64 + fn * 16 + l] = s1[fn];
            lsq[wm][wn * 64 + fn * 16 + l] = s2v[fn];
        }
    }
    __syncthreads();
    if (t < 128) {
        part2[(size_t)t * NBLK + blockIdx.x]        = lsum[0][t] + lsum[1][t];
        part2[(size_t)(C1 + t) * NBLK + blockIdx.x] = lsq[0][t] + lsq[1][t];
    }
}

// ---------- K7: final BN2+ReLU + transpose [b,n,o] -> [b,o,n] f32 ----------
__global__ void finalize_k(const unsigned short* __restrict__ h2,
                           const float* __restrict__ sc, const float* __restrict__ sh,
                           float* __restrict__ out)
{
    __shared__ float tile[64][65];
    const int b = blockIdx.z, o0 = blockIdx.y * 64, n0 = blockIdx.x * 64;
    const int t = threadIdx.x, j = t & 63, i4 = t >> 6;
    const float scv = sc[o0 + j], shv = sh[o0 + j];
#pragma unroll
    for (int p = 0; p < 64; p += 4) {
        int ni = p + i4;
        float f = b2f(h2[((size_t)b * NN + n0 + ni) * C1 + o0 + j]);
        tile[ni][j] = fmaxf(0.0f, fmaf(scv, f, shv));
    }
    __syncthreads();
#pragma unroll
    for (int p = 0; p < 64; p += 4) {
        int oi = p + i4;
        out[((size_t)(b * C1 + o0 + oi)) * NN + n0 + j] = tile[j][oi];
    }
}

// ---------- launch ----------
extern "C" void kernel_launch(void* const* d_in, const int* in_sizes, int n_in,
                              void* d_out, int out_size, void* d_ws, size_t ws_size,
                              hipStream_t stream)
{
    const float* xyz1    = (const float*)d_in[0];
    const float* xyz2    = (const float*)d_in[1];
    const float* points1 = (const float*)d_in[2];
    const float* points2 = (const float*)d_in[3];
    const float* w0      = (const float*)d_in[4];
    const float* g0      = (const float*)d_in[6];
    const float* be0     = (const float*)d_in[7];
    const float* w1      = (const float*)d_in[8];
    const float* g1      = (const float*)d_in[10];
    const float* be1     = (const float*)d_in[11];
    float* out = (float*)d_out;
    char* ws = (char*)d_ws;

    unsigned short* P1T = (unsigned short*)(ws + 0);           // 16777216
    unsigned short* h1  = (unsigned short*)(ws + 16777216);    // 33554432
    unsigned short* P2T = (unsigned short*)(ws + 50331648);    // 8388608
    unsigned short* h2  = (unsigned short*)(ws + 58720256);    // 16777216
    int*   idxb  = (int*)  (ws + 75497472);                    // 786432
    float* wtb   = (float*)(ws + 76283904);                    // 786432
    unsigned short* w0b = (unsigned short*)(ws + 77070336);    // 196608
    unsigned short* w1b = (unsigned short*)(ws + 77266944);    // 65536
    float* part1 = (float*)(ws + 77332480);                    // 1048576
    float* part2 = (float*)(ws + 78381056);                    // 524288
    float* sc1   = (float*)(ws + 78905344);
    float* sh1   = (float*)(ws + 78906368);
    float* sc2   = (float*)(ws + 78907392);
    float* sh2   = (float*)(ws + 78908416);
    // total ws needed: ~79 MB

    mega_front_k<<<86 * 64, 256, 0, stream>>>(xyz1, xyz2, points1, points2, w0, w1,
                                              P1T, P2T, w0b, w1b, idxb, wtb);
    gemm1_k<<<MM/128, 512, 0, stream>>>(P1T, P2T, idxb, wtb, w0b, h1, part1);
    stats_k<<<C0/4, 256, 0, stream>>>(part1, NBLK, C0, g0, be0, sc1, sh1);
    gemm2_k<<<MM/128, 256, 0, stream>>>(h1, w1b, sc1, sh1, h2, part2);
    stats_k<<<C1/4, 256, 0, stream>>>(part2, NBLK, C1, g1, be1, sc2, sh2);
    finalize_k<<<dim3(NN/64, C1/64, BB), 256, 0, stream>>>(h2, sc2, sh2, out);
}

// Round 9
// 109.525 us; speedup vs baseline: 2.0530x; 1.0400x over previous
//
#include <hip/hip_runtime.h>
#include <cstdint>
#include <cstddef>

// ---------- problem constants ----------
#define BB   16
#define NN   4096
#define SS   1024
#define D1   128
#define D2   256
#define CIN  384
#define C0   256
#define C1   128
#define MM   (BB*NN)          // 65536
#define NBLK (MM/128)         // 512 gemm blocks

typedef __attribute__((ext_vector_type(8))) short short8;
typedef __attribute__((ext_vector_type(4))) float f32x4;

__device__ __forceinline__ float b2f(unsigned short h) {
    union { unsigned int u; float f; } x; x.u = ((unsigned int)h) << 16; return x.f;
}
__device__ __forceinline__ unsigned short f2b(float f) {
    union { float f; unsigned int u; } x; x.f = f;
    unsigned int r = x.u + 0x7FFFu + ((x.u >> 16) & 1u);
    return (unsigned short)(r >> 16);
}

#define GLD16(g, l) __builtin_amdgcn_global_load_lds( \
    (const __attribute__((address_space(1))) void*)(g), \
    (__attribute__((address_space(3))) void*)(l), 16, 0, 0)

// ---------- knn v6: v5 + explicit 4-candidate register batch (load/use separation) ----------
// Distance textually identical to rounds 1-3 (naive (p-q)^2). key = double(hi=f32 d
// bits, lo=idx): nonneg d => f64 compare == (d,idx) lexicographic == stable argsort.
__device__ __forceinline__ void knn_body6(const float* __restrict__ xyz1,
                                          const float* __restrict__ xyz2,
                                          int* __restrict__ idxb, float* __restrict__ wtb,
                                          int rb, int t, char* smem)
{
    float4* cnd = (float4*)smem;           // [8][129] float4, chunk-padded
    const int b    = rb >> 7;              // 128 blocks per batch
    const int bx   = rb & 127;
    const int chunk = t & 7;
    const int n    = bx * 32 + (t >> 3);

    for (int i = t; i < SS; i += 256) {
        float qx = xyz2[((size_t)b * 3 + 0) * SS + i];
        float qy = xyz2[((size_t)b * 3 + 1) * SS + i];
        float qz = xyz2[((size_t)b * 3 + 2) * SS + i];
        cnd[(i >> 7) * 129 + (i & 127)] = make_float4(qx, qy, qz, 0.f);
    }
    __syncthreads();

    const float px = xyz1[((size_t)b * 3 + 0) * NN + n];
    const float py = xyz1[((size_t)b * 3 + 1) * NN + n];
    const float pz = xyz1[((size_t)b * 3 + 2) * NN + n];

    const double INITK = __hiloint2double(0x7F7FFFFF, 0);
    double A0 = INITK, A1 = INITK, A2 = INITK;
    double B0 = INITK, B1 = INITK, B2 = INITK;
    const float4* cc = cnd + chunk * 129;
    const int sbase = chunk * 128;

#define INS_A(kk) do { double t0 = fmin((kk), A0), h0 = fmax((kk), A0); \
    double t1 = fmin(h0, A1), h1 = fmax(h0, A1); \
    A2 = fmin(h1, A2); A0 = t0; A1 = t1; } while (0)
#define INS_B(kk) do { double t0 = fmin((kk), B0), h0 = fmax((kk), B0); \
    double t1 = fmin(h0, B1), h1 = fmax(h0, B1); \
    B2 = fmin(h1, B2); B0 = t0; B1 = t1; } while (0)

#pragma unroll 2
    for (int c = 0; c < 128; c += 4) {
        // load 4 candidates into registers first (4 ds_read_b128 back-to-back)
        float4 q0v = cc[c + 0];
        float4 q1v = cc[c + 1];
        float4 q2v = cc[c + 2];
        float4 q3v = cc[c + 3];
        // compute all 4 distances (naive form, bit-identical to rounds 1-3)
        float e0, e1, e2, e3;
        { float dx = px - q0v.x, dy = py - q0v.y, dz = pz - q0v.z; e0 = dx*dx + dy*dy + dz*dz; }
        { float dx = px - q1v.x, dy = py - q1v.y, dz = pz - q1v.z; e1 = dx*dx + dy*dy + dz*dz; }
        { float dx = px - q2v.x, dy = py - q2v.y, dz = pz - q2v.z; e2 = dx*dx + dy*dy + dz*dz; }
        { float dx = px - q3v.x, dy = py - q3v.y, dz = pz - q3v.z; e3 = dx*dx + dy*dy + dz*dz; }
        double k0 = __hiloint2double(__float_as_int(e0), sbase + c + 0);
        double k1 = __hiloint2double(__float_as_int(e1), sbase + c + 1);
        double k2 = __hiloint2double(__float_as_int(e2), sbase + c + 2);
        double k3 = __hiloint2double(__float_as_int(e3), sbase + c + 3);
        INS_A(k0); INS_B(k1); INS_A(k2); INS_B(k3);
    }
#undef INS_A
#undef INS_B

    // in-lane merge of sorted triples A,B (keys unique -> exact order)
    double K0, K1, K2;
    {
        double y0 = fmax(A0, B0);
        K0 = fmin(A0, B0);
        double x1 = fmin(A1, B1);
        K1 = fmin(y0, x1);
        double z  = fmax(y0, x1);
        K2 = fmin(z, fmin(A2, B2));
    }
    // merge across the 8 chunk lanes (keys unique -> plain min/max network exact)
#pragma unroll
    for (int r = 1; r <= 4; r <<= 1) {
        double C0d = __shfl_xor(K0, r);
        double C1d = __shfl_xor(K1, r);
        double C2d = __shfl_xor(K2, r);
        double y0 = fmax(K0, C0d);
        K0 = fmin(K0, C0d);
        double x1 = fmin(K1, C1d);
        double nK1 = fmin(y0, x1);
        double z  = fmax(y0, x1);
        K2 = fmin(z, fmin(K2, C2d));
        K1 = nK1;
    }

    if (chunk == 0) {
        int j0 = __double2loint(K0), j1 = __double2loint(K1), j2 = __double2loint(K2);
        // weights: distances to s=0,1,2, naive form (faithful to rounds 1-3)
        float4 q0 = cnd[0], q1 = cnd[1], q2 = cnd[2];
        float dd0, dd1, dd2;
        { float dx=px-q0.x, dy=py-q0.y, dz=pz-q0.z; dd0 = fmaxf(dx*dx+dy*dy+dz*dz, 1e-10f); }
        { float dx=px-q1.x, dy=py-q1.y, dz=pz-q1.z; dd1 = fmaxf(dx*dx+dy*dy+dz*dz, 1e-10f); }
        { float dx=px-q2.x, dy=py-q2.y, dz=pz-q2.z; dd2 = fmaxf(dx*dx+dy*dy+dz*dz, 1e-10f); }
        float r0 = 1.f/dd0, r1 = 1.f/dd1, r2 = 1.f/dd2;
        float inv = 1.f / (r0 + r1 + r2);
        size_t base = ((size_t)b * NN + n) * 3;
        idxb[base+0] = j0; idxb[base+1] = j1; idxb[base+2] = j2;
        wtb[base+0] = r0*inv; wtb[base+1] = r1*inv; wtb[base+2] = r2*inv;
    }
}

__device__ __forceinline__ void transpose_body(const float* __restrict__ src,
                                               unsigned short* __restrict__ dst,
                                               int C, int Np, int dstStride,
                                               int b, int cblk, int nblk, int t, char* smem)
{
    float (*tile)[65] = (float(*)[65])smem;
    const int c0 = cblk * 64, n0 = nblk * 64;
    const int j = t & 63, i4 = t >> 6;
#pragma unroll
    for (int p = 0; p < 64; p += 4) {
        int ci = p + i4;
        tile[ci][j] = src[((size_t)b * C + c0 + ci) * Np + n0 + j];
    }
    __syncthreads();
#pragma unroll
    for (int p = 0; p < 64; p += 4) {
        int ni = p + i4;
        dst[((size_t)b * Np + n0 + ni) * dstStride + c0 + j] = f2b(tile[j][ni]);
    }
}

// ---------- mega front kernel: knn + 2 transposes + weight cvt, role-interleaved ----------
// groups of 86 blocks: 32 knn + 32 P1T + 16 P2T + 6 cvtw; 64 groups (exact cover).
__global__ __launch_bounds__(256) void mega_front_k(
    const float* __restrict__ xyz1, const float* __restrict__ xyz2,
    const float* __restrict__ points1, const float* __restrict__ points2,
    const float* __restrict__ w0, const float* __restrict__ w1,
    unsigned short* __restrict__ P1T, unsigned short* __restrict__ P2T,
    unsigned short* __restrict__ w0b, unsigned short* __restrict__ w1b,
    int* __restrict__ idxb, float* __restrict__ wtb)
{
    __shared__ __align__(16) char smem[16640];
    const unsigned bid = blockIdx.x;
    const int g = bid / 86, r = bid % 86;
    const int t = threadIdx.x;

    if (r < 32) {
        knn_body6(xyz1, xyz2, idxb, wtb, g * 32 + r, t, smem);
    } else if (r < 64) {
        int rb = g * 32 + (r - 32);              // 2048 blocks: (64 nblk, 2 cblk, 16 b)
        transpose_body(points1, P1T, D1, NN, D1,
                       rb >> 7, (rb >> 6) & 1, rb & 63, t, smem);
    } else if (r < 80) {
        int rb = g * 16 + (r - 64);              // 1024 blocks: (16 nblk, 4 cblk, 16 b)
        transpose_body(points2, P2T, D2, SS, D2,
                       rb >> 6, (rb >> 4) & 3, rb & 15, t, smem);
    } else {
        int rb = g * 6 + (r - 80);               // 384 blocks
        int i = rb * 256 + t;
        if (i < C0 * CIN) w0b[i] = f2b(w0[i]);
        if (i < C1 * C0)  w1b[i] = f2b(w1[i]);
    }
}

// ---------- K3: GEMM1 with interpolation fused into A staging ----------
// launch_bounds (512,4): cap VGPR at 128 -> 2 blocks/CU (16 waves) for latency hiding.
__launch_bounds__(512, 4)
__global__ void gemm1_k(const unsigned short* __restrict__ P1T,
                        const unsigned short* __restrict__ P2T,
                        const int* __restrict__ idxb, const float* __restrict__ wtb,
                        const unsigned short* __restrict__ w0b,
                        unsigned short* __restrict__ h1, float* __restrict__ part1)
{
    __shared__ unsigned short Als[128 * 64];   // [row][k] bf16, XOR-swizzled
    __shared__ unsigned short Bls[256 * 64];
    __shared__ float lsum[2][256];
    __shared__ float lsq[2][256];

    const int t = threadIdx.x;
    const int wv = t >> 6, l = t & 63, g = l >> 4, lc = l & 15;
    const int wm = wv >> 2, wn = wv & 3;
    const int m0 = blockIdx.x * 128;
    const int b  = blockIdx.x >> 5;            // 32 blocks per batch
    const int sub = t & 7;

    const int grow = t >> 2;
    const size_t gb = ((size_t)(m0 + grow)) * 3;
    const int gi0 = idxb[gb], gi1 = idxb[gb+1], gi2 = idxb[gb+2];
    const float gw0 = wtb[gb], gw1 = wtb[gb+1], gw2 = wtb[gb+2];
    const char* gp0 = (const char*)(P2T + ((size_t)b * SS + gi0) * D2) + (t & 3) * 32;
    const char* gp1 = (const char*)(P2T + ((size_t)b * SS + gi1) * D2) + (t & 3) * 32;
    const char* gp2 = (const char*)(P2T + ((size_t)b * SS + gi2) * D2) + (t & 3) * 32;
    char* gdst = (char*)Als + grow * 128;
    const int gsw = (grow & 7) << 4;

    f32x4 acc[4][4];
#pragma unroll
    for (int i = 0; i < 4; ++i)
#pragma unroll
        for (int j = 0; j < 4; ++j) acc[i][j] = (f32x4){0.f, 0.f, 0.f, 0.f};

    for (int ks = 0; ks < 6; ++ks) {
        const int k0 = ks * 64;
        __syncthreads();
        if (ks < 2) {
#pragma unroll
            for (int q = 0; q < 2; ++q) {      // A from P1T via global_load_lds
                int row = q * 64 + (t >> 3);
                int bco = (sub * 16) ^ ((row & 7) << 4);
                const char* src = (const char*)P1T + (((size_t)(m0 + row)) * D1 + k0) * 2 + bco;
                char* dst = (char*)Als + (q * 512 + wv * 64) * 16;
                GLD16(src, dst);
            }
        } else {
            const int cgB = (ks - 2) * 128;
#pragma unroll
            for (int h = 0; h < 2; ++h) {
                union { uint4 v; unsigned short s[8]; } a0, a1, a2, ov;
                a0.v = *(const uint4*)(gp0 + cgB + h * 16);
                a1.v = *(const uint4*)(gp1 + cgB + h * 16);
                a2.v = *(const uint4*)(gp2 + cgB + h * 16);
#pragma unroll
                for (int i = 0; i < 8; ++i)
                    ov.s[i] = f2b(gw0 * b2f(a0.s[i]) + gw1 * b2f(a1.s[i]) + gw2 * b2f(a2.s[i]));
                *(uint4*)(gdst + (((t & 3) * 32 + h * 16) ^ gsw)) = ov.v;
            }
        }
#pragma unroll
        for (int q = 0; q < 4; ++q) {      // B: 32KB
            int o = q * 64 + (t >> 3);
            int bco = (sub * 16) ^ ((o & 7) << 4);
            const char* src = (const char*)w0b + (((size_t)o) * CIN + k0) * 2 + bco;
            char* dst = (char*)Bls + (q * 512 + wv * 64) * 16;
            GLD16(src, dst);
        }
        __syncthreads();
#pragma unroll
        for (int kk = 0; kk < 2; ++kk) {
            short8 af[4], bfr[4];
#pragma unroll
            for (int fm = 0; fm < 4; ++fm) {
                int row = wm * 64 + fm * 16 + lc;
                int bcol = kk * 64 + g * 16;
                af[fm] = *(const short8*)((const char*)Als + row * 128 + (bcol ^ ((row & 7) << 4)));
            }
#pragma unroll
            for (int fn = 0; fn < 4; ++fn) {
                int o = wn * 64 + fn * 16 + lc;
                int bcol = kk * 64 + g * 16;
                bfr[fn] = *(const short8*)((const char*)Bls + o * 128 + (bcol ^ ((o & 7) << 4)));
            }
#pragma unroll
            for (int fm = 0; fm < 4; ++fm)
#pragma unroll
                for (int fn = 0; fn < 4; ++fn)
                    acc[fm][fn] = __builtin_amdgcn_mfma_f32_16x16x32_bf16(af[fm], bfr[fn], acc[fm][fn], 0, 0, 0);
        }
    }

    float s1[4] = {0,0,0,0}, s2v[4] = {0,0,0,0};
#pragma unroll
    for (int fm = 0; fm < 4; ++fm)
#pragma unroll
        for (int fn = 0; fn < 4; ++fn) {
            int row = m0 + wm * 64 + fm * 16 + g * 4;
            int col = wn * 64 + fn * 16 + lc;
#pragma unroll
            for (int j = 0; j < 4; ++j) {
                float v = acc[fm][fn][j];
                h1[((size_t)(row + j)) * C0 + col] = f2b(v);
                s1[fn] += v; s2v[fn] += v * v;
            }
        }
#pragma unroll
    for (int fn = 0; fn < 4; ++fn) {
        s1[fn] += __shfl_xor(s1[fn], 16); s1[fn] += __shfl_xor(s1[fn], 32);
        s2v[fn] += __shfl_xor(s2v[fn], 16); s2v[fn] += __shfl_xor(s2v[fn], 32);
    }
    if (l < 16) {
#pragma unroll
        for (int fn = 0; fn < 4; ++fn) {
            lsum[wm][wn * 64 + fn * 16 + l] = s1[fn];
            lsq[wm][wn * 64 + fn * 16 + l] = s2v[fn];
        }
    }
    __syncthreads();
    if (t < 256) {
        part1[(size_t)t * NBLK + blockIdx.x]        = lsum[0][t] + lsum[1][t];
        part1[(size_t)(C0 + t) * NBLK + blockIdx.x] = lsq[0][t] + lsq[1][t];
    }
}

// ---------- stats: one wave per channel, coalesced [channel][block] reads ----------
__global__ void stats_k(const float* __restrict__ part, int nblk, int C,
                        const float* __restrict__ gam, const float* __restrict__ bet,
                        float* __restrict__ sc, float* __restrict__ sh)
{
    const int w = threadIdx.x >> 6, l = threadIdx.x & 63;
    const int o = blockIdx.x * 4 + w;
    if (o >= C) return;
    float s = 0.f, q = 0.f;
    for (int i = l; i < nblk; i += 64) {
        s += part[(size_t)o * nblk + i];
        q += part[(size_t)(C + o) * nblk + i];
    }
#pragma unroll
    for (int r = 32; r; r >>= 1) { s += __shfl_xor(s, r); q += __shfl_xor(q, r); }
    if (l == 0) {
        const float inv = 1.0f / (float)MM;
        float mean = s * inv;
        float var = q * inv - mean * mean;
        float scale = gam[o] * rsqrtf(var + 1e-5f);
        sc[o] = scale;
        sh[o] = bet[o] - mean * scale;
    }
}

// ---------- K5: GEMM2 with BN1+ReLU fused into A staging ----------
// launch_bounds (256,4): cap VGPR at 128 -> 4 blocks/CU (16 waves).
__launch_bounds__(256, 4)
__global__ void gemm2_k(const unsigned short* __restrict__ h1, const unsigned short* __restrict__ w1b,
                        const float* __restrict__ sc1, const float* __restrict__ sh1,
                        unsigned short* __restrict__ h2, float* __restrict__ part2)
{
    __shared__ unsigned short Als[128 * 64];
    __shared__ unsigned short Bls[128 * 64];
    __shared__ float scl[256], shl[256];
    __shared__ float lsum[2][128];
    __shared__ float lsq[2][128];

    const int t = threadIdx.x;
    const int wv = t >> 6, l = t & 63, g = l >> 4, lc = l & 15;
    const int wm = wv >> 1, wn = wv & 1;
    const int m0 = blockIdx.x * 128;
    const int sub = t & 7;

    scl[t] = sc1[t]; shl[t] = sh1[t];

    f32x4 acc[4][4];
#pragma unroll
    for (int i = 0; i < 4; ++i)
#pragma unroll
        for (int j = 0; j < 4; ++j) acc[i][j] = (f32x4){0.f, 0.f, 0.f, 0.f};

    for (int ks = 0; ks < 4; ++ks) {
        const int k0 = ks * 64;
        __syncthreads();
        uint4 r[4];
#pragma unroll
        for (int q = 0; q < 4; ++q) {
            int row = q * 32 + (t >> 3);
            r[q] = *(const uint4*)((const char*)h1 + (((size_t)(m0 + row)) * C0 + k0) * 2 + sub * 16);
        }
#pragma unroll
        for (int q = 0; q < 4; ++q) {
            int row = q * 32 + (t >> 3);
            union { uint4 v; unsigned short s[8]; } u, ov;
            u.v = r[q];
#pragma unroll
            for (int i = 0; i < 8; ++i) {
                int k = k0 + sub * 8 + i;
                float f = b2f(u.s[i]);
                ov.s[i] = f2b(fmaxf(0.0f, fmaf(scl[k], f, shl[k])));
            }
            *(uint4*)((char*)Als + row * 128 + ((sub * 16) ^ ((row & 7) << 4))) = ov.v;
        }
#pragma unroll
        for (int q = 0; q < 4; ++q) {
            int o = q * 32 + (t >> 3);
            int bco = (sub * 16) ^ ((o & 7) << 4);
            const char* src = (const char*)w1b + (((size_t)o) * C0 + k0) * 2 + bco;
            char* dst = (char*)Bls + (q * 256 + wv * 64) * 16;
            GLD16(src, dst);
        }
        __syncthreads();
#pragma unroll
        for (int kk = 0; kk < 2; ++kk) {
            short8 af[4], bfr[4];
#pragma unroll
            for (int fm = 0; fm < 4; ++fm) {
                int row = wm * 64 + fm * 16 + lc;
                int bcol = kk * 64 + g * 16;
                af[fm] = *(const short8*)((const char*)Als + row * 128 + (bcol ^ ((row & 7) << 4)));
            }
#pragma unroll
            for (int fn = 0; fn < 4; ++fn) {
                int o = wn * 64 + fn * 16 + lc;
                int bcol = kk * 64 + g * 16;
                bfr[fn] = *(const short8*)((const char*)Bls + o * 128 + (bcol ^ ((o & 7) << 4)));
            }
#pragma unroll
            for (int fm = 0; fm < 4; ++fm)
#pragma unroll
                for (int fn = 0; fn < 4; ++fn)
                    acc[fm][fn] = __builtin_amdgcn_mfma_f32_16x16x32_bf16(af[fm], bfr[fn], acc[fm][fn], 0, 0, 0);
        }
    }

    float s1[4] = {0,0,0,0}, s2v[4] = {0,0,0,0};
#pragma unroll
    for (int fm = 0; fm < 4; ++fm)
#pragma unroll
        for (int fn = 0; fn < 4; ++fn) {
            int row = m0 + wm * 64 + fm * 16 + g * 4;
            int col = wn * 64 + fn * 16 + lc;
#pragma unroll
            for (int j = 0; j < 4; ++j) {
                float v = acc[fm][fn][j];
                h2[((size_t)(row + j)) * C1 + col] = f2b(v);
                s1[fn] += v; s2v[fn] += v * v;
            }
        }
#pragma unroll
    for (int fn = 0; fn < 4; ++fn) {
        s1[fn] += __shfl_xor(s1[fn], 16); s1[fn] += __shfl_xor(s1[fn], 32);
        s2v[fn] += __shfl_xor(s2v[fn], 16); s2v[fn] += __shfl_xor(s2v[fn], 32);
    }
    if (l < 16) {
#pragma unroll
        for (int fn = 0; fn < 4; ++fn) {
            lsum[wm][wn * 64 + fn * 16 + l] = s1[fn];
            lsq[wm][wn * 64 + fn * 16 + l] = s2v[fn];
        }
    }
    __syncthreads();
    if (t < 128) {
        part2[(size_t)t * NBLK + blockIdx.x]        = lsum[0][t] + lsum[1][t];
        part2[(size_t)(C1 + t) * NBLK + blockIdx.x] = lsq[0][t] + lsq[1][t];
    }
}

// ---------- K7: final BN2+ReLU + transpose [b,n,o] -> [b,o,n] f32 ----------
__global__ void finalize_k(const unsigned short* __restrict__ h2,
                           const float* __restrict__ sc, const float* __restrict__ sh,
                           float* __restrict__ out)
{
    __shared__ float tile[64][65];
    const int b = blockIdx.z, o0 = blockIdx.y * 64, n0 = blockIdx.x * 64;
    const int t = threadIdx.x, j = t & 63, i4 = t >> 6;
    const float scv = sc[o0 + j], shv = sh[o0 + j];
#pragma unroll
    for (int p = 0; p < 64; p += 4) {
        int ni = p + i4;
        float f = b2f(h2[((size_t)b * NN + n0 + ni) * C1 + o0 + j]);
        tile[ni][j] = fmaxf(0.0f, fmaf(scv, f, shv));
    }
    __syncthreads();
#pragma unroll
    for (int p = 0; p < 64; p += 4) {
        int oi = p + i4;
        out[((size_t)(b * C1 + o0 + oi)) * NN + n0 + j] = tile[j][oi];
    }
}

// ---------- launch ----------
extern "C" void kernel_launch(void* const* d_in, const int* in_sizes, int n_in,
                              void* d_out, int out_size, void* d_ws, size_t ws_size,
                              hipStream_t stream)
{
    const float* xyz1    = (const float*)d_in[0];
    const float* xyz2    = (const float*)d_in[1];
    const float* points1 = (const float*)d_in[2];
    const float* points2 = (const float*)d_in[3];
    const float* w0      = (const float*)d_in[4];
    const float* g0      = (const float*)d_in[6];
    const float* be0     = (const float*)d_in[7];
    const float* w1      = (const float*)d_in[8];
    const float* g1      = (const float*)d_in[10];
    const float* be1     = (const float*)d_in[11];
    float* out = (float*)d_out;
    char* ws = (char*)d_ws;

    unsigned short* P1T = (unsigned short*)(ws + 0);           // 16777216
    unsigned short* h1  = (unsigned short*)(ws + 16777216);    // 33554432
    unsigned short* P2T = (unsigned short*)(ws + 50331648);    // 8388608
    unsigned short* h2  = (unsigned short*)(ws + 58720256);    // 16777216
    int*   idxb  = (int*)  (ws + 75497472);                    // 786432
    float* wtb   = (float*)(ws + 76283904);                    // 786432
    unsigned short* w0b = (unsigned short*)(ws + 77070336);    // 196608
    unsigned short* w1b = (unsigned short*)(ws + 77266944);    // 65536
    float* part1 = (float*)(ws + 77332480);                    // 1048576
    float* part2 = (float*)(ws + 78381056);                    // 524288
    float* sc1   = (float*)(ws + 78905344);
    float* sh1   = (float*)(ws + 78906368);
    float* sc2   = (float*)(ws + 78907392);
    float* sh2   = (float*)(ws + 78908416);
    // total ws needed: ~79 MB

    mega_front_k<<<86 * 64, 256, 0, stream>>>(xyz1, xyz2, points1, points2, w0, w1,
                                              P1T, P2T, w0b, w1b, idxb, wtb);
    gemm1_k<<<MM/128, 512, 0, stream>>>(P1T, P2T, idxb, wtb, w0b, h1, part1);
    stats_k<<<C0/4, 256, 0, stream>>>(part1, NBLK, C0, g0, be0, sc1, sh1);
    gemm2_k<<<MM/128, 256, 0, stream>>>(h1, w1b, sc1, sh1, h2, part2);
    stats_k<<<C1/4, 256, 0, stream>>>(part2, NBLK, C1, g1, be1, sc2, sh2);
    finalize_k<<<dim3(NN/64, C1/64, BB), 256, 0, stream>>>(h2, sc2, sh2, out);
}

// Round 10
// 108.568 us; speedup vs baseline: 2.0711x; 1.0088x over previous
//
#include <hip/hip_runtime.h>
#include <cstdint>
#include <cstddef>

// ---------- problem constants ----------
#define BB   16
#define NN   4096
#define SS   1024
#define D1   128
#define D2   256
#define CIN  384
#define C0   256
#define C1   128
#define MM   (BB*NN)          // 65536
#define NBLK (MM/128)         // 512 gemm blocks

typedef __attribute__((ext_vector_type(8))) short short8;
typedef __attribute__((ext_vector_type(4))) float f32x4;

__device__ __forceinline__ float b2f(unsigned short h) {
    union { unsigned int u; float f; } x; x.u = ((unsigned int)h) << 16; return x.f;
}
__device__ __forceinline__ unsigned short f2b(float f) {
    union { float f; unsigned int u; } x; x.f = f;
    unsigned int r = x.u + 0x7FFFu + ((x.u >> 16) & 1u);
    return (unsigned short)(r >> 16);
}

#define GLD16(g, l) __builtin_amdgcn_global_load_lds( \
    (const __attribute__((address_space(1))) void*)(g), \
    (__attribute__((address_space(3))) void*)(l), 16, 0, 0)

// ---------- knn v7: half-candidate blocks (512 cands each), f64 packed keys ----------
// Each half-block writes its sorted triple of keys (d,idx packed in f64) to trip[];
// gemm1's prologue merges the two halves exactly. Distance = naive (p-q)^2,
// textually identical to the passing rounds. Half 0 also writes the weights
// (reference uses UNSORTED cols 0..2, which live in half 0's chunk 0).
__device__ __forceinline__ void knn_body7(const float* __restrict__ xyz1,
                                          const float* __restrict__ xyz2,
                                          double* __restrict__ trip, float* __restrict__ wtb,
                                          int kb, int t, char* smem)
{
    float4* cnd = (float4*)smem;           // [8][65] float4, chunk-padded
    const int h    = kb & 1;               // candidate half
    const int pb   = kb >> 1;              // point-block 0..2047
    const int b    = pb >> 7;              // 128 point-blocks per batch
    const int bx   = pb & 127;
    const int chunk = t & 7;
    const int n    = bx * 32 + (t >> 3);

    for (int i = t; i < 512; i += 256) {
        int s = h * 512 + i;
        float qx = xyz2[((size_t)b * 3 + 0) * SS + s];
        float qy = xyz2[((size_t)b * 3 + 1) * SS + s];
        float qz = xyz2[((size_t)b * 3 + 2) * SS + s];
        cnd[(i >> 6) * 65 + (i & 63)] = make_float4(qx, qy, qz, 0.f);
    }
    __syncthreads();

    const float px = xyz1[((size_t)b * 3 + 0) * NN + n];
    const float py = xyz1[((size_t)b * 3 + 1) * NN + n];
    const float pz = xyz1[((size_t)b * 3 + 2) * NN + n];

    const double INITK = __hiloint2double(0x7F7FFFFF, 0);
    double A0 = INITK, A1 = INITK, A2 = INITK;
    double B0 = INITK, B1 = INITK, B2 = INITK;
    const float4* cc = cnd + chunk * 65;
    const int sbase = h * 512 + chunk * 64;

#pragma unroll 4
    for (int c = 0; c < 64; c += 2) {
        {
            float4 q = cc[c];
            float dx = px - q.x, dy = py - q.y, dz = pz - q.z;
            float d = dx*dx + dy*dy + dz*dz;
            double k = __hiloint2double(__float_as_int(d), sbase + c);
            double t0 = fmin(k, A0), h0 = fmax(k, A0);
            double t1 = fmin(h0, A1), h1 = fmax(h0, A1);
            A2 = fmin(h1, A2); A0 = t0; A1 = t1;
        }
        {
            float4 q = cc[c + 1];
            float dx = px - q.x, dy = py - q.y, dz = pz - q.z;
            float d = dx*dx + dy*dy + dz*dz;
            double k = __hiloint2double(__float_as_int(d), sbase + c + 1);
            double t0 = fmin(k, B0), h0 = fmax(k, B0);
            double t1 = fmin(h0, B1), h1 = fmax(h0, B1);
            B2 = fmin(h1, B2); B0 = t0; B1 = t1;
        }
    }

    // in-lane merge of sorted triples A,B (keys unique -> exact order)
    double K0, K1, K2;
    {
        double y0 = fmax(A0, B0);
        K0 = fmin(A0, B0);
        double x1 = fmin(A1, B1);
        K1 = fmin(y0, x1);
        double z  = fmax(y0, x1);
        K2 = fmin(z, fmin(A2, B2));
    }
    // merge across the 8 chunk lanes
#pragma unroll
    for (int r = 1; r <= 4; r <<= 1) {
        double C0d = __shfl_xor(K0, r);
        double C1d = __shfl_xor(K1, r);
        double C2d = __shfl_xor(K2, r);
        double y0 = fmax(K0, C0d);
        K0 = fmin(K0, C0d);
        double x1 = fmin(K1, C1d);
        double nK1 = fmin(y0, x1);
        double z  = fmax(y0, x1);
        K2 = fmin(z, fmin(K2, C2d));
        K1 = nK1;
    }

    if (chunk == 0) {
        size_t m = (size_t)b * NN + n;
        double* tp = trip + ((size_t)h * MM + m) * 3;
        tp[0] = K0; tp[1] = K1; tp[2] = K2;
        if (h == 0) {
            // weights: distances to s=0,1,2 (faithful to reference's unsorted-column bug)
            float4 q0 = cnd[0], q1 = cnd[1], q2 = cnd[2];
            float dd0, dd1, dd2;
            { float dx=px-q0.x, dy=py-q0.y, dz=pz-q0.z; dd0 = fmaxf(dx*dx+dy*dy+dz*dz, 1e-10f); }
            { float dx=px-q1.x, dy=py-q1.y, dz=pz-q1.z; dd1 = fmaxf(dx*dx+dy*dy+dz*dz, 1e-10f); }
            { float dx=px-q2.x, dy=py-q2.y, dz=pz-q2.z; dd2 = fmaxf(dx*dx+dy*dy+dz*dz, 1e-10f); }
            float r0 = 1.f/dd0, r1 = 1.f/dd1, r2 = 1.f/dd2;
            float inv = 1.f / (r0 + r1 + r2);
            wtb[m*3+0] = r0*inv; wtb[m*3+1] = r1*inv; wtb[m*3+2] = r2*inv;
        }
    }
}

__device__ __forceinline__ void transpose_body(const float* __restrict__ src,
                                               unsigned short* __restrict__ dst,
                                               int C, int Np, int dstStride,
                                               int b, int cblk, int nblk, int t, char* smem)
{
    float (*tile)[65] = (float(*)[65])smem;
    const int c0 = cblk * 64, n0 = nblk * 64;
    const int j = t & 63, i4 = t >> 6;
#pragma unroll
    for (int p = 0; p < 64; p += 4) {
        int ci = p + i4;
        tile[ci][j] = src[((size_t)b * C + c0 + ci) * Np + n0 + j];
    }
    __syncthreads();
#pragma unroll
    for (int p = 0; p < 64; p += 4) {
        int ni = p + i4;
        dst[((size_t)b * Np + n0 + ni) * dstStride + c0 + j] = f2b(tile[j][ni]);
    }
}

// ---------- mega front kernel: knn-halves + 2 transposes + weight cvt ----------
// groups of 118 blocks: 64 knn-half + 32 P1T + 16 P2T + 6 cvtw; 64 groups.
__global__ __launch_bounds__(256) void mega_front_k(
    const float* __restrict__ xyz1, const float* __restrict__ xyz2,
    const float* __restrict__ points1, const float* __restrict__ points2,
    const float* __restrict__ w0, const float* __restrict__ w1,
    unsigned short* __restrict__ P1T, unsigned short* __restrict__ P2T,
    unsigned short* __restrict__ w0b, unsigned short* __restrict__ w1b,
    double* __restrict__ trip, float* __restrict__ wtb)
{
    __shared__ __align__(16) char smem[16640];
    const unsigned bid = blockIdx.x;
    const int g = bid / 118, r = bid % 118;
    const int t = threadIdx.x;

    if (r < 64) {
        knn_body7(xyz1, xyz2, trip, wtb, g * 64 + r, t, smem);
    } else if (r < 96) {
        int rb = g * 32 + (r - 64);              // 2048 blocks: (64 nblk, 2 cblk, 16 b)
        transpose_body(points1, P1T, D1, NN, D1,
                       rb >> 7, (rb >> 6) & 1, rb & 63, t, smem);
    } else if (r < 112) {
        int rb = g * 16 + (r - 96);              // 1024 blocks: (16 nblk, 4 cblk, 16 b)
        transpose_body(points2, P2T, D2, SS, D2,
                       rb >> 6, (rb >> 4) & 3, rb & 15, t, smem);
    } else {
        int rb = g * 6 + (r - 112);              // 384 blocks
        int i = rb * 256 + t;
        if (i < C0 * CIN) w0b[i] = f2b(w0[i]);
        if (i < C1 * C0)  w1b[i] = f2b(w1[i]);
    }
}

// ---------- K3: GEMM1 with interpolation fused; merges knn halves in prologue ----------
__launch_bounds__(512, 4)
__global__ void gemm1_k(const unsigned short* __restrict__ P1T,
                        const unsigned short* __restrict__ P2T,
                        const double* __restrict__ trip, const float* __restrict__ wtb,
                        const unsigned short* __restrict__ w0b,
                        unsigned short* __restrict__ h1, float* __restrict__ part1)
{
    __shared__ unsigned short Als[128 * 64];   // [row][k] bf16, XOR-swizzled
    __shared__ unsigned short Bls[256 * 64];
    __shared__ float lsum[2][256];
    __shared__ float lsq[2][256];

    const int t = threadIdx.x;
    const int wv = t >> 6, l = t & 63, g = l >> 4, lc = l & 15;
    const int wm = wv >> 2, wn = wv & 3;
    const int m0 = blockIdx.x * 128;
    const int b  = blockIdx.x >> 5;            // 32 blocks per batch
    const int sub = t & 7;

    const int grow = t >> 2;
    const size_t gm = (size_t)(m0 + grow);
    // merge the two knn half-triples (exact f64 merge, keys unique)
    const double* tpA = trip + gm * 3;
    const double* tpB = trip + ((size_t)MM + gm) * 3;
    double hA0 = tpA[0], hA1 = tpA[1], hA2 = tpA[2];
    double hB0 = tpB[0], hB1 = tpB[1], hB2 = tpB[2];
    double y0 = fmax(hA0, hB0), K0 = fmin(hA0, hB0);
    double x1 = fmin(hA1, hB1), K1 = fmin(y0, x1);
    double z  = fmax(y0, x1),   K2 = fmin(z, fmin(hA2, hB2));
    const int gi0 = __double2loint(K0);
    const int gi1 = __double2loint(K1);
    const int gi2 = __double2loint(K2);
    const float gw0 = wtb[gm*3], gw1 = wtb[gm*3+1], gw2 = wtb[gm*3+2];
    const char* gp0 = (const char*)(P2T + ((size_t)b * SS + gi0) * D2) + (t & 3) * 32;
    const char* gp1 = (const char*)(P2T + ((size_t)b * SS + gi1) * D2) + (t & 3) * 32;
    const char* gp2 = (const char*)(P2T + ((size_t)b * SS + gi2) * D2) + (t & 3) * 32;
    char* gdst = (char*)Als + grow * 128;
    const int gsw = (grow & 7) << 4;

    f32x4 acc[4][4];
#pragma unroll
    for (int i = 0; i < 4; ++i)
#pragma unroll
        for (int j = 0; j < 4; ++j) acc[i][j] = (f32x4){0.f, 0.f, 0.f, 0.f};

    for (int ks = 0; ks < 6; ++ks) {
        const int k0 = ks * 64;
        __syncthreads();
        if (ks < 2) {
#pragma unroll
            for (int q = 0; q < 2; ++q) {      // A from P1T via global_load_lds
                int row = q * 64 + (t >> 3);
                int bco = (sub * 16) ^ ((row & 7) << 4);
                const char* src = (const char*)P1T + (((size_t)(m0 + row)) * D1 + k0) * 2 + bco;
                char* dst = (char*)Als + (q * 512 + wv * 64) * 16;
                GLD16(src, dst);
            }
        } else {
            const int cgB = (ks - 2) * 128;
#pragma unroll
            for (int h = 0; h < 2; ++h) {
                union { uint4 v; unsigned short s[8]; } a0, a1, a2, ov;
                a0.v = *(const uint4*)(gp0 + cgB + h * 16);
                a1.v = *(const uint4*)(gp1 + cgB + h * 16);
                a2.v = *(const uint4*)(gp2 + cgB + h * 16);
#pragma unroll
                for (int i = 0; i < 8; ++i)
                    ov.s[i] = f2b(gw0 * b2f(a0.s[i]) + gw1 * b2f(a1.s[i]) + gw2 * b2f(a2.s[i]));
                *(uint4*)(gdst + (((t & 3) * 32 + h * 16) ^ gsw)) = ov.v;
            }
        }
#pragma unroll
        for (int q = 0; q < 4; ++q) {      // B: 32KB
            int o = q * 64 + (t >> 3);
            int bco = (sub * 16) ^ ((o & 7) << 4);
            const char* src = (const char*)w0b + (((size_t)o) * CIN + k0) * 2 + bco;
            char* dst = (char*)Bls + (q * 512 + wv * 64) * 16;
            GLD16(src, dst);
        }
        __syncthreads();
#pragma unroll
        for (int kk = 0; kk < 2; ++kk) {
            short8 af[4], bfr[4];
#pragma unroll
            for (int fm = 0; fm < 4; ++fm) {
                int row = wm * 64 + fm * 16 + lc;
                int bcol = kk * 64 + g * 16;
                af[fm] = *(const short8*)((const char*)Als + row * 128 + (bcol ^ ((row & 7) << 4)));
            }
#pragma unroll
            for (int fn = 0; fn < 4; ++fn) {
                int o = wn * 64 + fn * 16 + lc;
                int bcol = kk * 64 + g * 16;
                bfr[fn] = *(const short8*)((const char*)Bls + o * 128 + (bcol ^ ((o & 7) << 4)));
            }
#pragma unroll
            for (int fm = 0; fm < 4; ++fm)
#pragma unroll
                for (int fn = 0; fn < 4; ++fn)
                    acc[fm][fn] = __builtin_amdgcn_mfma_f32_16x16x32_bf16(af[fm], bfr[fn], acc[fm][fn], 0, 0, 0);
        }
    }

    float s1[4] = {0,0,0,0}, s2v[4] = {0,0,0,0};
#pragma unroll
    for (int fm = 0; fm < 4; ++fm)
#pragma unroll
        for (int fn = 0; fn < 4; ++fn) {
            int row = m0 + wm * 64 + fm * 16 + g * 4;
            int col = wn * 64 + fn * 16 + lc;
#pragma unroll
            for (int j = 0; j < 4; ++j) {
                float v = acc[fm][fn][j];
                h1[((size_t)(row + j)) * C0 + col] = f2b(v);
                s1[fn] += v; s2v[fn] += v * v;
            }
        }
#pragma unroll
    for (int fn = 0; fn < 4; ++fn) {
        s1[fn] += __shfl_xor(s1[fn], 16); s1[fn] += __shfl_xor(s1[fn], 32);
        s2v[fn] += __shfl_xor(s2v[fn], 16); s2v[fn] += __shfl_xor(s2v[fn], 32);
    }
    if (l < 16) {
#pragma unroll
        for (int fn = 0; fn < 4; ++fn) {
            lsum[wm][wn * 64 + fn * 16 + l] = s1[fn];
            lsq[wm][wn * 64 + fn * 16 + l] = s2v[fn];
        }
    }
    __syncthreads();
    if (t < 256) {
        part1[(size_t)t * NBLK + blockIdx.x]        = lsum[0][t] + lsum[1][t];
        part1[(size_t)(C0 + t) * NBLK + blockIdx.x] = lsq[0][t] + lsq[1][t];
    }
}

// ---------- stats: one wave per channel, coalesced [channel][block] reads ----------
__global__ void stats_k(const float* __restrict__ part, int nblk, int C,
                        const float* __restrict__ gam, const float* __restrict__ bet,
                        float* __restrict__ sc, float* __restrict__ sh)
{
    const int w = threadIdx.x >> 6, l = threadIdx.x & 63;
    const int o = blockIdx.x * 4 + w;
    if (o >= C) return;
    float s = 0.f, q = 0.f;
    for (int i = l; i < nblk; i += 64) {
        s += part[(size_t)o * nblk + i];
        q += part[(size_t)(C + o) * nblk + i];
    }
#pragma unroll
    for (int r = 32; r; r >>= 1) { s += __shfl_xor(s, r); q += __shfl_xor(q, r); }
    if (l == 0) {
        const float inv = 1.0f / (float)MM;
        float mean = s * inv;
        float var = q * inv - mean * mean;
        float scale = gam[o] * rsqrtf(var + 1e-5f);
        sc[o] = scale;
        sh[o] = bet[o] - mean * scale;
    }
}

// ---------- K5: GEMM2 with BN1+ReLU fused into A staging ----------
__launch_bounds__(256, 4)
__global__ void gemm2_k(const unsigned short* __restrict__ h1, const unsigned short* __restrict__ w1b,
                        const float* __restrict__ sc1, const float* __restrict__ sh1,
                        unsigned short* __restrict__ h2, float* __restrict__ part2)
{
    __shared__ unsigned short Als[128 * 64];
    __shared__ unsigned short Bls[128 * 64];
    __shared__ float scl[256], shl[256];
    __shared__ float lsum[2][128];
    __shared__ float lsq[2][128];

    const int t = threadIdx.x;
    const int wv = t >> 6, l = t & 63, g = l >> 4, lc = l & 15;
    const int wm = wv >> 1, wn = wv & 1;
    const int m0 = blockIdx.x * 128;
    const int sub = t & 7;

    scl[t] = sc1[t]; shl[t] = sh1[t];

    f32x4 acc[4][4];
#pragma unroll
    for (int i = 0; i < 4; ++i)
#pragma unroll
        for (int j = 0; j < 4; ++j) acc[i][j] = (f32x4){0.f, 0.f, 0.f, 0.f};

    for (int ks = 0; ks < 4; ++ks) {
        const int k0 = ks * 64;
        __syncthreads();
        uint4 r[4];
#pragma unroll
        for (int q = 0; q < 4; ++q) {
            int row = q * 32 + (t >> 3);
            r[q] = *(const uint4*)((const char*)h1 + (((size_t)(m0 + row)) * C0 + k0) * 2 + sub * 16);
        }
#pragma unroll
        for (int q = 0; q < 4; ++q) {
            int row = q * 32 + (t >> 3);
            union { uint4 v; unsigned short s[8]; } u, ov;
            u.v = r[q];
#pragma unroll
            for (int i = 0; i < 8; ++i) {
                int k = k0 + sub * 8 + i;
                float f = b2f(u.s[i]);
                ov.s[i] = f2b(fmaxf(0.0f, fmaf(scl[k], f, shl[k])));
            }
            *(uint4*)((char*)Als + row * 128 + ((sub * 16) ^ ((row & 7) << 4))) = ov.v;
        }
#pragma unroll
        for (int q = 0; q < 4; ++q) {
            int o = q * 32 + (t >> 3);
            int bco = (sub * 16) ^ ((o & 7) << 4);
            const char* src = (const char*)w1b + (((size_t)o) * C0 + k0) * 2 + bco;
            char* dst = (char*)Bls + (q * 256 + wv * 64) * 16;
            GLD16(src, dst);
        }
        __syncthreads();
#pragma unroll
        for (int kk = 0; kk < 2; ++kk) {
            short8 af[4], bfr[4];
#pragma unroll
            for (int fm = 0; fm < 4; ++fm) {
                int row = wm * 64 + fm * 16 + lc;
                int bcol = kk * 64 + g * 16;
                af[fm] = *(const short8*)((const char*)Als + row * 128 + (bcol ^ ((row & 7) << 4)));
            }
#pragma unroll
            for (int fn = 0; fn < 4; ++fn) {
                int o = wn * 64 + fn * 16 + lc;
                int bcol = kk * 64 + g * 16;
                bfr[fn] = *(const short8*)((const char*)Bls + o * 128 + (bcol ^ ((o & 7) << 4)));
            }
#pragma unroll
            for (int fm = 0; fm < 4; ++fm)
#pragma unroll
                for (int fn = 0; fn < 4; ++fn)
                    acc[fm][fn] = __builtin_amdgcn_mfma_f32_16x16x32_bf16(af[fm], bfr[fn], acc[fm][fn], 0, 0, 0);
        }
    }

    float s1[4] = {0,0,0,0}, s2v[4] = {0,0,0,0};
#pragma unroll
    for (int fm = 0; fm < 4; ++fm)
#pragma unroll
        for (int fn = 0; fn < 4; ++fn) {
            int row = m0 + wm * 64 + fm * 16 + g * 4;
            int col = wn * 64 + fn * 16 + lc;
#pragma unroll
            for (int j = 0; j < 4; ++j) {
                float v = acc[fm][fn][j];
                h2[((size_t)(row + j)) * C1 + col] = f2b(v);
                s1[fn] += v; s2v[fn] += v * v;
            }
        }
#pragma unroll
    for (int fn = 0; fn < 4; ++fn) {
        s1[fn] += __shfl_xor(s1[fn], 16); s1[fn] += __shfl_xor(s1[fn], 32);
        s2v[fn] += __shfl_xor(s2v[fn], 16); s2v[fn] += __shfl_xor(s2v[fn], 32);
    }
    if (l < 16) {
#pragma unroll
        for (int fn = 0; fn < 4; ++fn) {
            lsum[wm][wn * 64 + fn * 16 + l] = s1[fn];
            lsq[wm][wn * 64 + fn * 16 + l] = s2v[fn];
        }
    }
    __syncthreads();
    if (t < 128) {
        part2[(size_t)t * NBLK + blockIdx.x]        = lsum[0][t] + lsum[1][t];
        part2[(size_t)(C1 + t) * NBLK + blockIdx.x] = lsq[0][t] + lsq[1][t];
    }
}

// ---------- K7: final BN2+ReLU + transpose [b,n,o] -> [b,o,n] f32 ----------
__global__ void finalize_k(const unsigned short* __restrict__ h2,
                           const float* __restrict__ sc, const float* __restrict__ sh,
                           float* __restrict__ out)
{
    __shared__ float tile[64][65];
    const int b = blockIdx.z, o0 = blockIdx.y * 64, n0 = blockIdx.x * 64;
    const int t = threadIdx.x, j = t & 63, i4 = t >> 6;
    const float scv = sc[o0 + j], shv = sh[o0 + j];
#pragma unroll
    for (int p = 0; p < 64; p += 4) {
        int ni = p + i4;
        float f = b2f(h2[((size_t)b * NN + n0 + ni) * C1 + o0 + j]);
        tile[ni][j] = fmaxf(0.0f, fmaf(scv, f, shv));
    }
    __syncthreads();
#pragma unroll
    for (int p = 0; p < 64; p += 4) {
        int oi = p + i4;
        out[((size_t)(b * C1 + o0 + oi)) * NN + n0 + j] = tile[j][oi];
    }
}

// ---------- launch ----------
extern "C" void kernel_launch(void* const* d_in, const int* in_sizes, int n_in,
                              void* d_out, int out_size, void* d_ws, size_t ws_size,
                              hipStream_t stream)
{
    const float* xyz1    = (const float*)d_in[0];
    const float* xyz2    = (const float*)d_in[1];
    const float* points1 = (const float*)d_in[2];
    const float* points2 = (const float*)d_in[3];
    const float* w0      = (const float*)d_in[4];
    const float* g0      = (const float*)d_in[6];
    const float* be0     = (const float*)d_in[7];
    const float* w1      = (const float*)d_in[8];
    const float* g1      = (const float*)d_in[10];
    const float* be1     = (const float*)d_in[11];
    float* out = (float*)d_out;
    char* ws = (char*)d_ws;

    unsigned short* P1T = (unsigned short*)(ws + 0);           // 16777216
    unsigned short* h1  = (unsigned short*)(ws + 16777216);    // 33554432
    unsigned short* P2T = (unsigned short*)(ws + 50331648);    // 8388608
    unsigned short* h2  = (unsigned short*)(ws + 58720256);    // 16777216
    double* trip = (double*)(ws + 75497472);                   // 2*65536*3*8 = 3145728
    float* wtb   = (float*)(ws + 78643200);                    // 786432
    unsigned short* w0b = (unsigned short*)(ws + 79429632);    // 196608
    unsigned short* w1b = (unsigned short*)(ws + 79626240);    // 65536
    float* part1 = (float*)(ws + 79691776);                    // 1048576
    float* part2 = (float*)(ws + 80740352);                    // 524288
    float* sc1   = (float*)(ws + 81264640);
    float* sh1   = (float*)(ws + 81265664);
    float* sc2   = (float*)(ws + 81266688);
    float* sh2   = (float*)(ws + 81267712);
    // total ws needed: ~81.3 MB

    mega_front_k<<<118 * 64, 256, 0, stream>>>(xyz1, xyz2, points1, points2, w0, w1,
                                               P1T, P2T, w0b, w1b, trip, wtb);
    gemm1_k<<<MM/128, 512, 0, stream>>>(P1T, P2T, trip, wtb, w0b, h1, part1);
    stats_k<<<C0/4, 256, 0, stream>>>(part1, NBLK, C0, g0, be0, sc1, sh1);
    gemm2_k<<<MM/128, 256, 0, stream>>>(h1, w1b, sc1, sh1, h2, part2);
    stats_k<<<C1/4, 256, 0, stream>>>(part2, NBLK, C1, g1, be1, sc2, sh2);
    finalize_k<<<dim3(NN/64, C1/64, BB), 256, 0, stream>>>(h2, sc2, sh2, out);
}